// Round 8
// baseline (736.619 us; speedup 1.0000x reference)
//
#include <hip/hip_runtime.h>
#include <math.h>

#define N_NODES 16384
#define N_EDGES 262144
#define EPSF 1e-8f

// ---------------- LDS pool layout (bytes), 32 edges/block ----------------
#define OFF_XE    0        // bf16 [32][232] = 14848   (LN 0..63, c0 64..223)
#define OFF_C12   14848    // bf16 [32][328] = 20992 -> 35840
#define OFF_FR    35840    // f16  [32][12]  =   768 -> 36608 (persistent)
#define OFF_EDST  36608    // int  [32]      =   128 -> 36736 (persistent)
#define OFF_ESRC  36736    // int  [32]      =   128 -> 36864 (persistent)
#define OFF_WENV  36864    // bf16 [32][200] = 12800 -> 49664 (persistent from G3)
#define POOL_BYTES 49664   // 3 blocks/CU (3*49664 = 148992 <= 163840)
// overlays (after G1/G2 done reading XE/C12) - all below 35840, WENV safe
#define OFF_SACT  0        // bf16 [32][136] = 8704
#define OFF_GATE  8704     // bf16 [32][72]  = 4608 -> 13312
#define OFF_C0O   13312    // bf16 [32][72]  = 4608 -> 17920
#define OFF_C1O   17920    // bf16 [32][72]  = 4608 -> 22528
#define OFF_C2O   22528    // bf16 [32][72]  = 4608 -> 27136
#define OFF_VG    8704     // bf16 [3][32][72] = 13824 -> 22528 (over GATE/C0O/C1O after consumed)
// final overlay: R f16 [32][320] = 20480 at 0 (after SACT/VG consumed)

typedef __bf16 bf16x8 __attribute__((ext_vector_type(8)));
typedef float  f32x4  __attribute__((ext_vector_type(4)));

__device__ __forceinline__ f32x4 MFMA16(bf16x8 a, bf16x8 b, f32x4 c){
  return __builtin_amdgcn_mfma_f32_16x16x32_bf16(a, b, c, 0, 0, 0);
}

__device__ __forceinline__ unsigned f2bf(float x){
  __bf16 h = (__bf16)x;
  union { __bf16 b; unsigned short u; } c; c.b = h;
  return (unsigned)c.u;
}
__device__ __forceinline__ float bf2f(unsigned short h){
  union { unsigned u; float f; } c; c.u = ((unsigned)h)<<16;
  return c.f;
}
__device__ __forceinline__ float wsum32(float v){
  #pragma unroll
  for (int m=1; m<32; m<<=1) v += __shfl_xor(v, m);
  return v;
}
__device__ __forceinline__ float wsum64(float v){
  #pragma unroll
  for (int m=1; m<64; m<<=1) v += __shfl_xor(v, m);
  return v;
}
__device__ __forceinline__ float sigm(float x){ return 1.0f/(1.0f+__expf(-x)); }
__device__ __forceinline__ float silu(float x){ return x/(1.0f+__expf(-x)); }

// ---------------- fused weight pack kernel (B-fragment layout) ----------------
__global__ __launch_bounds__(256) void k_pack_all(
  const float* __restrict__ Wm0, const float* __restrict__ wr,
  const float* __restrict__ wi,  const float* __restrict__ Wenv,
  const float* __restrict__ Wp0, const float* __restrict__ Wpv,
  unsigned short* __restrict__ wpk)
{
  int i = blockIdx.x*256 + threadIdx.x;
  if (i < 122880){                       // Wm0 [480][256]
    int k = i >> 8, n = i & 255;
    int idx = (((k>>5)*256 + n)*4 + ((k>>3)&3))*8 + (k&7);
    wpk[idx] = f2bf(Wm0[i]);
  } else if (i < 163840){                // Wc [320][128] = [[wr,wi],[-wi,wr]]
    int j = i - 122880;
    int k = j >> 7, n = j & 127;
    float v;
    if (k < 160) v = (n < 64) ? wr[k*64 + n]        : wi[k*64 + (n-64)];
    else         v = (n < 64) ? -wi[(k-160)*64 + n] : wr[(k-160)*64 + (n-64)];
    int idx = (((k>>5)*128 + n)*4 + ((k>>3)&3))*8 + (k&7);
    wpk[122880 + idx] = f2bf(v);
  } else if (i < 188416){                // Wenv [128][192]
    int j = i - 163840;
    int k = j / 192, n = j - k*192;
    int idx = (((k>>5)*192 + n)*4 + ((k>>3)&3))*8 + (k&7);
    wpk[163840 + idx] = f2bf(Wenv[j]);
  } else if (i < 204800){                // Wp0 [128][128]
    int j = i - 188416;
    int k = j >> 7, n = j & 127;
    int idx = (((k>>5)*128 + n)*4 + ((k>>3)&3))*8 + (k&7);
    wpk[188416 + idx] = f2bf(Wp0[j]);
  } else if (i < 208896){                // Wpv [64][64]
    int j = i - 204800;
    int k = j >> 6, n = j & 63;
    int idx = (((k>>5)*64 + n)*4 + ((k>>3)&3))*8 + (k&7);
    wpk[204800 + idx] = f2bf(Wpv[j]);
  }
}

// ---------------- CSR build (perm = edges sorted by dst) ----------------
__global__ __launch_bounds__(256) void k_hist(const int* __restrict__ eidx, int* __restrict__ cnt){
  int e = blockIdx.x*256 + threadIdx.x;
  if (e < N_EDGES) atomicAdd(&cnt[eidx[N_EDGES+e]], 1);
}
__global__ __launch_bounds__(256) void k_scan(const int* __restrict__ cnt,
                                              int* __restrict__ rowp, int* __restrict__ cursor){
  __shared__ int part[256];
  __shared__ int pref[257];
  const int t = threadIdx.x;
  const int base = t*64;
  int s = 0;
  for (int i=0;i<64;i++) s += cnt[base+i];
  part[t] = s; __syncthreads();
  if (t==0){ int a=0; for (int i=0;i<256;i++){ pref[i]=a; a+=part[i]; } pref[256]=a; }
  __syncthreads();
  int a = pref[t];
  for (int i=0;i<64;i++){ rowp[base+i]=a; cursor[base+i]=a; a += cnt[base+i]; }
  if (t==0) rowp[N_NODES] = pref[256];
}
__global__ __launch_bounds__(256) void k_fill(const int* __restrict__ eidx,
                                              int* __restrict__ cursor, int* __restrict__ perm){
  int e = blockIdx.x*256 + threadIdx.x;
  if (e < N_EDGES){
    int pos = atomicAdd(&cursor[eidx[N_EDGES+e]], 1);
    perm[pos] = e;
  }
}

// ---------------- Kernel 1: node separable LN (scalars bf16, vectors f16) ----------------
__global__ __launch_bounds__(256) void k_node_ln(
    const float* __restrict__ nf, const float* __restrict__ g0,
    const float* __restrict__ b0, const float* __restrict__ g1,
    unsigned short* __restrict__ ns_ln, _Float16* __restrict__ nv_ln)
{
  const int tid  = threadIdx.x;
  const int lane = tid & 63;
  const int n    = blockIdx.x*4 + (tid>>6);
  const float* row = nf + (size_t)n*320;

  float s0 = row[lane], s1 = row[64+lane];
  float mu = wsum64(s0+s1) * (1.0f/128.0f);
  float d0 = s0-mu, d1 = s1-mu;
  float var = wsum64(d0*d0+d1*d1) * (1.0f/128.0f);
  float rs = rsqrtf(var + EPSF);
  ns_ln[(size_t)n*128 + lane]    = f2bf(d0*rs*g0[lane]    + b0[lane]);
  ns_ln[(size_t)n*128 + 64+lane] = f2bf(d1*rs*g0[64+lane] + b0[64+lane]);

  float px = row[128+lane*3+0], py = row[128+lane*3+1], pz = row[128+lane*3+2];
  float vvar = wsum64(px*px+py*py+pz*pz) * (1.0f/192.0f);
  float vsc = rsqrtf(vvar + EPSF) * g1[lane];
  nv_ln[(size_t)n*192 + lane*3+0] = (_Float16)(px*vsc);
  nv_ln[(size_t)n*192 + lane*3+1] = (_Float16)(py*vsc);
  nv_ln[(size_t)n*192 + lane*3+2] = (_Float16)(pz*vsc);
}

// ---------------- Kernel 2: edge message kernel (MFMA, 32 edges/block, slot order) ----------------
__global__ __launch_bounds__(256,3) void k_edge(
  const float* __restrict__ ef, const float* __restrict__ evec,
  const float* __restrict__ lats,
  const float* __restrict__ g0e, const float* __restrict__ b0e, const float* __restrict__ g1e,
  const unsigned short* __restrict__ pWm0, const unsigned short* __restrict__ pWc,
  const unsigned short* __restrict__ pWenv, const unsigned short* __restrict__ pWp0,
  const unsigned short* __restrict__ pWpv,
  const float* __restrict__ bp0,
  const int* __restrict__ eidx, const int* __restrict__ perm,
  const unsigned short* __restrict__ ns_ln, const _Float16* __restrict__ nv_ln,
  float* __restrict__ sa, float* __restrict__ va)
{
  extern __shared__ unsigned char pool[];
  const int tid = threadIdx.x;
  unsigned short* XE   = (unsigned short*)(pool + OFF_XE);
  unsigned short* C12s = (unsigned short*)(pool + OFF_C12);
  _Float16* FRh = (_Float16*)(pool + OFF_FR);
  int* EDST = (int*)(pool + OFF_EDST);
  int* ESRC = (int*)(pool + OFF_ESRC);
  unsigned short* WEs = (unsigned short*)(pool + OFF_WENV);

  // XCD-aware swizzle: contiguous slot span per XCD (nwg = 8192, %8 == 0)
  const int nwg = gridDim.x;
  const int bswz = (blockIdx.x & 7)*(nwg>>3) + (blockIdx.x >> 3);

  const int wid = tid>>6, l = tid&63;
  const int r15 = l&15, g = l>>4;
  const int sbase = bswz*32;

  // ---------------- Phase A: prep (4 passes of 8 edges, 32 lanes/edge) ----------------
  {
    const int ln = tid & 31;
    #pragma unroll
    for (int eo=0; eo<4; ++eo){
      const int el = eo*8 + (tid>>5);
      const int slot = sbase + el;
      const size_t e = (size_t)perm[slot];
      const int src = eidx[e];
      const int dst = eidx[N_EDGES + e];

      // frame (redundant per lane)
      float vx=evec[e*3+0], vy=evec[e*3+1], vz=evec[e*3+2];
      float rn = rsqrtf(vx*vx+vy*vy+vz*vz+EPSF);
      float ax=vx*rn, ay=vy*rn, az=vz*rn;
      float hx, hz;
      if (fabsf(az) < 0.99f){ hx=0.f; hz=1.f; } else { hx=1.f; hz=0.f; }
      float e1x = -hz*ay;
      float e1y = hz*ax - hx*az;
      float e1z = hx*ay;
      float rn1 = rsqrtf(e1x*e1x+e1y*e1y+e1z*e1z+EPSF);
      e1x*=rn1; e1y*=rn1; e1z*=rn1;
      float e2x = ay*e1z - az*e1y;
      float e2y = az*e1x - ax*e1z;
      float e2z = ax*e1y - ay*e1x;
      if (ln==0){
        FRh[el*12+0]=(_Float16)ax;  FRh[el*12+1]=(_Float16)ay;  FRh[el*12+2]=(_Float16)az;
        FRh[el*12+3]=(_Float16)e1x; FRh[el*12+4]=(_Float16)e1y; FRh[el*12+5]=(_Float16)e1z;
        FRh[el*12+6]=(_Float16)e2x; FRh[el*12+7]=(_Float16)e2y; FRh[el*12+8]=(_Float16)e2z;
        EDST[el]=dst;
        ESRC[el]=src;
      }

      const float* erow = ef + e*160;

      // edge scalar LN: 2 consecutive channels per lane, packed b32 write
      {
        float2 sp = *(const float2*)&erow[2*ln];
        float mu = wsum32(sp.x+sp.y)*(1.f/64.f);
        float d0=sp.x-mu, d1=sp.y-mu;
        float var = wsum32(d0*d0+d1*d1)*(1.f/64.f);
        float rs = rsqrtf(var+EPSF);
        float2 gv = *(const float2*)&g0e[2*ln];
        float2 bv = *(const float2*)&b0e[2*ln];
        unsigned lo = f2bf(d0*rs*gv.x + bv.x);
        unsigned hi = f2bf(d1*rs*gv.y + bv.y);
        *(unsigned*)&XE[el*232 + 2*ln] = lo | (hi<<16);
      }

      // edge-vec channels: lanes 0..7, 4 channels each
      {
        float evb[12];
        float evq = 0.f;
        if (ln < 8){
          float4 p0 = *(const float4*)&erow[64 + ln*12];
          float4 p1 = *(const float4*)&erow[64 + ln*12 + 4];
          float4 p2 = *(const float4*)&erow[64 + ln*12 + 8];
          evb[0]=p0.x; evb[1]=p0.y; evb[2]=p0.z; evb[3]=p0.w;
          evb[4]=p1.x; evb[5]=p1.y; evb[6]=p1.z; evb[7]=p1.w;
          evb[8]=p2.x; evb[9]=p2.y; evb[10]=p2.z; evb[11]=p2.w;
          #pragma unroll
          for (int i=0;i<12;i++) evq += evb[i]*evb[i];
        }
        float vvar = wsum32(evq)*(1.f/96.f);
        float vsce = rsqrtf(vvar+EPSF);
        if (ln < 8){
          unsigned xw[2]={0,0}, c1w[2]={0,0}, c2w[2]={0,0};
          #pragma unroll
          for (int i=0;i<4;i++){
            float s = vsce * g1e[ln*4+i];
            float wx=evb[3*i]*s, wy=evb[3*i+1]*s, wz=evb[3*i+2]*s;
            unsigned c0 = f2bf(wx*ax +wy*ay +wz*az);
            unsigned c1 = f2bf(wx*e1x+wy*e1y+wz*e1z);
            unsigned c2 = f2bf(wx*e2x+wy*e2y+wz*e2z);
            int w = i>>1, sh = (i&1)*16;
            xw[w] |= c0<<sh; c1w[w] |= c1<<sh; c2w[w] |= c2<<sh;
          }
          uint2 xv={xw[0],xw[1]}, c1v={c1w[0],c1w[1]}, c2v={c2w[0],c2w[1]};
          *(uint2*)&XE  [el*232 + 128 + ln*4]      = xv;   // c0 edge channels u=64..95
          *(uint2*)&C12s[el*328 + 64 + ln*4]       = c1v;
          *(uint2*)&C12s[el*328 + 160 + 64 + ln*4] = c2v;
        }
      }

      // node-vector channels: lanes 0..15 src (4 ch each), 16..31 dst
      {
        const int isrc = (ln < 16);
        const int u0 = (ln & 15)*4;
        const int node = isrc ? src : dst;
        const _Float16* nvp = nv_ln + (size_t)node*192 + u0*3;
        union { uint2 u2; _Float16 h[4]; } nb0, nb1, nb2;
        nb0.u2 = *(const uint2*)(nvp);
        nb1.u2 = *(const uint2*)(nvp+4);
        nb2.u2 = *(const uint2*)(nvp+8);
        _Float16 hh[12];
        *(uint2*)&hh[0] = nb0.u2; *(uint2*)&hh[4] = nb1.u2; *(uint2*)&hh[8] = nb2.u2;
        unsigned xw[2]={0,0}, c1w[2]={0,0}, c2w[2]={0,0};
        #pragma unroll
        for (int i=0;i<4;i++){
          float px=(float)hh[3*i], py=(float)hh[3*i+1], pz=(float)hh[3*i+2];
          unsigned c0 = f2bf(px*ax +py*ay +pz*az);
          unsigned c1 = f2bf(px*e1x+py*e1y+pz*e1z);
          unsigned c2 = f2bf(px*e2x+py*e2y+pz*e2z);
          int w = i>>1, sh = (i&1)*16;
          xw[w] |= c0<<sh; c1w[w] |= c1<<sh; c2w[w] |= c2<<sh;
        }
        const int cb = isrc ? u0 : (96 + u0);
        uint2 xv={xw[0],xw[1]}, c1v={c1w[0],c1w[1]}, c2v={c2w[0],c2w[1]};
        *(uint2*)&XE  [el*232 + 64 + cb]  = xv;
        *(uint2*)&C12s[el*328 + cb]       = c1v;
        *(uint2*)&C12s[el*328 + 160 + cb] = c2v;
      }
    }
  }
  __syncthreads();

  const f32x4 zero4 = {0.f,0.f,0.f,0.f};

  // G1: m0 = X[32x480] @ Wm0[480x256]
  f32x4 acc1[2][4];
  #pragma unroll
  for (int m=0;m<2;m++)
    #pragma unroll
    for (int n=0;n<4;n++) acc1[m][n]=zero4;
  {
    const unsigned short* bbase = pWm0 + ((size_t)(wid*64 + r15)*4 + g)*8;
    bf16x8 gA[2][8];
    {
      const int rs0 = ESRC[r15], rs1 = ESRC[16+r15];
      const int rd0 = EDST[r15], rd1 = EDST[16+r15];
      #pragma unroll
      for (int q=0;q<4;q++){
        gA[0][q]   = *(const bf16x8*)&ns_ln[(size_t)rs0*128 + q*32 + g*8];
        gA[1][q]   = *(const bf16x8*)&ns_ln[(size_t)rs1*128 + q*32 + g*8];
        gA[0][4+q] = *(const bf16x8*)&ns_ln[(size_t)rd0*128 + q*32 + g*8];
        gA[1][4+q] = *(const bf16x8*)&ns_ln[(size_t)rd1*128 + q*32 + g*8];
      }
    }
    #pragma unroll
    for (int t=0;t<7;t++){
      const int kc  = (t<2) ? (4+t) : (10 + t-2);
      const int col = (t<2) ? (t*32) : (64 + (t-2)*32);
      bf16x8 a0 = *(const bf16x8*)&XE[(    r15)*232 + col + g*8];
      bf16x8 a1 = *(const bf16x8*)&XE[(16+ r15)*232 + col + g*8];
      const unsigned short* bp = bbase + (size_t)kc*8192;
      #pragma unroll
      for (int n=0;n<4;n++){
        bf16x8 b = *(const bf16x8*)(bp + n*512);
        acc1[0][n] = MFMA16(a0,b,acc1[0][n]);
        acc1[1][n] = MFMA16(a1,b,acc1[1][n]);
      }
    }
    #pragma unroll
    for (int t=0;t<8;t++){
      const int kc = (t<4) ? t : (6 + t-4);
      const unsigned short* bp = bbase + (size_t)kc*8192;
      #pragma unroll
      for (int n=0;n<4;n++){
        bf16x8 b = *(const bf16x8*)(bp + n*512);
        acc1[0][n] = MFMA16(gA[0][t],b,acc1[0][n]);
        acc1[1][n] = MFMA16(gA[1][t],b,acc1[1][n]);
      }
    }
  }

  // G2: c12o = C12[32x320] @ Wc[320x128]
  f32x4 acc2[2][2];
  #pragma unroll
  for (int m=0;m<2;m++){ acc2[m][0]=zero4; acc2[m][1]=zero4; }
  {
    const unsigned short* bbase = pWc + ((size_t)(wid*32 + r15)*4 + g)*8;
    #pragma unroll
    for (int kc=0;kc<10;kc++){
      bf16x8 a0 = *(const bf16x8*)&C12s[(    r15)*328 + kc*32 + g*8];
      bf16x8 a1 = *(const bf16x8*)&C12s[(16+ r15)*328 + kc*32 + g*8];
      const unsigned short* bp = bbase + (size_t)kc*4096;
      #pragma unroll
      for (int n=0;n<2;n++){
        bf16x8 b = *(const bf16x8*)(bp + n*512);
        acc2[0][n] = MFMA16(a0,b,acc2[0][n]);
        acc2[1][n] = MFMA16(a1,b,acc2[1][n]);
      }
    }
  }

  // G3: w = LAT[32x128] @ Wenv[128x192], A from global lats (f32->bf16)
  {
    f32x4 acc3[2][3];
    #pragma unroll
    for (int m=0;m<2;m++)
      #pragma unroll
      for (int n=0;n<3;n++) acc3[m][n]=zero4;
    const int eA0 = perm[sbase + r15];
    const int eA1 = perm[sbase + 16 + r15];
    const float* la0 = lats + (size_t)eA0*128;
    const float* la1 = lats + (size_t)eA1*128;
    const unsigned short* bbase = pWenv + ((size_t)(wid*48 + r15)*4 + g)*8;
    #pragma unroll
    for (int kc=0;kc<4;kc++){
      float4 f00 = *(const float4*)&la0[kc*32 + g*8];
      float4 f01 = *(const float4*)&la0[kc*32 + g*8 + 4];
      float4 f10 = *(const float4*)&la1[kc*32 + g*8];
      float4 f11 = *(const float4*)&la1[kc*32 + g*8 + 4];
      union { bf16x8 v; unsigned short s[8]; } a0, a1;
      a0.s[0]=f2bf(f00.x); a0.s[1]=f2bf(f00.y); a0.s[2]=f2bf(f00.z); a0.s[3]=f2bf(f00.w);
      a0.s[4]=f2bf(f01.x); a0.s[5]=f2bf(f01.y); a0.s[6]=f2bf(f01.z); a0.s[7]=f2bf(f01.w);
      a1.s[0]=f2bf(f10.x); a1.s[1]=f2bf(f10.y); a1.s[2]=f2bf(f10.z); a1.s[3]=f2bf(f10.w);
      a1.s[4]=f2bf(f11.x); a1.s[5]=f2bf(f11.y); a1.s[6]=f2bf(f11.z); a1.s[7]=f2bf(f11.w);
      #pragma unroll
      for (int n=0;n<3;n++){
        bf16x8 b = *(const bf16x8*)(bbase + (size_t)kc*6144 + n*512);
        acc3[0][n] = MFMA16(a0.v, b, acc3[0][n]);
        acc3[1][n] = MFMA16(a1.v, b, acc3[1][n]);
      }
    }
    // epilogue -> WENV (separate LDS region; pre-barrier safe)
    #pragma unroll
    for (int m=0;m<2;m++)
      #pragma unroll
      for (int n=0;n<3;n++)
        #pragma unroll
        for (int r=0;r<4;r++){
          int e = m*16 + g*4 + r;
          int j = wid*48 + n*16 + r15;
          WEs[e*200 + j] = f2bf(acc3[m][n][r]*0.08838834764831845f);
        }
  }

  __syncthreads();   // XE/C12 reads done; WENV visible

  // read epilogue scale operands from WENV
  float wsc[2][2][4], wvc[2][4], bp0v[2];
  #pragma unroll
  for (int n=0;n<2;n++) bp0v[n] = bp0[wid*32 + n*16 + r15];
  #pragma unroll
  for (int m=0;m<2;m++)
    #pragma unroll
    for (int r=0;r<4;r++){
      int e = m*16 + g*4 + r;
      #pragma unroll
      for (int n=0;n<2;n++)
        wsc[m][n][r] = bf2f(WEs[e*200 + wid*32 + n*16 + r15]);
      wvc[m][r] = bf2f(WEs[e*200 + 128 + wid*16 + r15]);
    }

  // G1/G2 epilogues -> overlays (bf16)
  {
    unsigned short* SAs = (unsigned short*)(pool + OFF_SACT);
    unsigned short* GAb = (unsigned short*)(pool + OFF_GATE);
    unsigned short* C0b = (unsigned short*)(pool + OFF_C0O);
    #pragma unroll
    for (int m=0;m<2;m++)
      #pragma unroll
      for (int n=0;n<4;n++)
        #pragma unroll
        for (int r=0;r<4;r++){
          int e = m*16 + g*4 + r;
          int j = wid*64 + n*16 + r15;
          float v = acc1[m][n][r]*0.04564354645876384f;  // 1/sqrt(480)
          if (j < 128)      SAs[e*136 + j] = f2bf(silu(v));
          else if (j < 192) GAb[e*72 + (j-128)] = f2bf(sigm(v));
          else              C0b[e*72 + (j-192)] = f2bf(v);
        }
    unsigned short* C1b = (unsigned short*)(pool + OFF_C1O);
    unsigned short* C2b = (unsigned short*)(pool + OFF_C2O);
    #pragma unroll
    for (int m=0;m<2;m++)
      #pragma unroll
      for (int n=0;n<2;n++)
        #pragma unroll
        for (int r=0;r<4;r++){
          int e = m*16 + g*4 + r;
          int j = wid*32 + n*16 + r15;
          float v = acc2[m][n][r]*0.07905694150420949f;  // 1/sqrt(160)
          if (j < 64) C1b[e*72 + j] = f2bf(v);
          else        C2b[e*72 + (j-64)] = f2bf(v);
        }
  }
  __syncthreads();

  // C1: v_g = (c0o*a + c1o*e1 + c2o*e2)*gate -> VG bf16 (8 u's/thread)
  {
    const int e = tid>>3, u0 = (tid&7)*8;
    const unsigned short* GAb = (const unsigned short*)(pool + OFF_GATE);
    const unsigned short* C0b = (const unsigned short*)(pool + OFF_C0O);
    const unsigned short* C1b = (const unsigned short*)(pool + OFF_C1O);
    const unsigned short* C2b = (const unsigned short*)(pool + OFF_C2O);
    float ax=(float)FRh[e*12+0],  ay=(float)FRh[e*12+1],  az=(float)FRh[e*12+2];
    float b1x=(float)FRh[e*12+3], b1y=(float)FRh[e*12+4], b1z=(float)FRh[e*12+5];
    float b2x=(float)FRh[e*12+6], b2y=(float)FRh[e*12+7], b2z=(float)FRh[e*12+8];
    float vgx[8], vgy[8], vgz[8];
    #pragma unroll
    for (int i=0;i<8;i++){
      int u = u0+i;
      float gt = bf2f(GAb[e*72+u]);
      float c0 = bf2f(C0b[e*72+u]), c1 = bf2f(C1b[e*72+u]), c2 = bf2f(C2b[e*72+u]);
      vgx[i] = (c0*ax + c1*b1x + c2*b2x)*gt;
      vgy[i] = (c0*ay + c1*b1y + c2*b2y)*gt;
      vgz[i] = (c0*az + c1*b1z + c2*b2z)*gt;
    }
    __syncthreads();   // GATE/C0O/C1O reads done before VG overlay writes
    unsigned short* VGs = (unsigned short*)(pool + OFF_VG);
    #pragma unroll
    for (int i=0;i<4;i++){
      unsigned wx = f2bf(vgx[2*i]) | (f2bf(vgx[2*i+1])<<16);
      unsigned wy = f2bf(vgy[2*i]) | (f2bf(vgy[2*i+1])<<16);
      unsigned wz = f2bf(vgz[2*i]) | (f2bf(vgz[2*i+1])<<16);
      *(unsigned*)&VGs[0*2304 + e*72 + u0 + 2*i] = wx;
      *(unsigned*)&VGs[1*2304 + e*72 + u0 + 2*i] = wy;
      *(unsigned*)&VGs[2*2304 + e*72 + u0 + 2*i] = wz;
    }
  }
  __syncthreads();

  // G4: s2 = SACT @ Wp0 ; G5: v2c = VG[c] @ Wpv
  {
    const unsigned short* SAs = (const unsigned short*)(pool + OFF_SACT);
    const unsigned short* VGs = (const unsigned short*)(pool + OFF_VG);

    f32x4 acc4[2][2], acc5[3][2];
    #pragma unroll
    for (int m=0;m<2;m++){ acc4[m][0]=zero4; acc4[m][1]=zero4; }
    #pragma unroll
    for (int c=0;c<3;c++){ acc5[c][0]=zero4; acc5[c][1]=zero4; }

    {
      const unsigned short* bbase = pWp0 + ((size_t)(wid*32 + r15)*4 + g)*8;
      #pragma unroll
      for (int kc=0;kc<4;kc++){
        bf16x8 a0 = *(const bf16x8*)&SAs[(    r15)*136 + kc*32 + g*8];
        bf16x8 a1 = *(const bf16x8*)&SAs[(16+ r15)*136 + kc*32 + g*8];
        #pragma unroll
        for (int n=0;n<2;n++){
          bf16x8 b = *(const bf16x8*)(bbase + (size_t)kc*4096 + n*512);
          acc4[0][n] = MFMA16(a0,b,acc4[0][n]);
          acc4[1][n] = MFMA16(a1,b,acc4[1][n]);
        }
      }
    }
    {
      bf16x8 b5[2];
      #pragma unroll
      for (int kc=0;kc<2;kc++)
        b5[kc] = *(const bf16x8*)(pWpv + ((size_t)(kc*64 + wid*16 + r15)*4 + g)*8);
      #pragma unroll
      for (int c=0;c<3;c++)
        #pragma unroll
        for (int kc=0;kc<2;kc++){
          bf16x8 a0 = *(const bf16x8*)&VGs[c*2304 + (    r15)*72 + kc*32 + g*8];
          bf16x8 a1 = *(const bf16x8*)&VGs[c*2304 + (16+ r15)*72 + kc*32 + g*8];
          acc5[c][0] = MFMA16(a0,b5[kc],acc5[c][0]);
          acc5[c][1] = MFMA16(a1,b5[kc],acc5[c][1]);
        }
    }

    __syncthreads();   // all waves done reading SACT/VG before R overlay
    _Float16* R = (_Float16*)pool;   // f16 [32][320]
    #pragma unroll
    for (int m=0;m<2;m++)
      #pragma unroll
      for (int n=0;n<2;n++)
        #pragma unroll
        for (int r=0;r<4;r++){
          int e = m*16 + g*4 + r;
          int j = wid*32 + n*16 + r15;
          R[e*320 + j] = (_Float16)((acc4[m][n][r]*0.08838834764831845f + bp0v[n]) * wsc[m][n][r]);
        }
    #pragma unroll
    for (int c=0;c<3;c++)
      #pragma unroll
      for (int m=0;m<2;m++)
        #pragma unroll
        for (int r=0;r<4;r++){
          int e = m*16 + g*4 + r;
          int vch = wid*16 + r15;
          R[e*320 + 128 + vch*3 + c] = (_Float16)(acc5[c][m][r]*0.125f * wvc[m][r]);
        }
    __syncthreads();

    // segmented reduction over dst runs (slot order => sorted dst), then atomics
    for (int j = tid; j < 320; j += 256){
      float accv = (float)R[j];
      int cur = EDST[0];
      for (int e=1;e<32;e++){
        int d = EDST[e];
        float v = (float)R[e*320 + j];
        if (d != cur){
          float* tgt = (j<128) ? &sa[(size_t)cur*128 + j] : &va[(size_t)cur*192 + (j-128)];
          atomicAdd(tgt, accv);
          accv = v; cur = d;
        } else accv += v;
      }
      float* tgt = (j<128) ? &sa[(size_t)cur*128 + j] : &va[(size_t)cur*192 + (j-128)];
      atomicAdd(tgt, accv);
    }
  }
}

// ---------------- Kernel 3: per-node head + residual ----------------
__global__ __launch_bounds__(256) void k_node_out(
  const float* __restrict__ nf, const float* __restrict__ oh,
  const float* __restrict__ Wtp0, const float* __restrict__ Wtp1,
  const float* __restrict__ Wo0, const float* __restrict__ bo0,
  const float* __restrict__ Wov, const float* __restrict__ resp,
  const float* __restrict__ sa, const float* __restrict__ va,
  float* __restrict__ out)
{
  __shared__ float SAB[4][128];
  __shared__ float VX[4][64], VY[4][64], VZ[4][64];
  __shared__ float S3 [4][128];
  __shared__ float V3 [4][256];
  const int tid=threadIdx.x, lane=tid&63, g=tid>>6;
  const int n = blockIdx.x*4 + g;

  float cf=0.f;
  #pragma unroll
  for (int j=0;j<16;j++) cf += j*oh[(size_t)n*16+j];
  const int c = (int)(cf+0.5f);

  SAB[g][lane]    = sa[(size_t)n*128+lane]   *0.25f;
  SAB[g][64+lane] = sa[(size_t)n*128+64+lane]*0.25f;
  VX[g][lane] = va[(size_t)n*192+lane*3+0]*0.25f;
  VY[g][lane] = va[(size_t)n*192+lane*3+1]*0.25f;
  VZ[g][lane] = va[(size_t)n*192+lane*3+2]*0.25f;
  __syncthreads();

  float t00=0.f, t01=0.f, t02=0.f;
  const float* w0c = Wtp0 + (size_t)c*192;
  for (int u=0;u<128;u++){
    float s = SAB[g][u];
    t00 += s * w0c[(size_t)u*3072 + lane];
    t01 += s * w0c[(size_t)u*3072 + lane+64];
    t02 += s * w0c[(size_t)u*3072 + lane+128];
  }
  const float sct0 = 0.02209708691f; // 1/sqrt(2048)
  t00*=sct0; t01*=sct0; t02*=sct0;

  float t1x=0.f,t1y=0.f,t1z=0.f;
  const float* w1c = Wtp1 + (size_t)c*64;
  for (int u=0;u<64;u++){
    float wv = w1c[(size_t)u*1024 + lane];
    t1x += VX[g][u]*wv;
    t1y += VY[g][u]*wv;
    t1z += VZ[g][u]*wv;
  }
  t1x*=0.03125f; t1y*=0.03125f; t1z*=0.03125f;

  S3[g][lane]    = silu(t00);
  S3[g][64+lane] = silu(t01);
  float g2 = sigm(t02);
  float4 v3v = {t1x*g2, t1y*g2, t1z*g2, 0.f};
  *(float4*)&V3[g][lane*4] = v3v;
  __syncthreads();

  float s40=0.f, s41=0.f;
  for (int k=0;k<128;k++){
    float s3k = S3[g][k];
    s40 += s3k*Wo0[k*128+lane];
    s41 += s3k*Wo0[k*128+64+lane];
  }
  s40 = s40*0.08838834765f + bo0[lane];
  s41 = s41*0.08838834765f + bo0[64+lane];

  float v4x=0.f,v4y=0.f,v4z=0.f;
  for (int u=0;u<64;u++){
    float4 v3u = *(const float4*)&V3[g][u*4];
    float wv = Wov[u*64+lane];
    v4x += v3u.x*wv; v4y += v3u.y*wv; v4z += v3u.z*wv;
  }
  v4x*=0.125f; v4y*=0.125f; v4z*=0.125f;

  const float r = sigm(resp[0]);
  const float* row = nf + (size_t)n*320;
  float* orow = out + (size_t)n*320;
  orow[lane]      = r*row[lane]      + (1.f-r)*s40;
  orow[64+lane]   = r*row[64+lane]   + (1.f-r)*s41;
  orow[128+lane*3+0] = r*row[128+lane*3+0] + (1.f-r)*v4x;
  orow[128+lane*3+1] = r*row[128+lane*3+1] + (1.f-r)*v4y;
  orow[128+lane*3+2] = r*row[128+lane*3+2] + (1.f-r)*v4z;
}

extern "C" void kernel_launch(void* const* d_in, const int* in_sizes, int n_in,
                              void* d_out, int out_size, void* d_ws, size_t ws_size,
                              hipStream_t stream)
{
  const float* nf   = (const float*)d_in[0];
  const float* ef   = (const float*)d_in[1];
  const float* evec = (const float*)d_in[2];
  const float* lats = (const float*)d_in[3];
  const float* oh   = (const float*)d_in[4];
  const float* g0n  = (const float*)d_in[5];
  const float* b0n  = (const float*)d_in[6];
  const float* g1n  = (const float*)d_in[7];
  const float* g0e  = (const float*)d_in[8];
  const float* b0e  = (const float*)d_in[9];
  const float* g1e  = (const float*)d_in[10];
  const float* Wm0  = (const float*)d_in[11];
  const float* wr   = (const float*)d_in[12];
  const float* wi   = (const float*)d_in[13];
  const float* Wenv = (const float*)d_in[14];
  const float* Wp0  = (const float*)d_in[15];
  const float* bp0  = (const float*)d_in[16];
  const float* Wpv  = (const float*)d_in[17];
  const float* Wtp0 = (const float*)d_in[18];
  const float* Wtp1 = (const float*)d_in[19];
  const float* Wo0  = (const float*)d_in[20];
  const float* bo0  = (const float*)d_in[21];
  const float* Wov  = (const float*)d_in[22];
  const float* resp = (const float*)d_in[23];
  const int*   eidx = (const int*)d_in[24];

  char* base = (char*)d_ws;
  unsigned short* ns_ln = (unsigned short*)(base);            // 4,194,304 B
  _Float16* nv_ln = (_Float16*)(base + 4194304);              // 6,291,456 -> 10,485,760
  float* sa    = (float*)(base + 10485760);                   // 8,388,608 -> 18,874,368
  float* va    = (float*)(base + 18874368);                   // 12,582,912 -> 31,457,280
  unsigned short* wpk = (unsigned short*)(base + 31457280);   // 417,792   -> 31,875,072
  unsigned short* pWm0  = wpk;            // 480*256
  unsigned short* pWc   = wpk + 122880;   // 320*128
  unsigned short* pWenv = wpk + 163840;   // 128*192
  unsigned short* pWp0  = wpk + 188416;   // 128*128
  unsigned short* pWpv  = wpk + 204800;   //  64*64
  int* ibuf   = (int*)(base + 31875072);                      // 311,297 ints
  int* cnt    = ibuf;
  int* rowp   = ibuf + 16384;
  int* cursor = ibuf + 32769;
  int* perm   = ibuf + 49153;

  hipMemsetAsync(sa, 0, (size_t)N_NODES*320*sizeof(float), stream);
  hipMemsetAsync(cnt, 0, N_NODES*sizeof(int), stream);

  k_pack_all<<<(208896+255)/256, 256, 0, stream>>>(Wm0, wr, wi, Wenv, Wp0, Wpv, wpk);
  k_node_ln<<<N_NODES/4, 256, 0, stream>>>(nf, g0n, b0n, g1n, ns_ln, nv_ln);

  k_hist<<<(N_EDGES+255)/256, 256, 0, stream>>>(eidx, cnt);
  k_scan<<<1, 256, 0, stream>>>(cnt, rowp, cursor);
  k_fill<<<(N_EDGES+255)/256, 256, 0, stream>>>(eidx, cursor, perm);

  k_edge<<<N_EDGES/32, 256, POOL_BYTES, stream>>>(ef, evec, lats, g0e, b0e, g1e,
                                                  pWm0, pWc, pWenv, pWp0, pWpv, bp0,
                                                  eidx, perm, ns_ln, nv_ln,
                                                  sa, va);
  k_node_out<<<N_NODES/4, 256, 0, stream>>>(nf, oh, Wtp0, Wtp1, Wo0, bo0, Wov,
                                            resp, sa, va, (float*)d_out);
}

// Round 9
// 619.672 us; speedup vs baseline: 1.1887x; 1.1887x over previous
//
#include <hip/hip_runtime.h>
#include <math.h>

#define N_NODES 16384
#define N_EDGES 262144
#define EPSF 1e-8f

// ---------------- LDS pool layout (bytes), 32 edges/block ----------------
#define OFF_XE    0        // bf16 [32][232] = 14848   (LN 0..63, c0 64..223)
#define OFF_C12   14848    // bf16 [32][328] = 20992 -> 35840
#define OFF_FR    35840    // f16  [32][12]  =   768 -> 36608 (persistent)
#define OFF_EDST  36608    // int  [32]      =   128 -> 36736 (persistent)
#define OFF_ESRC  36736    // int  [32]      =   128 -> 36864 (persistent)
#define POOL_BYTES 36864   // 4 blocks/CU: 4*36864 = 147456 <= 163840
// overlays (after G1/G2 done reading XE/C12)
#define OFF_SACT  0        // bf16 [32][136] = 8704
#define OFF_GATE  8704     // bf16 [32][72]  = 4608 -> 13312
#define OFF_C0O   13312    // bf16 [32][72]  = 4608 -> 17920
#define OFF_C1O   17920    // bf16 [32][72]  = 4608 -> 22528
#define OFF_C2O   22528    // bf16 [32][72]  = 4608 -> 27136
#define OFF_VG    8704     // bf16 [3][32][72] = 13824 -> 22528 (over GATE/C0O/C1O after consumed)
// final overlay: R f16 [32][320] = 20480 at 0 (after SACT/VG consumed)

typedef __bf16 bf16x8 __attribute__((ext_vector_type(8)));
typedef float  f32x4  __attribute__((ext_vector_type(4)));

__device__ __forceinline__ f32x4 MFMA16(bf16x8 a, bf16x8 b, f32x4 c){
  return __builtin_amdgcn_mfma_f32_16x16x32_bf16(a, b, c, 0, 0, 0);
}

__device__ __forceinline__ unsigned f2bf(float x){
  __bf16 h = (__bf16)x;
  union { __bf16 b; unsigned short u; } c; c.b = h;
  return (unsigned)c.u;
}
__device__ __forceinline__ float bf2f(unsigned short h){
  union { unsigned u; float f; } c; c.u = ((unsigned)h)<<16;
  return c.f;
}
__device__ __forceinline__ float wsum32(float v){
  #pragma unroll
  for (int m=1; m<32; m<<=1) v += __shfl_xor(v, m);
  return v;
}
__device__ __forceinline__ float wsum64(float v){
  #pragma unroll
  for (int m=1; m<64; m<<=1) v += __shfl_xor(v, m);
  return v;
}
__device__ __forceinline__ float sigm(float x){ return 1.0f/(1.0f+__expf(-x)); }
__device__ __forceinline__ float silu(float x){ return x/(1.0f+__expf(-x)); }

// ---------------- fused weight pack kernel (B-fragment layout) ----------------
__global__ __launch_bounds__(256) void k_pack_all(
  const float* __restrict__ Wm0, const float* __restrict__ wr,
  const float* __restrict__ wi,  const float* __restrict__ Wenv,
  const float* __restrict__ Wp0, const float* __restrict__ Wpv,
  unsigned short* __restrict__ wpk)
{
  int i = blockIdx.x*256 + threadIdx.x;
  if (i < 122880){                       // Wm0 [480][256]
    int k = i >> 8, n = i & 255;
    int idx = (((k>>5)*256 + n)*4 + ((k>>3)&3))*8 + (k&7);
    wpk[idx] = f2bf(Wm0[i]);
  } else if (i < 163840){                // Wc [320][128] = [[wr,wi],[-wi,wr]]
    int j = i - 122880;
    int k = j >> 7, n = j & 127;
    float v;
    if (k < 160) v = (n < 64) ? wr[k*64 + n]        : wi[k*64 + (n-64)];
    else         v = (n < 64) ? -wi[(k-160)*64 + n] : wr[(k-160)*64 + (n-64)];
    int idx = (((k>>5)*128 + n)*4 + ((k>>3)&3))*8 + (k&7);
    wpk[122880 + idx] = f2bf(v);
  } else if (i < 188416){                // Wenv [128][192]
    int j = i - 163840;
    int k = j / 192, n = j - k*192;
    int idx = (((k>>5)*192 + n)*4 + ((k>>3)&3))*8 + (k&7);
    wpk[163840 + idx] = f2bf(Wenv[j]);
  } else if (i < 204800){                // Wp0 [128][128]
    int j = i - 188416;
    int k = j >> 7, n = j & 127;
    int idx = (((k>>5)*128 + n)*4 + ((k>>3)&3))*8 + (k&7);
    wpk[188416 + idx] = f2bf(Wp0[j]);
  } else if (i < 208896){                // Wpv [64][64]
    int j = i - 204800;
    int k = j >> 6, n = j & 63;
    int idx = (((k>>5)*64 + n)*4 + ((k>>3)&3))*8 + (k&7);
    wpk[204800 + idx] = f2bf(Wpv[j]);
  }
}

// ---------------- CSR build (perm = edges sorted by dst) ----------------
__global__ __launch_bounds__(256) void k_hist(const int* __restrict__ eidx, int* __restrict__ cnt){
  int e = blockIdx.x*256 + threadIdx.x;
  if (e < N_EDGES) atomicAdd(&cnt[eidx[N_EDGES+e]], 1);
}
__global__ __launch_bounds__(256) void k_scan(const int* __restrict__ cnt,
                                              int* __restrict__ rowp, int* __restrict__ cursor){
  __shared__ int part[256];
  __shared__ int pref[257];
  const int t = threadIdx.x;
  const int base = t*64;
  int s = 0;
  for (int i=0;i<64;i++) s += cnt[base+i];
  part[t] = s; __syncthreads();
  if (t==0){ int a=0; for (int i=0;i<256;i++){ pref[i]=a; a+=part[i]; } pref[256]=a; }
  __syncthreads();
  int a = pref[t];
  for (int i=0;i<64;i++){ rowp[base+i]=a; cursor[base+i]=a; a += cnt[base+i]; }
  if (t==0) rowp[N_NODES] = pref[256];
}
__global__ __launch_bounds__(256) void k_fill(const int* __restrict__ eidx,
                                              int* __restrict__ cursor, int* __restrict__ perm){
  int e = blockIdx.x*256 + threadIdx.x;
  if (e < N_EDGES){
    int pos = atomicAdd(&cursor[eidx[N_EDGES+e]], 1);
    perm[pos] = e;
  }
}

// ---------------- Kernel 1: node separable LN (scalars bf16, vectors f16) ----------------
__global__ __launch_bounds__(256) void k_node_ln(
    const float* __restrict__ nf, const float* __restrict__ g0,
    const float* __restrict__ b0, const float* __restrict__ g1,
    unsigned short* __restrict__ ns_ln, _Float16* __restrict__ nv_ln)
{
  const int tid  = threadIdx.x;
  const int lane = tid & 63;
  const int n    = blockIdx.x*4 + (tid>>6);
  const float* row = nf + (size_t)n*320;

  float s0 = row[lane], s1 = row[64+lane];
  float mu = wsum64(s0+s1) * (1.0f/128.0f);
  float d0 = s0-mu, d1 = s1-mu;
  float var = wsum64(d0*d0+d1*d1) * (1.0f/128.0f);
  float rs = rsqrtf(var + EPSF);
  ns_ln[(size_t)n*128 + lane]    = f2bf(d0*rs*g0[lane]    + b0[lane]);
  ns_ln[(size_t)n*128 + 64+lane] = f2bf(d1*rs*g0[64+lane] + b0[64+lane]);

  float px = row[128+lane*3+0], py = row[128+lane*3+1], pz = row[128+lane*3+2];
  float vvar = wsum64(px*px+py*py+pz*pz) * (1.0f/192.0f);
  float vsc = rsqrtf(vvar + EPSF) * g1[lane];
  nv_ln[(size_t)n*192 + lane*3+0] = (_Float16)(px*vsc);
  nv_ln[(size_t)n*192 + lane*3+1] = (_Float16)(py*vsc);
  nv_ln[(size_t)n*192 + lane*3+2] = (_Float16)(pz*vsc);
}

// ---------------- Kernel 1b: w = latents[perm] @ W_env (slot-ordered) ----------------
__global__ __launch_bounds__(256) void k_wenv(
  const float* __restrict__ lats, const unsigned short* __restrict__ pWenv,
  const int* __restrict__ perm, unsigned short* __restrict__ wbuf)
{
  __shared__ unsigned short A[64*136];
  const int tid = threadIdx.x;
  {
    const int row = tid>>2, part = tid&3;
    const int slot = blockIdx.x*64 + row;
    const int e = perm[slot];
    const float* lr = lats + (size_t)e*128 + part*32;
    #pragma unroll
    for (int q=0;q<8;q++){
      float4 v = *(const float4*)(lr + q*4);
      int cb = part*32 + q*4;
      A[row*136 + cb+0] = f2bf(v.x);
      A[row*136 + cb+1] = f2bf(v.y);
      A[row*136 + cb+2] = f2bf(v.z);
      A[row*136 + cb+3] = f2bf(v.w);
    }
  }
  __syncthreads();
  const int wid = tid>>6, l = tid&63, r15 = l&15, g = l>>4;
  const f32x4 zero4 = {0.f,0.f,0.f,0.f};
  f32x4 acc[4][3];
  #pragma unroll
  for (int m=0;m<4;m++)
    #pragma unroll
    for (int n=0;n<3;n++) acc[m][n]=zero4;

  const unsigned short* bbase = pWenv + ((size_t)(wid*48 + r15)*4 + g)*8;
  #pragma unroll
  for (int kc=0;kc<4;kc++){
    bf16x8 b[3];
    #pragma unroll
    for (int n=0;n<3;n++) b[n] = *(const bf16x8*)(bbase + (size_t)kc*6144 + n*512);
    #pragma unroll
    for (int m=0;m<4;m++){
      bf16x8 a = *(const bf16x8*)&A[(m*16+r15)*136 + kc*32 + g*8];
      #pragma unroll
      for (int n=0;n<3;n++) acc[m][n] = MFMA16(a, b[n], acc[m][n]);
    }
  }
  #pragma unroll
  for (int m=0;m<4;m++)
    #pragma unroll
    for (int n=0;n<3;n++)
      #pragma unroll
      for (int r=0;r<4;r++){
        int sr = m*16 + g*4 + r;
        int j  = wid*48 + n*16 + r15;
        wbuf[(size_t)(blockIdx.x*64 + sr)*192 + j] = f2bf(acc[m][n][r]*0.08838834764831845f);
      }
}

// ---------------- Kernel 2: edge message kernel (MFMA, 32 edges/block, slot order) ----------------
__global__ __launch_bounds__(256,4) void k_edge(
  const float* __restrict__ ef, const float* __restrict__ evec,
  const float* __restrict__ g0e, const float* __restrict__ b0e, const float* __restrict__ g1e,
  const unsigned short* __restrict__ pWm0, const unsigned short* __restrict__ pWc,
  const unsigned short* __restrict__ pWp0, const unsigned short* __restrict__ pWpv,
  const float* __restrict__ bp0,
  const int* __restrict__ eidx, const int* __restrict__ perm,
  const unsigned short* __restrict__ ns_ln, const _Float16* __restrict__ nv_ln,
  const unsigned short* __restrict__ wbuf,
  float* __restrict__ sa, float* __restrict__ va)
{
  extern __shared__ unsigned char pool[];
  const int tid = threadIdx.x;
  unsigned short* XE   = (unsigned short*)(pool + OFF_XE);
  unsigned short* C12s = (unsigned short*)(pool + OFF_C12);
  _Float16* FRh = (_Float16*)(pool + OFF_FR);
  int* EDST = (int*)(pool + OFF_EDST);
  int* ESRC = (int*)(pool + OFF_ESRC);

  // XCD-aware swizzle: contiguous slot span per XCD (nwg = 8192, %8 == 0)
  const int nwg = gridDim.x;
  const int bswz = (blockIdx.x & 7)*(nwg>>3) + (blockIdx.x >> 3);

  const int wid = tid>>6, l = tid&63;
  const int r15 = l&15, g = l>>4;
  const int sbase = bswz*32;

  // ---------------- Phase A: prep (4 passes of 8 edges, 32 lanes/edge, vectorized) ----------------
  {
    const int ln = tid & 31;
    #pragma unroll
    for (int eo=0; eo<4; ++eo){
      const int el = eo*8 + (tid>>5);
      const int slot = sbase + el;
      const size_t e = (size_t)perm[slot];
      const int src = eidx[e];
      const int dst = eidx[N_EDGES + e];

      // frame (redundant per lane)
      float vx=evec[e*3+0], vy=evec[e*3+1], vz=evec[e*3+2];
      float rn = rsqrtf(vx*vx+vy*vy+vz*vz+EPSF);
      float ax=vx*rn, ay=vy*rn, az=vz*rn;
      float hx, hz;
      if (fabsf(az) < 0.99f){ hx=0.f; hz=1.f; } else { hx=1.f; hz=0.f; }
      float e1x = -hz*ay;
      float e1y = hz*ax - hx*az;
      float e1z = hx*ay;
      float rn1 = rsqrtf(e1x*e1x+e1y*e1y+e1z*e1z+EPSF);
      e1x*=rn1; e1y*=rn1; e1z*=rn1;
      float e2x = ay*e1z - az*e1y;
      float e2y = az*e1x - ax*e1z;
      float e2z = ax*e1y - ay*e1x;
      if (ln==0){
        FRh[el*12+0]=(_Float16)ax;  FRh[el*12+1]=(_Float16)ay;  FRh[el*12+2]=(_Float16)az;
        FRh[el*12+3]=(_Float16)e1x; FRh[el*12+4]=(_Float16)e1y; FRh[el*12+5]=(_Float16)e1z;
        FRh[el*12+6]=(_Float16)e2x; FRh[el*12+7]=(_Float16)e2y; FRh[el*12+8]=(_Float16)e2z;
        EDST[el]=dst;
        ESRC[el]=src;
      }

      const float* erow = ef + e*160;

      // edge scalar LN: 2 consecutive channels per lane, packed b32 write
      {
        float2 sp = *(const float2*)&erow[2*ln];
        float mu = wsum32(sp.x+sp.y)*(1.f/64.f);
        float d0=sp.x-mu, d1=sp.y-mu;
        float var = wsum32(d0*d0+d1*d1)*(1.f/64.f);
        float rs = rsqrtf(var+EPSF);
        float2 gv = *(const float2*)&g0e[2*ln];
        float2 bv = *(const float2*)&b0e[2*ln];
        unsigned lo = f2bf(d0*rs*gv.x + bv.x);
        unsigned hi = f2bf(d1*rs*gv.y + bv.y);
        *(unsigned*)&XE[el*232 + 2*ln] = lo | (hi<<16);
      }

      // edge-vec channels: lanes 0..7, 4 channels each
      {
        float evb[12];
        float evq = 0.f;
        if (ln < 8){
          float4 p0 = *(const float4*)&erow[64 + ln*12];
          float4 p1 = *(const float4*)&erow[64 + ln*12 + 4];
          float4 p2 = *(const float4*)&erow[64 + ln*12 + 8];
          evb[0]=p0.x; evb[1]=p0.y; evb[2]=p0.z; evb[3]=p0.w;
          evb[4]=p1.x; evb[5]=p1.y; evb[6]=p1.z; evb[7]=p1.w;
          evb[8]=p2.x; evb[9]=p2.y; evb[10]=p2.z; evb[11]=p2.w;
          #pragma unroll
          for (int i=0;i<12;i++) evq += evb[i]*evb[i];
        }
        float vvar = wsum32(evq)*(1.f/96.f);
        float vsce = rsqrtf(vvar+EPSF);
        if (ln < 8){
          unsigned xw[2]={0,0}, c1w[2]={0,0}, c2w[2]={0,0};
          #pragma unroll
          for (int i=0;i<4;i++){
            float s = vsce * g1e[ln*4+i];
            float wx=evb[3*i]*s, wy=evb[3*i+1]*s, wz=evb[3*i+2]*s;
            unsigned c0 = f2bf(wx*ax +wy*ay +wz*az);
            unsigned c1 = f2bf(wx*e1x+wy*e1y+wz*e1z);
            unsigned c2 = f2bf(wx*e2x+wy*e2y+wz*e2z);
            int w = i>>1, sh = (i&1)*16;
            xw[w] |= c0<<sh; c1w[w] |= c1<<sh; c2w[w] |= c2<<sh;
          }
          uint2 xv={xw[0],xw[1]}, c1v={c1w[0],c1w[1]}, c2v={c2w[0],c2w[1]};
          *(uint2*)&XE  [el*232 + 128 + ln*4]      = xv;   // c0 edge channels u=64..95
          *(uint2*)&C12s[el*328 + 64 + ln*4]       = c1v;
          *(uint2*)&C12s[el*328 + 160 + 64 + ln*4] = c2v;
        }
      }

      // node-vector channels: lanes 0..15 src (4 ch each), 16..31 dst
      {
        const int isrc = (ln < 16);
        const int u0 = (ln & 15)*4;
        const int node = isrc ? src : dst;
        const _Float16* nvp = nv_ln + (size_t)node*192 + u0*3;
        _Float16 hh[12];
        *(uint2*)&hh[0] = *(const uint2*)(nvp);
        *(uint2*)&hh[4] = *(const uint2*)(nvp+4);
        *(uint2*)&hh[8] = *(const uint2*)(nvp+8);
        unsigned xw[2]={0,0}, c1w[2]={0,0}, c2w[2]={0,0};
        #pragma unroll
        for (int i=0;i<4;i++){
          float px=(float)hh[3*i], py=(float)hh[3*i+1], pz=(float)hh[3*i+2];
          unsigned c0 = f2bf(px*ax +py*ay +pz*az);
          unsigned c1 = f2bf(px*e1x+py*e1y+pz*e1z);
          unsigned c2 = f2bf(px*e2x+py*e2y+pz*e2z);
          int w = i>>1, sh = (i&1)*16;
          xw[w] |= c0<<sh; c1w[w] |= c1<<sh; c2w[w] |= c2<<sh;
        }
        const int cb = isrc ? u0 : (96 + u0);
        uint2 xv={xw[0],xw[1]}, c1v={c1w[0],c1w[1]}, c2v={c2w[0],c2w[1]};
        *(uint2*)&XE  [el*232 + 64 + cb]  = xv;
        *(uint2*)&C12s[el*328 + cb]       = c1v;
        *(uint2*)&C12s[el*328 + 160 + cb] = c2v;
      }
    }
  }
  __syncthreads();

  const f32x4 zero4 = {0.f,0.f,0.f,0.f};

  // G1: m0 = X[32x480] @ Wm0[480x256]
  f32x4 acc1[2][4];
  #pragma unroll
  for (int m=0;m<2;m++)
    #pragma unroll
    for (int n=0;n<4;n++) acc1[m][n]=zero4;
  {
    const unsigned short* bbase = pWm0 + ((size_t)(wid*64 + r15)*4 + g)*8;
    bf16x8 gA[2][8];
    {
      const int rs0 = ESRC[r15], rs1 = ESRC[16+r15];
      const int rd0 = EDST[r15], rd1 = EDST[16+r15];
      #pragma unroll
      for (int q=0;q<4;q++){
        gA[0][q]   = *(const bf16x8*)&ns_ln[(size_t)rs0*128 + q*32 + g*8];
        gA[1][q]   = *(const bf16x8*)&ns_ln[(size_t)rs1*128 + q*32 + g*8];
        gA[0][4+q] = *(const bf16x8*)&ns_ln[(size_t)rd0*128 + q*32 + g*8];
        gA[1][4+q] = *(const bf16x8*)&ns_ln[(size_t)rd1*128 + q*32 + g*8];
      }
    }
    #pragma unroll
    for (int t=0;t<7;t++){
      const int kc  = (t<2) ? (4+t) : (10 + t-2);
      const int col = (t<2) ? (t*32) : (64 + (t-2)*32);
      bf16x8 a0 = *(const bf16x8*)&XE[(    r15)*232 + col + g*8];
      bf16x8 a1 = *(const bf16x8*)&XE[(16+ r15)*232 + col + g*8];
      const unsigned short* bp = bbase + (size_t)kc*8192;
      #pragma unroll
      for (int n=0;n<4;n++){
        bf16x8 b = *(const bf16x8*)(bp + n*512);
        acc1[0][n] = MFMA16(a0,b,acc1[0][n]);
        acc1[1][n] = MFMA16(a1,b,acc1[1][n]);
      }
    }
    #pragma unroll
    for (int t=0;t<8;t++){
      const int kc = (t<4) ? t : (6 + t-4);
      const unsigned short* bp = bbase + (size_t)kc*8192;
      #pragma unroll
      for (int n=0;n<4;n++){
        bf16x8 b = *(const bf16x8*)(bp + n*512);
        acc1[0][n] = MFMA16(gA[0][t],b,acc1[0][n]);
        acc1[1][n] = MFMA16(gA[1][t],b,acc1[1][n]);
      }
    }
  }

  // G2: c12o = C12[32x320] @ Wc[320x128]
  f32x4 acc2[2][2];
  #pragma unroll
  for (int m=0;m<2;m++){ acc2[m][0]=zero4; acc2[m][1]=zero4; }
  {
    const unsigned short* bbase = pWc + ((size_t)(wid*32 + r15)*4 + g)*8;
    #pragma unroll
    for (int kc=0;kc<10;kc++){
      bf16x8 a0 = *(const bf16x8*)&C12s[(    r15)*328 + kc*32 + g*8];
      bf16x8 a1 = *(const bf16x8*)&C12s[(16+ r15)*328 + kc*32 + g*8];
      const unsigned short* bp = bbase + (size_t)kc*4096;
      #pragma unroll
      for (int n=0;n<2;n++){
        bf16x8 b = *(const bf16x8*)(bp + n*512);
        acc2[0][n] = MFMA16(a0,b,acc2[0][n]);
        acc2[1][n] = MFMA16(a1,b,acc2[1][n]);
      }
    }
  }

  // prefetch epilogue operands (wbuf stream + bias) while barrier drains
  float wsc[2][2][4], wvc[2][4], bp0v[2];
  #pragma unroll
  for (int n=0;n<2;n++) bp0v[n] = bp0[wid*32 + n*16 + r15];
  #pragma unroll
  for (int m=0;m<2;m++)
    #pragma unroll
    for (int r=0;r<4;r++){
      int e = m*16 + g*4 + r;
      #pragma unroll
      for (int n=0;n<2;n++)
        wsc[m][n][r] = bf2f(wbuf[(size_t)(sbase+e)*192 + wid*32 + n*16 + r15]);
      wvc[m][r] = bf2f(wbuf[(size_t)(sbase+e)*192 + 128 + wid*16 + r15]);
    }

  __syncthreads();   // all waves done reading XE/C12

  // G1/G2 epilogues -> overlays (bf16)
  {
    unsigned short* SAs = (unsigned short*)(pool + OFF_SACT);
    unsigned short* GAb = (unsigned short*)(pool + OFF_GATE);
    unsigned short* C0b = (unsigned short*)(pool + OFF_C0O);
    #pragma unroll
    for (int m=0;m<2;m++)
      #pragma unroll
      for (int n=0;n<4;n++)
        #pragma unroll
        for (int r=0;r<4;r++){
          int e = m*16 + g*4 + r;
          int j = wid*64 + n*16 + r15;
          float v = acc1[m][n][r]*0.04564354645876384f;  // 1/sqrt(480)
          if (j < 128)      SAs[e*136 + j] = f2bf(silu(v));
          else if (j < 192) GAb[e*72 + (j-128)] = f2bf(sigm(v));
          else              C0b[e*72 + (j-192)] = f2bf(v);
        }
    unsigned short* C1b = (unsigned short*)(pool + OFF_C1O);
    unsigned short* C2b = (unsigned short*)(pool + OFF_C2O);
    #pragma unroll
    for (int m=0;m<2;m++)
      #pragma unroll
      for (int n=0;n<2;n++)
        #pragma unroll
        for (int r=0;r<4;r++){
          int e = m*16 + g*4 + r;
          int j = wid*32 + n*16 + r15;
          float v = acc2[m][n][r]*0.07905694150420949f;  // 1/sqrt(160)
          if (j < 64) C1b[e*72 + j] = f2bf(v);
          else        C2b[e*72 + (j-64)] = f2bf(v);
        }
  }
  __syncthreads();

  // C1: v_g = (c0o*a + c1o*e1 + c2o*e2)*gate -> VG bf16 (8 u's/thread, packed writes)
  {
    const int e = tid>>3, u0 = (tid&7)*8;
    const unsigned short* GAb = (const unsigned short*)(pool + OFF_GATE);
    const unsigned short* C0b = (const unsigned short*)(pool + OFF_C0O);
    const unsigned short* C1b = (const unsigned short*)(pool + OFF_C1O);
    const unsigned short* C2b = (const unsigned short*)(pool + OFF_C2O);
    float ax=(float)FRh[e*12+0],  ay=(float)FRh[e*12+1],  az=(float)FRh[e*12+2];
    float b1x=(float)FRh[e*12+3], b1y=(float)FRh[e*12+4], b1z=(float)FRh[e*12+5];
    float b2x=(float)FRh[e*12+6], b2y=(float)FRh[e*12+7], b2z=(float)FRh[e*12+8];
    float vgx[8], vgy[8], vgz[8];
    #pragma unroll
    for (int i=0;i<8;i++){
      int u = u0+i;
      float gt = bf2f(GAb[e*72+u]);
      float c0 = bf2f(C0b[e*72+u]), c1 = bf2f(C1b[e*72+u]), c2 = bf2f(C2b[e*72+u]);
      vgx[i] = (c0*ax + c1*b1x + c2*b2x)*gt;
      vgy[i] = (c0*ay + c1*b1y + c2*b2y)*gt;
      vgz[i] = (c0*az + c1*b1z + c2*b2z)*gt;
    }
    __syncthreads();   // GATE/C0O/C1O reads done before VG overlay writes
    unsigned short* VGs = (unsigned short*)(pool + OFF_VG);
    #pragma unroll
    for (int i=0;i<4;i++){
      unsigned wx = f2bf(vgx[2*i]) | (f2bf(vgx[2*i+1])<<16);
      unsigned wy = f2bf(vgy[2*i]) | (f2bf(vgy[2*i+1])<<16);
      unsigned wz = f2bf(vgz[2*i]) | (f2bf(vgz[2*i+1])<<16);
      *(unsigned*)&VGs[0*2304 + e*72 + u0 + 2*i] = wx;
      *(unsigned*)&VGs[1*2304 + e*72 + u0 + 2*i] = wy;
      *(unsigned*)&VGs[2*2304 + e*72 + u0 + 2*i] = wz;
    }
  }
  __syncthreads();

  // G4: s2 = SACT @ Wp0 ; G5: v2c = VG[c] @ Wpv
  {
    const unsigned short* SAs = (const unsigned short*)(pool + OFF_SACT);
    const unsigned short* VGs = (const unsigned short*)(pool + OFF_VG);

    f32x4 acc4[2][2], acc5[3][2];
    #pragma unroll
    for (int m=0;m<2;m++){ acc4[m][0]=zero4; acc4[m][1]=zero4; }
    #pragma unroll
    for (int c=0;c<3;c++){ acc5[c][0]=zero4; acc5[c][1]=zero4; }

    {
      const unsigned short* bbase = pWp0 + ((size_t)(wid*32 + r15)*4 + g)*8;
      #pragma unroll
      for (int kc=0;kc<4;kc++){
        bf16x8 a0 = *(const bf16x8*)&SAs[(    r15)*136 + kc*32 + g*8];
        bf16x8 a1 = *(const bf16x8*)&SAs[(16+ r15)*136 + kc*32 + g*8];
        #pragma unroll
        for (int n=0;n<2;n++){
          bf16x8 b = *(const bf16x8*)(bbase + (size_t)kc*4096 + n*512);
          acc4[0][n] = MFMA16(a0,b,acc4[0][n]);
          acc4[1][n] = MFMA16(a1,b,acc4[1][n]);
        }
      }
    }
    {
      bf16x8 b5[2];
      #pragma unroll
      for (int kc=0;kc<2;kc++)
        b5[kc] = *(const bf16x8*)(pWpv + ((size_t)(kc*64 + wid*16 + r15)*4 + g)*8);
      #pragma unroll
      for (int c=0;c<3;c++)
        #pragma unroll
        for (int kc=0;kc<2;kc++){
          bf16x8 a0 = *(const bf16x8*)&VGs[c*2304 + (    r15)*72 + kc*32 + g*8];
          bf16x8 a1 = *(const bf16x8*)&VGs[c*2304 + (16+ r15)*72 + kc*32 + g*8];
          acc5[c][0] = MFMA16(a0,b5[kc],acc5[c][0]);
          acc5[c][1] = MFMA16(a1,b5[kc],acc5[c][1]);
        }
    }

    __syncthreads();   // all waves done reading SACT/VG before R overlay
    _Float16* R = (_Float16*)pool;   // f16 [32][320]
    #pragma unroll
    for (int m=0;m<2;m++)
      #pragma unroll
      for (int n=0;n<2;n++)
        #pragma unroll
        for (int r=0;r<4;r++){
          int e = m*16 + g*4 + r;
          int j = wid*32 + n*16 + r15;
          R[e*320 + j] = (_Float16)((acc4[m][n][r]*0.08838834764831845f + bp0v[n]) * wsc[m][n][r]);
        }
    #pragma unroll
    for (int c=0;c<3;c++)
      #pragma unroll
      for (int m=0;m<2;m++)
        #pragma unroll
        for (int r=0;r<4;r++){
          int e = m*16 + g*4 + r;
          int vch = wid*16 + r15;
          R[e*320 + 128 + vch*3 + c] = (_Float16)(acc5[c][m][r]*0.125f * wvc[m][r]);
        }
    __syncthreads();

    // segmented reduction over dst runs (slot order => sorted dst), then atomics
    for (int j = tid; j < 320; j += 256){
      float accv = (float)R[j];
      int cur = EDST[0];
      for (int e=1;e<32;e++){
        int d = EDST[e];
        float v = (float)R[e*320 + j];
        if (d != cur){
          float* tgt = (j<128) ? &sa[(size_t)cur*128 + j] : &va[(size_t)cur*192 + (j-128)];
          atomicAdd(tgt, accv);
          accv = v; cur = d;
        } else accv += v;
      }
      float* tgt = (j<128) ? &sa[(size_t)cur*128 + j] : &va[(size_t)cur*192 + (j-128)];
      atomicAdd(tgt, accv);
    }
  }
}

// ---------------- Kernel 3: per-node head + residual ----------------
__global__ __launch_bounds__(256) void k_node_out(
  const float* __restrict__ nf, const float* __restrict__ oh,
  const float* __restrict__ Wtp0, const float* __restrict__ Wtp1,
  const float* __restrict__ Wo0, const float* __restrict__ bo0,
  const float* __restrict__ Wov, const float* __restrict__ resp,
  const float* __restrict__ sa, const float* __restrict__ va,
  float* __restrict__ out)
{
  __shared__ float SAB[4][128];
  __shared__ float VX[4][64], VY[4][64], VZ[4][64];
  __shared__ float S3 [4][128];
  __shared__ float V3 [4][256];
  const int tid=threadIdx.x, lane=tid&63, g=tid>>6;
  const int n = blockIdx.x*4 + g;

  float cf=0.f;
  #pragma unroll
  for (int j=0;j<16;j++) cf += j*oh[(size_t)n*16+j];
  const int c = (int)(cf+0.5f);

  SAB[g][lane]    = sa[(size_t)n*128+lane]   *0.25f;
  SAB[g][64+lane] = sa[(size_t)n*128+64+lane]*0.25f;
  VX[g][lane] = va[(size_t)n*192+lane*3+0]*0.25f;
  VY[g][lane] = va[(size_t)n*192+lane*3+1]*0.25f;
  VZ[g][lane] = va[(size_t)n*192+lane*3+2]*0.25f;
  __syncthreads();

  float t00=0.f, t01=0.f, t02=0.f;
  const float* w0c = Wtp0 + (size_t)c*192;
  for (int u=0;u<128;u++){
    float s = SAB[g][u];
    t00 += s * w0c[(size_t)u*3072 + lane];
    t01 += s * w0c[(size_t)u*3072 + lane+64];
    t02 += s * w0c[(size_t)u*3072 + lane+128];
  }
  const float sct0 = 0.02209708691f; // 1/sqrt(2048)
  t00*=sct0; t01*=sct0; t02*=sct0;

  float t1x=0.f,t1y=0.f,t1z=0.f;
  const float* w1c = Wtp1 + (size_t)c*64;
  for (int u=0;u<64;u++){
    float wv = w1c[(size_t)u*1024 + lane];
    t1x += VX[g][u]*wv;
    t1y += VY[g][u]*wv;
    t1z += VZ[g][u]*wv;
  }
  t1x*=0.03125f; t1y*=0.03125f; t1z*=0.03125f;

  S3[g][lane]    = silu(t00);
  S3[g][64+lane] = silu(t01);
  float g2 = sigm(t02);
  float4 v3v = {t1x*g2, t1y*g2, t1z*g2, 0.f};
  *(float4*)&V3[g][lane*4] = v3v;
  __syncthreads();

  float s40=0.f, s41=0.f;
  for (int k=0;k<128;k++){
    float s3k = S3[g][k];
    s40 += s3k*Wo0[k*128+lane];
    s41 += s3k*Wo0[k*128+64+lane];
  }
  s40 = s40*0.08838834765f + bo0[lane];
  s41 = s41*0.08838834765f + bo0[64+lane];

  float v4x=0.f,v4y=0.f,v4z=0.f;
  for (int u=0;u<64;u++){
    float4 v3u = *(const float4*)&V3[g][u*4];
    float wv = Wov[u*64+lane];
    v4x += v3u.x*wv; v4y += v3u.y*wv; v4z += v3u.z*wv;
  }
  v4x*=0.125f; v4y*=0.125f; v4z*=0.125f;

  const float r = sigm(resp[0]);
  const float* row = nf + (size_t)n*320;
  float* orow = out + (size_t)n*320;
  orow[lane]      = r*row[lane]      + (1.f-r)*s40;
  orow[64+lane]   = r*row[64+lane]   + (1.f-r)*s41;
  orow[128+lane*3+0] = r*row[128+lane*3+0] + (1.f-r)*v4x;
  orow[128+lane*3+1] = r*row[128+lane*3+1] + (1.f-r)*v4y;
  orow[128+lane*3+2] = r*row[128+lane*3+2] + (1.f-r)*v4z;
}

extern "C" void kernel_launch(void* const* d_in, const int* in_sizes, int n_in,
                              void* d_out, int out_size, void* d_ws, size_t ws_size,
                              hipStream_t stream)
{
  const float* nf   = (const float*)d_in[0];
  const float* ef   = (const float*)d_in[1];
  const float* evec = (const float*)d_in[2];
  const float* lats = (const float*)d_in[3];
  const float* oh   = (const float*)d_in[4];
  const float* g0n  = (const float*)d_in[5];
  const float* b0n  = (const float*)d_in[6];
  const float* g1n  = (const float*)d_in[7];
  const float* g0e  = (const float*)d_in[8];
  const float* b0e  = (const float*)d_in[9];
  const float* g1e  = (const float*)d_in[10];
  const float* Wm0  = (const float*)d_in[11];
  const float* wr   = (const float*)d_in[12];
  const float* wi   = (const float*)d_in[13];
  const float* Wenv = (const float*)d_in[14];
  const float* Wp0  = (const float*)d_in[15];
  const float* bp0  = (const float*)d_in[16];
  const float* Wpv  = (const float*)d_in[17];
  const float* Wtp0 = (const float*)d_in[18];
  const float* Wtp1 = (const float*)d_in[19];
  const float* Wo0  = (const float*)d_in[20];
  const float* bo0  = (const float*)d_in[21];
  const float* Wov  = (const float*)d_in[22];
  const float* resp = (const float*)d_in[23];
  const int*   eidx = (const int*)d_in[24];

  char* base = (char*)d_ws;
  unsigned short* ns_ln = (unsigned short*)(base);            // 4,194,304 B
  _Float16* nv_ln = (_Float16*)(base + 4194304);              // 6,291,456 -> 10,485,760
  float* sa    = (float*)(base + 10485760);                   // 8,388,608 -> 18,874,368
  float* va    = (float*)(base + 18874368);                   // 12,582,912 -> 31,457,280
  unsigned short* wpk = (unsigned short*)(base + 31457280);   // 417,792   -> 31,875,072
  unsigned short* pWm0  = wpk;            // 480*256
  unsigned short* pWc   = wpk + 122880;   // 320*128
  unsigned short* pWenv = wpk + 163840;   // 128*192
  unsigned short* pWp0  = wpk + 188416;   // 128*128
  unsigned short* pWpv  = wpk + 204800;   //  64*64
  int* ibuf   = (int*)(base + 31875072);                      // 311,297 ints
  int* cnt    = ibuf;
  int* rowp   = ibuf + 16384;
  int* cursor = ibuf + 32769;
  int* perm   = ibuf + 49153;
  unsigned short* wbuf = (unsigned short*)(base + 33120264);  // E*192*2 = 100,663,296

  hipMemsetAsync(sa, 0, (size_t)N_NODES*320*sizeof(float), stream);
  hipMemsetAsync(cnt, 0, N_NODES*sizeof(int), stream);

  k_pack_all<<<(208896+255)/256, 256, 0, stream>>>(Wm0, wr, wi, Wenv, Wp0, Wpv, wpk);
  k_node_ln<<<N_NODES/4, 256, 0, stream>>>(nf, g0n, b0n, g1n, ns_ln, nv_ln);

  k_hist<<<(N_EDGES+255)/256, 256, 0, stream>>>(eidx, cnt);
  k_scan<<<1, 256, 0, stream>>>(cnt, rowp, cursor);
  k_fill<<<(N_EDGES+255)/256, 256, 0, stream>>>(eidx, cursor, perm);

  k_wenv<<<N_EDGES/64, 256, 0, stream>>>(lats, pWenv, perm, wbuf);

  k_edge<<<N_EDGES/32, 256, POOL_BYTES, stream>>>(ef, evec, g0e, b0e, g1e,
                                                  pWm0, pWc, pWp0, pWpv, bp0,
                                                  eidx, perm, ns_ln, nv_ln, wbuf,
                                                  sa, va);
  k_node_out<<<N_NODES/4, 256, 0, stream>>>(nf, oh, Wtp0, Wtp1, Wo0, bo0, Wov,
                                            resp, sa, va, (float*)d_out);
}

// Round 10
// 612.023 us; speedup vs baseline: 1.2036x; 1.0125x over previous
//
#include <hip/hip_runtime.h>
#include <math.h>

#define N_NODES 16384
#define N_EDGES 262144
#define EPSF 1e-8f

// ---------------- LDS pool layout (bytes), 32 edges/block ----------------
#define OFF_XE    0        // bf16 [32][232] = 14848   (LN 0..63, c0 64..223)
#define OFF_C12   14848    // bf16 [32][328] = 20992 -> 35840
#define OFF_FR    35840    // f16  [32][12]  =   768 -> 36608 (persistent)
#define OFF_EDST  36608    // int  [32]      =   128 -> 36736 (persistent)
#define OFF_ESRC  36736    // int  [32]      =   128 -> 36864 (persistent)
#define POOL_BYTES 36864
// overlays (after G1/G2 done reading XE/C12)
#define OFF_SACT  0        // bf16 [32][136] = 8704
#define OFF_GATE  8704     // bf16 [32][72]  = 4608 -> 13312
#define OFF_C0O   13312    // bf16 [32][72]  = 4608 -> 17920
#define OFF_C1O   17920    // bf16 [32][72]  = 4608 -> 22528
#define OFF_C2O   22528    // bf16 [32][72]  = 4608 -> 27136
#define OFF_VG    8704     // bf16 [3][32][72] = 13824 -> 22528 (over GATE/C0O/C1O after consumed)
// final overlay: R f16 [32][320] = 20480 at 0 (after SACT/VG consumed)

typedef __bf16 bf16x8 __attribute__((ext_vector_type(8)));
typedef float  f32x4  __attribute__((ext_vector_type(4)));

__device__ __forceinline__ f32x4 MFMA16(bf16x8 a, bf16x8 b, f32x4 c){
  return __builtin_amdgcn_mfma_f32_16x16x32_bf16(a, b, c, 0, 0, 0);
}

__device__ __forceinline__ unsigned short f2bf(float x){
  __bf16 h = (__bf16)x;
  union { __bf16 b; unsigned short u; } c; c.b = h;
  return c.u;
}
__device__ __forceinline__ float bf2f(unsigned short h){
  union { unsigned u; float f; } c; c.u = ((unsigned)h)<<16;
  return c.f;
}
__device__ __forceinline__ float wsum32(float v){
  #pragma unroll
  for (int m=1; m<32; m<<=1) v += __shfl_xor(v, m);
  return v;
}
__device__ __forceinline__ float wsum64(float v){
  #pragma unroll
  for (int m=1; m<64; m<<=1) v += __shfl_xor(v, m);
  return v;
}
__device__ __forceinline__ float sigm(float x){ return 1.0f/(1.0f+__expf(-x)); }
__device__ __forceinline__ float silu(float x){ return x/(1.0f+__expf(-x)); }

// ---------------- fused weight pack kernel (B-fragment layout) ----------------
__global__ __launch_bounds__(256) void k_pack_all(
  const float* __restrict__ Wm0, const float* __restrict__ wr,
  const float* __restrict__ wi,  const float* __restrict__ Wenv,
  const float* __restrict__ Wp0, const float* __restrict__ Wpv,
  unsigned short* __restrict__ wpk)
{
  int i = blockIdx.x*256 + threadIdx.x;
  if (i < 122880){                       // Wm0 [480][256]
    int k = i >> 8, n = i & 255;
    int idx = (((k>>5)*256 + n)*4 + ((k>>3)&3))*8 + (k&7);
    wpk[idx] = f2bf(Wm0[i]);
  } else if (i < 163840){                // Wc [320][128] = [[wr,wi],[-wi,wr]]
    int j = i - 122880;
    int k = j >> 7, n = j & 127;
    float v;
    if (k < 160) v = (n < 64) ? wr[k*64 + n]        : wi[k*64 + (n-64)];
    else         v = (n < 64) ? -wi[(k-160)*64 + n] : wr[(k-160)*64 + (n-64)];
    int idx = (((k>>5)*128 + n)*4 + ((k>>3)&3))*8 + (k&7);
    wpk[122880 + idx] = f2bf(v);
  } else if (i < 188416){                // Wenv [128][192]
    int j = i - 163840;
    int k = j / 192, n = j - k*192;
    int idx = (((k>>5)*192 + n)*4 + ((k>>3)&3))*8 + (k&7);
    wpk[163840 + idx] = f2bf(Wenv[j]);
  } else if (i < 204800){                // Wp0 [128][128]
    int j = i - 188416;
    int k = j >> 7, n = j & 127;
    int idx = (((k>>5)*128 + n)*4 + ((k>>3)&3))*8 + (k&7);
    wpk[188416 + idx] = f2bf(Wp0[j]);
  } else if (i < 208896){                // Wpv [64][64]
    int j = i - 204800;
    int k = j >> 6, n = j & 63;
    int idx = (((k>>5)*64 + n)*4 + ((k>>3)&3))*8 + (k&7);
    wpk[204800 + idx] = f2bf(Wpv[j]);
  }
}

// ---------------- CSR build (perm = edges sorted by dst) ----------------
__global__ __launch_bounds__(256) void k_hist(const int* __restrict__ eidx, int* __restrict__ cnt){
  int e = blockIdx.x*256 + threadIdx.x;
  if (e < N_EDGES) atomicAdd(&cnt[eidx[N_EDGES+e]], 1);
}
__global__ __launch_bounds__(256) void k_scan(const int* __restrict__ cnt,
                                              int* __restrict__ rowp, int* __restrict__ cursor){
  __shared__ int part[256];
  __shared__ int pref[257];
  const int t = threadIdx.x;
  const int base = t*64;
  int s = 0;
  for (int i=0;i<64;i++) s += cnt[base+i];
  part[t] = s; __syncthreads();
  if (t==0){ int a=0; for (int i=0;i<256;i++){ pref[i]=a; a+=part[i]; } pref[256]=a; }
  __syncthreads();
  int a = pref[t];
  for (int i=0;i<64;i++){ rowp[base+i]=a; cursor[base+i]=a; a += cnt[base+i]; }
  if (t==0) rowp[N_NODES] = pref[256];
}
__global__ __launch_bounds__(256) void k_fill(const int* __restrict__ eidx,
                                              int* __restrict__ cursor, int* __restrict__ perm){
  int e = blockIdx.x*256 + threadIdx.x;
  if (e < N_EDGES){
    int pos = atomicAdd(&cursor[eidx[N_EDGES+e]], 1);
    perm[pos] = e;
  }
}

// ---------------- Kernel 1: node separable LN (scalars bf16, vectors f16) ----------------
__global__ __launch_bounds__(256) void k_node_ln(
    const float* __restrict__ nf, const float* __restrict__ g0,
    const float* __restrict__ b0, const float* __restrict__ g1,
    unsigned short* __restrict__ ns_ln, _Float16* __restrict__ nv_ln)
{
  const int tid  = threadIdx.x;
  const int lane = tid & 63;
  const int n    = blockIdx.x*4 + (tid>>6);
  const float* row = nf + (size_t)n*320;

  float s0 = row[lane], s1 = row[64+lane];
  float mu = wsum64(s0+s1) * (1.0f/128.0f);
  float d0 = s0-mu, d1 = s1-mu;
  float var = wsum64(d0*d0+d1*d1) * (1.0f/128.0f);
  float rs = rsqrtf(var + EPSF);
  ns_ln[(size_t)n*128 + lane]    = f2bf(d0*rs*g0[lane]    + b0[lane]);
  ns_ln[(size_t)n*128 + 64+lane] = f2bf(d1*rs*g0[64+lane] + b0[64+lane]);

  float px = row[128+lane*3+0], py = row[128+lane*3+1], pz = row[128+lane*3+2];
  float vvar = wsum64(px*px+py*py+pz*pz) * (1.0f/192.0f);
  float vsc = rsqrtf(vvar + EPSF) * g1[lane];
  nv_ln[(size_t)n*192 + lane*3+0] = (_Float16)(px*vsc);
  nv_ln[(size_t)n*192 + lane*3+1] = (_Float16)(py*vsc);
  nv_ln[(size_t)n*192 + lane*3+2] = (_Float16)(pz*vsc);
}

// ---------------- Kernel 1b: w = latents[perm] @ W_env (slot-ordered) ----------------
__global__ __launch_bounds__(256) void k_wenv(
  const float* __restrict__ lats, const unsigned short* __restrict__ pWenv,
  const int* __restrict__ perm, unsigned short* __restrict__ wbuf)
{
  __shared__ unsigned short A[64*136];
  const int tid = threadIdx.x;
  {
    const int row = tid>>2, part = tid&3;
    const int slot = blockIdx.x*64 + row;
    const int e = perm[slot];
    const float* lr = lats + (size_t)e*128 + part*32;
    #pragma unroll
    for (int q=0;q<8;q++){
      float4 v = *(const float4*)(lr + q*4);
      int cb = part*32 + q*4;
      A[row*136 + cb+0] = f2bf(v.x);
      A[row*136 + cb+1] = f2bf(v.y);
      A[row*136 + cb+2] = f2bf(v.z);
      A[row*136 + cb+3] = f2bf(v.w);
    }
  }
  __syncthreads();
  const int wid = tid>>6, l = tid&63, r15 = l&15, g = l>>4;
  const f32x4 zero4 = {0.f,0.f,0.f,0.f};
  f32x4 acc[4][3];
  #pragma unroll
  for (int m=0;m<4;m++)
    #pragma unroll
    for (int n=0;n<3;n++) acc[m][n]=zero4;

  const unsigned short* bbase = pWenv + ((size_t)(wid*48 + r15)*4 + g)*8;
  #pragma unroll
  for (int kc=0;kc<4;kc++){
    bf16x8 b[3];
    #pragma unroll
    for (int n=0;n<3;n++) b[n] = *(const bf16x8*)(bbase + (size_t)kc*6144 + n*512);
    #pragma unroll
    for (int m=0;m<4;m++){
      bf16x8 a = *(const bf16x8*)&A[(m*16+r15)*136 + kc*32 + g*8];
      #pragma unroll
      for (int n=0;n<3;n++) acc[m][n] = MFMA16(a, b[n], acc[m][n]);
    }
  }
  #pragma unroll
  for (int m=0;m<4;m++)
    #pragma unroll
    for (int n=0;n<3;n++)
      #pragma unroll
      for (int r=0;r<4;r++){
        int sr = m*16 + g*4 + r;
        int j  = wid*48 + n*16 + r15;
        wbuf[(size_t)(blockIdx.x*64 + sr)*192 + j] = f2bf(acc[m][n][r]*0.08838834764831845f);
      }
}

// ---------------- Kernel 2: edge message kernel (MFMA, 32 edges/block, slot order) ----------------
__global__ __launch_bounds__(256,3) void k_edge(
  const float* __restrict__ ef, const float* __restrict__ evec,
  const float* __restrict__ g0e, const float* __restrict__ b0e, const float* __restrict__ g1e,
  const unsigned short* __restrict__ pWm0, const unsigned short* __restrict__ pWc,
  const unsigned short* __restrict__ pWp0, const unsigned short* __restrict__ pWpv,
  const float* __restrict__ bp0,
  const int* __restrict__ eidx, const int* __restrict__ perm,
  const unsigned short* __restrict__ ns_ln, const _Float16* __restrict__ nv_ln,
  const unsigned short* __restrict__ wbuf,
  float* __restrict__ sa, float* __restrict__ va)
{
  extern __shared__ unsigned char pool[];
  const int tid = threadIdx.x;
  unsigned short* XE   = (unsigned short*)(pool + OFF_XE);
  unsigned short* C12s = (unsigned short*)(pool + OFF_C12);
  _Float16* FRh = (_Float16*)(pool + OFF_FR);
  int* EDST = (int*)(pool + OFF_EDST);
  int* ESRC = (int*)(pool + OFF_ESRC);

  // XCD-aware swizzle: contiguous slot span per XCD (nwg = 8192, %8 == 0)
  const int nwg = gridDim.x;
  const int bswz = (blockIdx.x & 7)*(nwg>>3) + (blockIdx.x >> 3);

  const int wid = tid>>6, l = tid&63;
  const int r15 = l&15, g = l>>4;
  const int sbase = bswz*32;

  // ---------------- Phase A: prep (4 passes of 8 edges, 32 lanes/edge) ----------------
  {
    const int ln = tid & 31;
    #pragma unroll
    for (int eo=0; eo<4; ++eo){
      const int el = eo*8 + (tid>>5);
      const int slot = sbase + el;
      const size_t e = (size_t)perm[slot];
      const int src = eidx[e];
      const int dst = eidx[N_EDGES + e];

      float vx=evec[e*3+0], vy=evec[e*3+1], vz=evec[e*3+2];
      float rn = rsqrtf(vx*vx+vy*vy+vz*vz+EPSF);
      float ax=vx*rn, ay=vy*rn, az=vz*rn;
      float hx, hz;
      if (fabsf(az) < 0.99f){ hx=0.f; hz=1.f; } else { hx=1.f; hz=0.f; }
      float e1x = -hz*ay;
      float e1y = hz*ax - hx*az;
      float e1z = hx*ay;
      float rn1 = rsqrtf(e1x*e1x+e1y*e1y+e1z*e1z+EPSF);
      e1x*=rn1; e1y*=rn1; e1z*=rn1;
      float e2x = ay*e1z - az*e1y;
      float e2y = az*e1x - ax*e1z;
      float e2z = ax*e1y - ay*e1x;
      if (ln==0){
        FRh[el*12+0]=(_Float16)ax;  FRh[el*12+1]=(_Float16)ay;  FRh[el*12+2]=(_Float16)az;
        FRh[el*12+3]=(_Float16)e1x; FRh[el*12+4]=(_Float16)e1y; FRh[el*12+5]=(_Float16)e1z;
        FRh[el*12+6]=(_Float16)e2x; FRh[el*12+7]=(_Float16)e2y; FRh[el*12+8]=(_Float16)e2z;
        EDST[el]=dst;
        ESRC[el]=src;
      }

      const float* erow = ef + e*160;
      float s0=erow[ln], s1=erow[32+ln];
      float mu = wsum32(s0+s1)*(1.f/64.f);
      float d0=s0-mu, d1=s1-mu;
      float var = wsum32(d0*d0+d1*d1)*(1.f/64.f);
      float rs = rsqrtf(var+EPSF);
      XE[el*232 + ln]    = f2bf(d0*rs*g0e[ln]    + b0e[ln]);
      XE[el*232 + 32+ln] = f2bf(d1*rs*g0e[32+ln] + b0e[32+ln]);

      float wx=erow[64+ln*3+0], wy=erow[64+ln*3+1], wz=erow[64+ln*3+2];
      float vvar = wsum32(wx*wx+wy*wy+wz*wz)*(1.f/96.f);
      float vsc = rsqrtf(vvar+EPSF)*g1e[ln];
      wx*=vsc; wy*=vsc; wz*=vsc;
      XE  [el*232 + 64+64+ln]    = f2bf(wx*ax +wy*ay +wz*az);
      C12s[el*328 + 64+ln]       = f2bf(wx*e1x+wy*e1y+wz*e1z);
      C12s[el*328 + 160+64+ln]   = f2bf(wx*e2x+wy*e2y+wz*e2z);

      const _Float16* nvs = nv_ln + (size_t)src*192;
      const _Float16* nvd = nv_ln + (size_t)dst*192;
      #pragma unroll
      for (int q=0;q<2;q++){
        int u = ln+32*q;
        float px=(float)nvs[u*3+0], py=(float)nvs[u*3+1], pz=(float)nvs[u*3+2];
        XE  [el*232 + 64+u]      = f2bf(px*ax +py*ay +pz*az);
        C12s[el*328 + u]         = f2bf(px*e1x+py*e1y+pz*e1z);
        C12s[el*328 + 160+u]     = f2bf(px*e2x+py*e2y+pz*e2z);
        px=(float)nvd[u*3+0]; py=(float)nvd[u*3+1]; pz=(float)nvd[u*3+2];
        XE  [el*232 + 64+96+u]   = f2bf(px*ax +py*ay +pz*az);
        C12s[el*328 + 96+u]      = f2bf(px*e1x+py*e1y+pz*e1z);
        C12s[el*328 + 160+96+u]  = f2bf(px*e2x+py*e2y+pz*e2z);
      }
    }
  }
  __syncthreads();

  const f32x4 zero4 = {0.f,0.f,0.f,0.f};

  // G1: m0 = X[32x480] @ Wm0[480x256] with 3-deep B prefetch + early gA issue
  f32x4 acc1[2][4];
  #pragma unroll
  for (int m=0;m<2;m++)
    #pragma unroll
    for (int n=0;n<4;n++) acc1[m][n]=zero4;
  {
    const unsigned short* bbase = pWm0 + ((size_t)(wid*64 + r15)*4 + g)*8;
    // issue all 16 global A-fragment gathers up front (consumed from t=7 onward)
    bf16x8 gA[2][8];
    {
      const int rs0 = ESRC[r15], rs1 = ESRC[16+r15];
      const int rd0 = EDST[r15], rd1 = EDST[16+r15];
      #pragma unroll
      for (int q=0;q<4;q++){
        gA[0][q]   = *(const bf16x8*)&ns_ln[(size_t)rs0*128 + q*32 + g*8];
        gA[1][q]   = *(const bf16x8*)&ns_ln[(size_t)rs1*128 + q*32 + g*8];
        gA[0][4+q] = *(const bf16x8*)&ns_ln[(size_t)rd0*128 + q*32 + g*8];
        gA[1][4+q] = *(const bf16x8*)&ns_ln[(size_t)rd1*128 + q*32 + g*8];
      }
    }
    // kc schedule: LDS-sourced first, then global-A
    const int kcs[15] = {4,5,10,11,12,13,14, 0,1,2,3, 6,7,8,9};
    bf16x8 B[3][4];
    #pragma unroll
    for (int d=0; d<3; d++){
      const unsigned short* bp = bbase + (size_t)kcs[d]*8192;
      #pragma unroll
      for (int n=0;n<4;n++) B[d][n] = *(const bf16x8*)(bp + n*512);
    }
    __builtin_amdgcn_sched_barrier(0);   // pin gA + initial B issue before compute

    #pragma unroll
    for (int t=0;t<15;t++){
      bf16x8 a0, a1;
      if (t<7){
        const int col = (t<2) ? (t*32) : (64 + (t-2)*32);
        a0 = *(const bf16x8*)&XE[(    r15)*232 + col + g*8];
        a1 = *(const bf16x8*)&XE[(16+ r15)*232 + col + g*8];
      } else {
        a0 = gA[0][t-7];
        a1 = gA[1][t-7];
      }
      const int d = t % 3;
      #pragma unroll
      for (int n=0;n<4;n++){
        acc1[0][n] = MFMA16(a0,B[d][n],acc1[0][n]);
        acc1[1][n] = MFMA16(a1,B[d][n],acc1[1][n]);
      }
      if (t+3 < 15){
        const unsigned short* bp = bbase + (size_t)kcs[t+3]*8192;
        #pragma unroll
        for (int n=0;n<4;n++) B[d][n] = *(const bf16x8*)(bp + n*512);
      }
    }
  }

  // G2: c12o = C12[32x320] @ Wc[320x128] with 3-deep B prefetch
  f32x4 acc2[2][2];
  #pragma unroll
  for (int m=0;m<2;m++){ acc2[m][0]=zero4; acc2[m][1]=zero4; }
  {
    const unsigned short* bbase = pWc + ((size_t)(wid*32 + r15)*4 + g)*8;
    bf16x8 B2[3][2];
    #pragma unroll
    for (int d=0; d<3; d++){
      #pragma unroll
      for (int n=0;n<2;n++) B2[d][n] = *(const bf16x8*)(bbase + (size_t)d*4096 + n*512);
    }
    #pragma unroll
    for (int kc=0;kc<10;kc++){
      bf16x8 a0 = *(const bf16x8*)&C12s[(    r15)*328 + kc*32 + g*8];
      bf16x8 a1 = *(const bf16x8*)&C12s[(16+ r15)*328 + kc*32 + g*8];
      const int d = kc % 3;
      #pragma unroll
      for (int n=0;n<2;n++){
        acc2[0][n] = MFMA16(a0,B2[d][n],acc2[0][n]);
        acc2[1][n] = MFMA16(a1,B2[d][n],acc2[1][n]);
      }
      if (kc+3 < 10){
        const unsigned short* bp = bbase + (size_t)(kc+3)*4096;
        #pragma unroll
        for (int n=0;n<2;n++) B2[d][n] = *(const bf16x8*)(bp + n*512);
      }
    }
  }

  // prefetch epilogue operands (wbuf stream + bias) while barrier drains
  float wsc[2][2][4], wvc[2][4], bp0v[2];
  #pragma unroll
  for (int n=0;n<2;n++) bp0v[n] = bp0[wid*32 + n*16 + r15];
  #pragma unroll
  for (int m=0;m<2;m++)
    #pragma unroll
    for (int r=0;r<4;r++){
      int e = m*16 + g*4 + r;
      #pragma unroll
      for (int n=0;n<2;n++)
        wsc[m][n][r] = bf2f(wbuf[(size_t)(sbase+e)*192 + wid*32 + n*16 + r15]);
      wvc[m][r] = bf2f(wbuf[(size_t)(sbase+e)*192 + 128 + wid*16 + r15]);
    }

  __syncthreads();   // all waves done reading XE/C12

  // G1/G2 epilogues -> overlays (bf16)
  {
    unsigned short* SAs = (unsigned short*)(pool + OFF_SACT);
    unsigned short* GAb = (unsigned short*)(pool + OFF_GATE);
    unsigned short* C0b = (unsigned short*)(pool + OFF_C0O);
    #pragma unroll
    for (int m=0;m<2;m++)
      #pragma unroll
      for (int n=0;n<4;n++)
        #pragma unroll
        for (int r=0;r<4;r++){
          int e = m*16 + g*4 + r;
          int j = wid*64 + n*16 + r15;
          float v = acc1[m][n][r]*0.04564354645876384f;  // 1/sqrt(480)
          if (j < 128)      SAs[e*136 + j] = f2bf(silu(v));
          else if (j < 192) GAb[e*72 + (j-128)] = f2bf(sigm(v));
          else              C0b[e*72 + (j-192)] = f2bf(v);
        }
    unsigned short* C1b = (unsigned short*)(pool + OFF_C1O);
    unsigned short* C2b = (unsigned short*)(pool + OFF_C2O);
    #pragma unroll
    for (int m=0;m<2;m++)
      #pragma unroll
      for (int n=0;n<2;n++)
        #pragma unroll
        for (int r=0;r<4;r++){
          int e = m*16 + g*4 + r;
          int j = wid*32 + n*16 + r15;
          float v = acc2[m][n][r]*0.07905694150420949f;  // 1/sqrt(160)
          if (j < 64) C1b[e*72 + j] = f2bf(v);
          else        C2b[e*72 + (j-64)] = f2bf(v);
        }
  }
  __syncthreads();

  // C1: v_g = (c0o*a + c1o*e1 + c2o*e2)*gate -> VG bf16 (8 u's/thread)
  {
    const int e = tid>>3, u0 = (tid&7)*8;
    const unsigned short* GAb = (const unsigned short*)(pool + OFF_GATE);
    const unsigned short* C0b = (const unsigned short*)(pool + OFF_C0O);
    const unsigned short* C1b = (const unsigned short*)(pool + OFF_C1O);
    const unsigned short* C2b = (const unsigned short*)(pool + OFF_C2O);
    float ax=(float)FRh[e*12+0],  ay=(float)FRh[e*12+1],  az=(float)FRh[e*12+2];
    float b1x=(float)FRh[e*12+3], b1y=(float)FRh[e*12+4], b1z=(float)FRh[e*12+5];
    float b2x=(float)FRh[e*12+6], b2y=(float)FRh[e*12+7], b2z=(float)FRh[e*12+8];
    float vgx[8], vgy[8], vgz[8];
    #pragma unroll
    for (int i=0;i<8;i++){
      int u = u0+i;
      float gt = bf2f(GAb[e*72+u]);
      float c0 = bf2f(C0b[e*72+u]), c1 = bf2f(C1b[e*72+u]), c2 = bf2f(C2b[e*72+u]);
      vgx[i] = (c0*ax + c1*b1x + c2*b2x)*gt;
      vgy[i] = (c0*ay + c1*b1y + c2*b2y)*gt;
      vgz[i] = (c0*az + c1*b1z + c2*b2z)*gt;
    }
    __syncthreads();   // GATE/C0O/C1O reads done before VG overlay writes
    unsigned short* VGs = (unsigned short*)(pool + OFF_VG);
    #pragma unroll
    for (int i=0;i<8;i++){
      VGs[0*2304 + e*72 + u0+i] = f2bf(vgx[i]);
      VGs[1*2304 + e*72 + u0+i] = f2bf(vgy[i]);
      VGs[2*2304 + e*72 + u0+i] = f2bf(vgz[i]);
    }
  }
  __syncthreads();

  // G4: s2 = SACT @ Wp0 ; G5: v2c = VG[c] @ Wpv
  {
    const unsigned short* SAs = (const unsigned short*)(pool + OFF_SACT);
    const unsigned short* VGs = (const unsigned short*)(pool + OFF_VG);

    f32x4 acc4[2][2], acc5[3][2];
    #pragma unroll
    for (int m=0;m<2;m++){ acc4[m][0]=zero4; acc4[m][1]=zero4; }
    #pragma unroll
    for (int c=0;c<3;c++){ acc5[c][0]=zero4; acc5[c][1]=zero4; }

    {
      const unsigned short* bbase = pWp0 + ((size_t)(wid*32 + r15)*4 + g)*8;
      #pragma unroll
      for (int kc=0;kc<4;kc++){
        bf16x8 a0 = *(const bf16x8*)&SAs[(    r15)*136 + kc*32 + g*8];
        bf16x8 a1 = *(const bf16x8*)&SAs[(16+ r15)*136 + kc*32 + g*8];
        #pragma unroll
        for (int n=0;n<2;n++){
          bf16x8 b = *(const bf16x8*)(bbase + (size_t)kc*4096 + n*512);
          acc4[0][n] = MFMA16(a0,b,acc4[0][n]);
          acc4[1][n] = MFMA16(a1,b,acc4[1][n]);
        }
      }
    }
    {
      bf16x8 b5[2];
      #pragma unroll
      for (int kc=0;kc<2;kc++)
        b5[kc] = *(const bf16x8*)(pWpv + ((size_t)(kc*64 + wid*16 + r15)*4 + g)*8);
      #pragma unroll
      for (int c=0;c<3;c++)
        #pragma unroll
        for (int kc=0;kc<2;kc++){
          bf16x8 a0 = *(const bf16x8*)&VGs[c*2304 + (    r15)*72 + kc*32 + g*8];
          bf16x8 a1 = *(const bf16x8*)&VGs[c*2304 + (16+ r15)*72 + kc*32 + g*8];
          acc5[c][0] = MFMA16(a0,b5[kc],acc5[c][0]);
          acc5[c][1] = MFMA16(a1,b5[kc],acc5[c][1]);
        }
    }

    __syncthreads();   // all waves done reading SACT/VG before R overlay
    _Float16* R = (_Float16*)pool;   // f16 [32][320]
    #pragma unroll
    for (int m=0;m<2;m++)
      #pragma unroll
      for (int n=0;n<2;n++)
        #pragma unroll
        for (int r=0;r<4;r++){
          int e = m*16 + g*4 + r;
          int j = wid*32 + n*16 + r15;
          R[e*320 + j] = (_Float16)((acc4[m][n][r]*0.08838834764831845f + bp0v[n]) * wsc[m][n][r]);
        }
    #pragma unroll
    for (int c=0;c<3;c++)
      #pragma unroll
      for (int m=0;m<2;m++)
        #pragma unroll
        for (int r=0;r<4;r++){
          int e = m*16 + g*4 + r;
          int vch = wid*16 + r15;
          R[e*320 + 128 + vch*3 + c] = (_Float16)(acc5[c][m][r]*0.125f * wvc[m][r]);
        }
    __syncthreads();

    // segmented reduction over dst runs (slot order => sorted dst), then atomics
    for (int j = tid; j < 320; j += 256){
      float accv = (float)R[j];
      int cur = EDST[0];
      for (int e=1;e<32;e++){
        int d = EDST[e];
        float v = (float)R[e*320 + j];
        if (d != cur){
          float* tgt = (j<128) ? &sa[(size_t)cur*128 + j] : &va[(size_t)cur*192 + (j-128)];
          atomicAdd(tgt, accv);
          accv = v; cur = d;
        } else accv += v;
      }
      float* tgt = (j<128) ? &sa[(size_t)cur*128 + j] : &va[(size_t)cur*192 + (j-128)];
      atomicAdd(tgt, accv);
    }
  }
}

// ---------------- Kernel 3: per-node head + residual ----------------
__global__ __launch_bounds__(256) void k_node_out(
  const float* __restrict__ nf, const float* __restrict__ oh,
  const float* __restrict__ Wtp0, const float* __restrict__ Wtp1,
  const float* __restrict__ Wo0, const float* __restrict__ bo0,
  const float* __restrict__ Wov, const float* __restrict__ resp,
  const float* __restrict__ sa, const float* __restrict__ va,
  float* __restrict__ out)
{
  __shared__ float SAB[4][128];
  __shared__ float VX[4][64], VY[4][64], VZ[4][64];
  __shared__ float S3 [4][128];
  __shared__ float V3 [4][256];
  const int tid=threadIdx.x, lane=tid&63, g=tid>>6;
  const int n = blockIdx.x*4 + g;

  float cf=0.f;
  #pragma unroll
  for (int j=0;j<16;j++) cf += j*oh[(size_t)n*16+j];
  const int c = (int)(cf+0.5f);

  SAB[g][lane]    = sa[(size_t)n*128+lane]   *0.25f;
  SAB[g][64+lane] = sa[(size_t)n*128+64+lane]*0.25f;
  VX[g][lane] = va[(size_t)n*192+lane*3+0]*0.25f;
  VY[g][lane] = va[(size_t)n*192+lane*3+1]*0.25f;
  VZ[g][lane] = va[(size_t)n*192+lane*3+2]*0.25f;
  __syncthreads();

  float t00=0.f, t01=0.f, t02=0.f;
  const float* w0c = Wtp0 + (size_t)c*192;
  for (int u=0;u<128;u++){
    float s = SAB[g][u];
    t00 += s * w0c[(size_t)u*3072 + lane];
    t01 += s * w0c[(size_t)u*3072 + lane+64];
    t02 += s * w0c[(size_t)u*3072 + lane+128];
  }
  const float sct0 = 0.02209708691f; // 1/sqrt(2048)
  t00*=sct0; t01*=sct0; t02*=sct0;

  float t1x=0.f,t1y=0.f,t1z=0.f;
  const float* w1c = Wtp1 + (size_t)c*64;
  for (int u=0;u<64;u++){
    float wv = w1c[(size_t)u*1024 + lane];
    t1x += VX[g][u]*wv;
    t1y += VY[g][u]*wv;
    t1z += VZ[g][u]*wv;
  }
  t1x*=0.03125f; t1y*=0.03125f; t1z*=0.03125f;

  S3[g][lane]    = silu(t00);
  S3[g][64+lane] = silu(t01);
  float g2 = sigm(t02);
  float4 v3v = {t1x*g2, t1y*g2, t1z*g2, 0.f};
  *(float4*)&V3[g][lane*4] = v3v;
  __syncthreads();

  float s40=0.f, s41=0.f;
  for (int k=0;k<128;k++){
    float s3k = S3[g][k];
    s40 += s3k*Wo0[k*128+lane];
    s41 += s3k*Wo0[k*128+64+lane];
  }
  s40 = s40*0.08838834765f + bo0[lane];
  s41 = s41*0.08838834765f + bo0[64+lane];

  float v4x=0.f,v4y=0.f,v4z=0.f;
  for (int u=0;u<64;u++){
    float4 v3u = *(const float4*)&V3[g][u*4];
    float wv = Wov[u*64+lane];
    v4x += v3u.x*wv; v4y += v3u.y*wv; v4z += v3u.z*wv;
  }
  v4x*=0.125f; v4y*=0.125f; v4z*=0.125f;

  const float r = sigm(resp[0]);
  const float* row = nf + (size_t)n*320;
  float* orow = out + (size_t)n*320;
  orow[lane]      = r*row[lane]      + (1.f-r)*s40;
  orow[64+lane]   = r*row[64+lane]   + (1.f-r)*s41;
  orow[128+lane*3+0] = r*row[128+lane*3+0] + (1.f-r)*v4x;
  orow[128+lane*3+1] = r*row[128+lane*3+1] + (1.f-r)*v4y;
  orow[128+lane*3+2] = r*row[128+lane*3+2] + (1.f-r)*v4z;
}

extern "C" void kernel_launch(void* const* d_in, const int* in_sizes, int n_in,
                              void* d_out, int out_size, void* d_ws, size_t ws_size,
                              hipStream_t stream)
{
  const float* nf   = (const float*)d_in[0];
  const float* ef   = (const float*)d_in[1];
  const float* evec = (const float*)d_in[2];
  const float* lats = (const float*)d_in[3];
  const float* oh   = (const float*)d_in[4];
  const float* g0n  = (const float*)d_in[5];
  const float* b0n  = (const float*)d_in[6];
  const float* g1n  = (const float*)d_in[7];
  const float* g0e  = (const float*)d_in[8];
  const float* b0e  = (const float*)d_in[9];
  const float* g1e  = (const float*)d_in[10];
  const float* Wm0  = (const float*)d_in[11];
  const float* wr   = (const float*)d_in[12];
  const float* wi   = (const float*)d_in[13];
  const float* Wenv = (const float*)d_in[14];
  const float* Wp0  = (const float*)d_in[15];
  const float* bp0  = (const float*)d_in[16];
  const float* Wpv  = (const float*)d_in[17];
  const float* Wtp0 = (const float*)d_in[18];
  const float* Wtp1 = (const float*)d_in[19];
  const float* Wo0  = (const float*)d_in[20];
  const float* bo0  = (const float*)d_in[21];
  const float* Wov  = (const float*)d_in[22];
  const float* resp = (const float*)d_in[23];
  const int*   eidx = (const int*)d_in[24];

  char* base = (char*)d_ws;
  unsigned short* ns_ln = (unsigned short*)(base);            // 4,194,304 B
  _Float16* nv_ln = (_Float16*)(base + 4194304);              // 6,291,456 -> 10,485,760
  float* sa    = (float*)(base + 10485760);                   // 8,388,608 -> 18,874,368
  float* va    = (float*)(base + 18874368);                   // 12,582,912 -> 31,457,280
  unsigned short* wpk = (unsigned short*)(base + 31457280);   // 417,792   -> 31,875,072
  unsigned short* pWm0  = wpk;            // 480*256
  unsigned short* pWc   = wpk + 122880;   // 320*128
  unsigned short* pWenv = wpk + 163840;   // 128*192
  unsigned short* pWp0  = wpk + 188416;   // 128*128
  unsigned short* pWpv  = wpk + 204800;   //  64*64
  int* ibuf   = (int*)(base + 31875072);                      // 311,297 ints
  int* cnt    = ibuf;
  int* rowp   = ibuf + 16384;
  int* cursor = ibuf + 32769;
  int* perm   = ibuf + 49153;
  unsigned short* wbuf = (unsigned short*)(base + 33120264);  // E*192*2 = 100,663,296

  hipMemsetAsync(sa, 0, (size_t)N_NODES*320*sizeof(float), stream);
  hipMemsetAsync(cnt, 0, N_NODES*sizeof(int), stream);

  k_pack_all<<<(208896+255)/256, 256, 0, stream>>>(Wm0, wr, wi, Wenv, Wp0, Wpv, wpk);
  k_node_ln<<<N_NODES/4, 256, 0, stream>>>(nf, g0n, b0n, g1n, ns_ln, nv_ln);

  k_hist<<<(N_EDGES+255)/256, 256, 0, stream>>>(eidx, cnt);
  k_scan<<<1, 256, 0, stream>>>(cnt, rowp, cursor);
  k_fill<<<(N_EDGES+255)/256, 256, 0, stream>>>(eidx, cursor, perm);

  k_wenv<<<N_EDGES/64, 256, 0, stream>>>(lats, pWenv, perm, wbuf);

  k_edge<<<N_EDGES/32, 256, POOL_BYTES, stream>>>(ef, evec, g0e, b0e, g1e,
                                                  pWm0, pWc, pWp0, pWpv, bp0,
                                                  eidx, perm, ns_ln, nv_ln, wbuf,
                                                  sa, va);
  k_node_out<<<N_NODES/4, 256, 0, stream>>>(nf, oh, Wtp0, Wtp1, Wo0, bo0, Wov,
                                            resp, sa, va, (float*)d_out);
}

// Round 11
// 584.263 us; speedup vs baseline: 1.2608x; 1.0475x over previous
//
#include <hip/hip_runtime.h>
#include <math.h>

#define N_NODES 16384
#define N_EDGES 262144
#define EPSF 1e-8f

// ---------------- LDS pool layout (bytes), 32 edges/block ----------------
#define OFF_XE    0        // bf16 [32][232] = 14848   (LN 0..63, c0 64..223)
#define OFF_C12   14848    // bf16 [32][328] = 20992 -> 35840
#define OFF_FR    35840    // f16  [32][12]  =   768 -> 36608 (persistent)
#define OFF_EDST  36608    // int  [32]      =   128 -> 36736 (persistent)
#define OFF_ESRC  36736    // int  [32]      =   128 -> 36864 (persistent)
#define POOL_BYTES 36864   // 4 blocks/CU
// overlays (after G1/G2 done reading XE/C12)
#define OFF_SACT  0        // bf16 [32][136] = 8704
#define OFF_GATE  8704     // bf16 [32][72]  = 4608 -> 13312
#define OFF_C0O   13312    // bf16 [32][72]  = 4608 -> 17920
#define OFF_C1O   17920    // bf16 [32][72]  = 4608 -> 22528
#define OFF_C2O   22528    // bf16 [32][72]  = 4608 -> 27136
#define OFF_VG    8704     // bf16 [3][32][72] = 13824 -> 22528 (over GATE/C0O/C1O after consumed)
// final overlay: R f16 [32][320] = 20480 at 0 (after SACT/VG consumed)

typedef __bf16 bf16x8 __attribute__((ext_vector_type(8)));
typedef float  f32x4  __attribute__((ext_vector_type(4)));

__device__ __forceinline__ f32x4 MFMA16(bf16x8 a, bf16x8 b, f32x4 c){
  return __builtin_amdgcn_mfma_f32_16x16x32_bf16(a, b, c, 0, 0, 0);
}

__device__ __forceinline__ unsigned short f2bf(float x){
  __bf16 h = (__bf16)x;
  union { __bf16 b; unsigned short u; } c; c.b = h;
  return c.u;
}
__device__ __forceinline__ float bf2f(unsigned short h){
  union { unsigned u; float f; } c; c.u = ((unsigned)h)<<16;
  return c.f;
}
__device__ __forceinline__ float wsum32(float v){
  #pragma unroll
  for (int m=1; m<32; m<<=1) v += __shfl_xor(v, m);
  return v;
}
__device__ __forceinline__ float wsum64(float v){
  #pragma unroll
  for (int m=1; m<64; m<<=1) v += __shfl_xor(v, m);
  return v;
}
__device__ __forceinline__ float sigm(float x){ return 1.0f/(1.0f+__expf(-x)); }
__device__ __forceinline__ float silu(float x){ return x/(1.0f+__expf(-x)); }

// ---------------- fused weight pack kernel (B-fragment layout) ----------------
__global__ __launch_bounds__(256) void k_pack_all(
  const float* __restrict__ Wm0, const float* __restrict__ wr,
  const float* __restrict__ wi,  const float* __restrict__ Wenv,
  const float* __restrict__ Wp0, const float* __restrict__ Wpv,
  unsigned short* __restrict__ wpk)
{
  int i = blockIdx.x*256 + threadIdx.x;
  if (i < 122880){                       // Wm0 [480][256]
    int k = i >> 8, n = i & 255;
    int idx = (((k>>5)*256 + n)*4 + ((k>>3)&3))*8 + (k&7);
    wpk[idx] = f2bf(Wm0[i]);
  } else if (i < 163840){                // Wc [320][128] = [[wr,wi],[-wi,wr]]
    int j = i - 122880;
    int k = j >> 7, n = j & 127;
    float v;
    if (k < 160) v = (n < 64) ? wr[k*64 + n]        : wi[k*64 + (n-64)];
    else         v = (n < 64) ? -wi[(k-160)*64 + n] : wr[(k-160)*64 + (n-64)];
    int idx = (((k>>5)*128 + n)*4 + ((k>>3)&3))*8 + (k&7);
    wpk[122880 + idx] = f2bf(v);
  } else if (i < 188416){                // Wenv [128][192]
    int j = i - 163840;
    int k = j / 192, n = j - k*192;
    int idx = (((k>>5)*192 + n)*4 + ((k>>3)&3))*8 + (k&7);
    wpk[163840 + idx] = f2bf(Wenv[j]);
  } else if (i < 204800){                // Wp0 [128][128]
    int j = i - 188416;
    int k = j >> 7, n = j & 127;
    int idx = (((k>>5)*128 + n)*4 + ((k>>3)&3))*8 + (k&7);
    wpk[188416 + idx] = f2bf(Wp0[j]);
  } else if (i < 208896){                // Wpv [64][64]
    int j = i - 204800;
    int k = j >> 6, n = j & 63;
    int idx = (((k>>5)*64 + n)*4 + ((k>>3)&3))*8 + (k&7);
    wpk[204800 + idx] = f2bf(Wpv[j]);
  }
}

// ---------------- CSR build (perm = edges sorted by dst) ----------------
__global__ __launch_bounds__(256) void k_hist(const int* __restrict__ eidx, int* __restrict__ cnt){
  int e = blockIdx.x*256 + threadIdx.x;
  if (e < N_EDGES) atomicAdd(&cnt[eidx[N_EDGES+e]], 1);
}
__global__ __launch_bounds__(256) void k_scan(const int* __restrict__ cnt,
                                              int* __restrict__ rowp, int* __restrict__ cursor){
  __shared__ int part[256];
  __shared__ int pref[257];
  const int t = threadIdx.x;
  const int base = t*64;
  int s = 0;
  for (int i=0;i<64;i++) s += cnt[base+i];
  part[t] = s; __syncthreads();
  if (t==0){ int a=0; for (int i=0;i<256;i++){ pref[i]=a; a+=part[i]; } pref[256]=a; }
  __syncthreads();
  int a = pref[t];
  for (int i=0;i<64;i++){ rowp[base+i]=a; cursor[base+i]=a; a += cnt[base+i]; }
  if (t==0) rowp[N_NODES] = pref[256];
}
__global__ __launch_bounds__(256) void k_fill(const int* __restrict__ eidx,
                                              int* __restrict__ cursor, int* __restrict__ perm){
  int e = blockIdx.x*256 + threadIdx.x;
  if (e < N_EDGES){
    int pos = atomicAdd(&cursor[eidx[N_EDGES+e]], 1);
    perm[pos] = e;
  }
}

// ---------------- Kernel 1: node separable LN (scalars bf16, vectors f16) ----------------
__global__ __launch_bounds__(256) void k_node_ln(
    const float* __restrict__ nf, const float* __restrict__ g0,
    const float* __restrict__ b0, const float* __restrict__ g1,
    unsigned short* __restrict__ ns_ln, _Float16* __restrict__ nv_ln)
{
  const int tid  = threadIdx.x;
  const int lane = tid & 63;
  const int n    = blockIdx.x*4 + (tid>>6);
  const float* row = nf + (size_t)n*320;

  float s0 = row[lane], s1 = row[64+lane];
  float mu = wsum64(s0+s1) * (1.0f/128.0f);
  float d0 = s0-mu, d1 = s1-mu;
  float var = wsum64(d0*d0+d1*d1) * (1.0f/128.0f);
  float rs = rsqrtf(var + EPSF);
  ns_ln[(size_t)n*128 + lane]    = f2bf(d0*rs*g0[lane]    + b0[lane]);
  ns_ln[(size_t)n*128 + 64+lane] = f2bf(d1*rs*g0[64+lane] + b0[64+lane]);

  float px = row[128+lane*3+0], py = row[128+lane*3+1], pz = row[128+lane*3+2];
  float vvar = wsum64(px*px+py*py+pz*pz) * (1.0f/192.0f);
  float vsc = rsqrtf(vvar + EPSF) * g1[lane];
  nv_ln[(size_t)n*192 + lane*3+0] = (_Float16)(px*vsc);
  nv_ln[(size_t)n*192 + lane*3+1] = (_Float16)(py*vsc);
  nv_ln[(size_t)n*192 + lane*3+2] = (_Float16)(pz*vsc);
}

// ---------------- Kernel 2: edge message kernel (MFMA, 32 edges/block, slot order) ----------------
__global__ __launch_bounds__(256,4) void k_edge(
  const float* __restrict__ ef, const float* __restrict__ evec,
  const float* __restrict__ lats,
  const float* __restrict__ g0e, const float* __restrict__ b0e, const float* __restrict__ g1e,
  const unsigned short* __restrict__ pWm0, const unsigned short* __restrict__ pWc,
  const unsigned short* __restrict__ pWenv, const unsigned short* __restrict__ pWp0,
  const unsigned short* __restrict__ pWpv,
  const float* __restrict__ bp0,
  const int* __restrict__ eidx, const int* __restrict__ perm,
  const unsigned short* __restrict__ ns_ln, const _Float16* __restrict__ nv_ln,
  float* __restrict__ sa, float* __restrict__ va)
{
  extern __shared__ unsigned char pool[];
  const int tid = threadIdx.x;
  unsigned short* XE   = (unsigned short*)(pool + OFF_XE);
  unsigned short* C12s = (unsigned short*)(pool + OFF_C12);
  _Float16* FRh = (_Float16*)(pool + OFF_FR);
  int* EDST = (int*)(pool + OFF_EDST);
  int* ESRC = (int*)(pool + OFF_ESRC);

  // XCD-aware swizzle: contiguous slot span per XCD (nwg = 8192, %8 == 0)
  const int nwg = gridDim.x;
  const int bswz = (blockIdx.x & 7)*(nwg>>3) + (blockIdx.x >> 3);

  const int wid = tid>>6, l = tid&63;
  const int r15 = l&15, g = l>>4;
  const int sbase = bswz*32;

  // ---------------- Phase A: prep (4 passes of 8 edges, 32 lanes/edge) ----------------
  {
    const int ln = tid & 31;
    #pragma unroll
    for (int eo=0; eo<4; ++eo){
      const int el = eo*8 + (tid>>5);
      const int slot = sbase + el;
      const size_t e = (size_t)perm[slot];
      const int src = eidx[e];
      const int dst = eidx[N_EDGES + e];

      float vx=evec[e*3+0], vy=evec[e*3+1], vz=evec[e*3+2];
      float rn = rsqrtf(vx*vx+vy*vy+vz*vz+EPSF);
      float ax=vx*rn, ay=vy*rn, az=vz*rn;
      float hx, hz;
      if (fabsf(az) < 0.99f){ hx=0.f; hz=1.f; } else { hx=1.f; hz=0.f; }
      float e1x = -hz*ay;
      float e1y = hz*ax - hx*az;
      float e1z = hx*ay;
      float rn1 = rsqrtf(e1x*e1x+e1y*e1y+e1z*e1z+EPSF);
      e1x*=rn1; e1y*=rn1; e1z*=rn1;
      float e2x = ay*e1z - az*e1y;
      float e2y = az*e1x - ax*e1z;
      float e2z = ax*e1y - ay*e1x;
      if (ln==0){
        FRh[el*12+0]=(_Float16)ax;  FRh[el*12+1]=(_Float16)ay;  FRh[el*12+2]=(_Float16)az;
        FRh[el*12+3]=(_Float16)e1x; FRh[el*12+4]=(_Float16)e1y; FRh[el*12+5]=(_Float16)e1z;
        FRh[el*12+6]=(_Float16)e2x; FRh[el*12+7]=(_Float16)e2y; FRh[el*12+8]=(_Float16)e2z;
        EDST[el]=dst;
        ESRC[el]=src;
      }

      const float* erow = ef + e*160;
      float s0=erow[ln], s1=erow[32+ln];
      float mu = wsum32(s0+s1)*(1.f/64.f);
      float d0=s0-mu, d1=s1-mu;
      float var = wsum32(d0*d0+d1*d1)*(1.f/64.f);
      float rs = rsqrtf(var+EPSF);
      XE[el*232 + ln]    = f2bf(d0*rs*g0e[ln]    + b0e[ln]);
      XE[el*232 + 32+ln] = f2bf(d1*rs*g0e[32+ln] + b0e[32+ln]);

      float wx=erow[64+ln*3+0], wy=erow[64+ln*3+1], wz=erow[64+ln*3+2];
      float vvar = wsum32(wx*wx+wy*wy+wz*wz)*(1.f/96.f);
      float vsc = rsqrtf(vvar+EPSF)*g1e[ln];
      wx*=vsc; wy*=vsc; wz*=vsc;
      XE  [el*232 + 64+64+ln]    = f2bf(wx*ax +wy*ay +wz*az);
      C12s[el*328 + 64+ln]       = f2bf(wx*e1x+wy*e1y+wz*e1z);
      C12s[el*328 + 160+64+ln]   = f2bf(wx*e2x+wy*e2y+wz*e2z);

      const _Float16* nvs = nv_ln + (size_t)src*192;
      const _Float16* nvd = nv_ln + (size_t)dst*192;
      #pragma unroll
      for (int q=0;q<2;q++){
        int u = ln+32*q;
        float px=(float)nvs[u*3+0], py=(float)nvs[u*3+1], pz=(float)nvs[u*3+2];
        XE  [el*232 + 64+u]      = f2bf(px*ax +py*ay +pz*az);
        C12s[el*328 + u]         = f2bf(px*e1x+py*e1y+pz*e1z);
        C12s[el*328 + 160+u]     = f2bf(px*e2x+py*e2y+pz*e2z);
        px=(float)nvd[u*3+0]; py=(float)nvd[u*3+1]; pz=(float)nvd[u*3+2];
        XE  [el*232 + 64+96+u]   = f2bf(px*ax +py*ay +pz*az);
        C12s[el*328 + 96+u]      = f2bf(px*e1x+py*e1y+pz*e1z);
        C12s[el*328 + 160+96+u]  = f2bf(px*e2x+py*e2y+pz*e2z);
      }
    }
  }

  const f32x4 zero4 = {0.f,0.f,0.f,0.f};

  // ---------------- G3 (in-wave): w = lats[32x128] @ Wenv col-tiles {wid*32, wid*32+16, 128+wid*16}
  // Each wave computes exactly the 48 w-columns its epilogue needs -> no LDS/cross-wave exchange.
  float wsc[2][2][4], wvc[2][4];
  {
    f32x4 acc3[2][3];
    #pragma unroll
    for (int m=0;m<2;m++)
      #pragma unroll
      for (int n=0;n<3;n++) acc3[m][n]=zero4;
    const int eg0 = perm[sbase + r15];
    const int eg1 = perm[sbase + 16 + r15];
    const float* la0 = lats + (size_t)eg0*128;
    const float* la1 = lats + (size_t)eg1*128;
    const int colb0 = wid*32, colb1 = wid*32+16, colb2 = 128+wid*16;
    #pragma unroll
    for (int kc=0;kc<4;kc++){
      float4 f00 = *(const float4*)&la0[kc*32 + g*8];
      float4 f01 = *(const float4*)&la0[kc*32 + g*8 + 4];
      float4 f10 = *(const float4*)&la1[kc*32 + g*8];
      float4 f11 = *(const float4*)&la1[kc*32 + g*8 + 4];
      union { bf16x8 v; unsigned short s[8]; } a0, a1;
      a0.s[0]=f2bf(f00.x); a0.s[1]=f2bf(f00.y); a0.s[2]=f2bf(f00.z); a0.s[3]=f2bf(f00.w);
      a0.s[4]=f2bf(f01.x); a0.s[5]=f2bf(f01.y); a0.s[6]=f2bf(f01.z); a0.s[7]=f2bf(f01.w);
      a1.s[0]=f2bf(f10.x); a1.s[1]=f2bf(f10.y); a1.s[2]=f2bf(f10.z); a1.s[3]=f2bf(f10.w);
      a1.s[4]=f2bf(f11.x); a1.s[5]=f2bf(f11.y); a1.s[6]=f2bf(f11.z); a1.s[7]=f2bf(f11.w);
      bf16x8 b0 = *(const bf16x8*)(pWenv + ((size_t)(kc*192 + colb0 + r15)*4 + g)*8);
      bf16x8 b1 = *(const bf16x8*)(pWenv + ((size_t)(kc*192 + colb1 + r15)*4 + g)*8);
      bf16x8 b2 = *(const bf16x8*)(pWenv + ((size_t)(kc*192 + colb2 + r15)*4 + g)*8);
      acc3[0][0] = MFMA16(a0.v,b0,acc3[0][0]);
      acc3[1][0] = MFMA16(a1.v,b0,acc3[1][0]);
      acc3[0][1] = MFMA16(a0.v,b1,acc3[0][1]);
      acc3[1][1] = MFMA16(a1.v,b1,acc3[1][1]);
      acc3[0][2] = MFMA16(a0.v,b2,acc3[0][2]);
      acc3[1][2] = MFMA16(a1.v,b2,acc3[1][2]);
    }
    const float S = 0.08838834764831845f;  // 1/sqrt(128)
    #pragma unroll
    for (int m=0;m<2;m++)
      #pragma unroll
      for (int r=0;r<4;r++){
        wsc[m][0][r] = acc3[m][0][r]*S;
        wsc[m][1][r] = acc3[m][1][r]*S;
        wvc[m][r]    = acc3[m][2][r]*S;
      }
  }
  __syncthreads();

  // G1: m0 = X[32x480] @ Wm0[480x256]
  f32x4 acc1[2][4];
  #pragma unroll
  for (int m=0;m<2;m++)
    #pragma unroll
    for (int n=0;n<4;n++) acc1[m][n]=zero4;
  {
    const unsigned short* bbase = pWm0 + ((size_t)(wid*64 + r15)*4 + g)*8;
    bf16x8 gA[2][8];
    {
      const int rs0 = ESRC[r15], rs1 = ESRC[16+r15];
      const int rd0 = EDST[r15], rd1 = EDST[16+r15];
      #pragma unroll
      for (int q=0;q<4;q++){
        gA[0][q]   = *(const bf16x8*)&ns_ln[(size_t)rs0*128 + q*32 + g*8];
        gA[1][q]   = *(const bf16x8*)&ns_ln[(size_t)rs1*128 + q*32 + g*8];
        gA[0][4+q] = *(const bf16x8*)&ns_ln[(size_t)rd0*128 + q*32 + g*8];
        gA[1][4+q] = *(const bf16x8*)&ns_ln[(size_t)rd1*128 + q*32 + g*8];
      }
    }
    #pragma unroll
    for (int t=0;t<7;t++){
      const int kc  = (t<2) ? (4+t) : (10 + t-2);
      const int col = (t<2) ? (t*32) : (64 + (t-2)*32);
      bf16x8 a0 = *(const bf16x8*)&XE[(    r15)*232 + col + g*8];
      bf16x8 a1 = *(const bf16x8*)&XE[(16+ r15)*232 + col + g*8];
      const unsigned short* bp = bbase + (size_t)kc*8192;
      #pragma unroll
      for (int n=0;n<4;n++){
        bf16x8 b = *(const bf16x8*)(bp + n*512);
        acc1[0][n] = MFMA16(a0,b,acc1[0][n]);
        acc1[1][n] = MFMA16(a1,b,acc1[1][n]);
      }
    }
    #pragma unroll
    for (int t=0;t<8;t++){
      const int kc = (t<4) ? t : (6 + t-4);
      const unsigned short* bp = bbase + (size_t)kc*8192;
      #pragma unroll
      for (int n=0;n<4;n++){
        bf16x8 b = *(const bf16x8*)(bp + n*512);
        acc1[0][n] = MFMA16(gA[0][t],b,acc1[0][n]);
        acc1[1][n] = MFMA16(gA[1][t],b,acc1[1][n]);
      }
    }
  }

  // G2: c12o = C12[32x320] @ Wc[320x128]
  f32x4 acc2[2][2];
  #pragma unroll
  for (int m=0;m<2;m++){ acc2[m][0]=zero4; acc2[m][1]=zero4; }
  {
    const unsigned short* bbase = pWc + ((size_t)(wid*32 + r15)*4 + g)*8;
    #pragma unroll
    for (int kc=0;kc<10;kc++){
      bf16x8 a0 = *(const bf16x8*)&C12s[(    r15)*328 + kc*32 + g*8];
      bf16x8 a1 = *(const bf16x8*)&C12s[(16+ r15)*328 + kc*32 + g*8];
      const unsigned short* bp = bbase + (size_t)kc*4096;
      #pragma unroll
      for (int n=0;n<2;n++){
        bf16x8 b = *(const bf16x8*)(bp + n*512);
        acc2[0][n] = MFMA16(a0,b,acc2[0][n]);
        acc2[1][n] = MFMA16(a1,b,acc2[1][n]);
      }
    }
  }

  // bias prefetch
  float bp0v[2];
  #pragma unroll
  for (int n=0;n<2;n++) bp0v[n] = bp0[wid*32 + n*16 + r15];

  __syncthreads();   // all waves done reading XE/C12

  // G1/G2 epilogues -> overlays (bf16)
  {
    unsigned short* SAs = (unsigned short*)(pool + OFF_SACT);
    unsigned short* GAb = (unsigned short*)(pool + OFF_GATE);
    unsigned short* C0b = (unsigned short*)(pool + OFF_C0O);
    #pragma unroll
    for (int m=0;m<2;m++)
      #pragma unroll
      for (int n=0;n<4;n++)
        #pragma unroll
        for (int r=0;r<4;r++){
          int e = m*16 + g*4 + r;
          int j = wid*64 + n*16 + r15;
          float v = acc1[m][n][r]*0.04564354645876384f;  // 1/sqrt(480)
          if (j < 128)      SAs[e*136 + j] = f2bf(silu(v));
          else if (j < 192) GAb[e*72 + (j-128)] = f2bf(sigm(v));
          else              C0b[e*72 + (j-192)] = f2bf(v);
        }
    unsigned short* C1b = (unsigned short*)(pool + OFF_C1O);
    unsigned short* C2b = (unsigned short*)(pool + OFF_C2O);
    #pragma unroll
    for (int m=0;m<2;m++)
      #pragma unroll
      for (int n=0;n<2;n++)
        #pragma unroll
        for (int r=0;r<4;r++){
          int e = m*16 + g*4 + r;
          int j = wid*32 + n*16 + r15;
          float v = acc2[m][n][r]*0.07905694150420949f;  // 1/sqrt(160)
          if (j < 64) C1b[e*72 + j] = f2bf(v);
          else        C2b[e*72 + (j-64)] = f2bf(v);
        }
  }
  __syncthreads();

  // C1: v_g = (c0o*a + c1o*e1 + c2o*e2)*gate -> VG bf16 (8 u's/thread)
  {
    const int e = tid>>3, u0 = (tid&7)*8;
    const unsigned short* GAb = (const unsigned short*)(pool + OFF_GATE);
    const unsigned short* C0b = (const unsigned short*)(pool + OFF_C0O);
    const unsigned short* C1b = (const unsigned short*)(pool + OFF_C1O);
    const unsigned short* C2b = (const unsigned short*)(pool + OFF_C2O);
    float ax=(float)FRh[e*12+0],  ay=(float)FRh[e*12+1],  az=(float)FRh[e*12+2];
    float b1x=(float)FRh[e*12+3], b1y=(float)FRh[e*12+4], b1z=(float)FRh[e*12+5];
    float b2x=(float)FRh[e*12+6], b2y=(float)FRh[e*12+7], b2z=(float)FRh[e*12+8];
    float vgx[8], vgy[8], vgz[8];
    #pragma unroll
    for (int i=0;i<8;i++){
      int u = u0+i;
      float gt = bf2f(GAb[e*72+u]);
      float c0 = bf2f(C0b[e*72+u]), c1 = bf2f(C1b[e*72+u]), c2 = bf2f(C2b[e*72+u]);
      vgx[i] = (c0*ax + c1*b1x + c2*b2x)*gt;
      vgy[i] = (c0*ay + c1*b1y + c2*b2y)*gt;
      vgz[i] = (c0*az + c1*b1z + c2*b2z)*gt;
    }
    __syncthreads();   // GATE/C0O/C1O reads done before VG overlay writes
    unsigned short* VGs = (unsigned short*)(pool + OFF_VG);
    #pragma unroll
    for (int i=0;i<8;i++){
      VGs[0*2304 + e*72 + u0+i] = f2bf(vgx[i]);
      VGs[1*2304 + e*72 + u0+i] = f2bf(vgy[i]);
      VGs[2*2304 + e*72 + u0+i] = f2bf(vgz[i]);
    }
  }
  __syncthreads();

  // G4: s2 = SACT @ Wp0 ; G5: v2c = VG[c] @ Wpv
  {
    const unsigned short* SAs = (const unsigned short*)(pool + OFF_SACT);
    const unsigned short* VGs = (const unsigned short*)(pool + OFF_VG);

    f32x4 acc4[2][2], acc5[3][2];
    #pragma unroll
    for (int m=0;m<2;m++){ acc4[m][0]=zero4; acc4[m][1]=zero4; }
    #pragma unroll
    for (int c=0;c<3;c++){ acc5[c][0]=zero4; acc5[c][1]=zero4; }

    {
      const unsigned short* bbase = pWp0 + ((size_t)(wid*32 + r15)*4 + g)*8;
      #pragma unroll
      for (int kc=0;kc<4;kc++){
        bf16x8 a0 = *(const bf16x8*)&SAs[(    r15)*136 + kc*32 + g*8];
        bf16x8 a1 = *(const bf16x8*)&SAs[(16+ r15)*136 + kc*32 + g*8];
        #pragma unroll
        for (int n=0;n<2;n++){
          bf16x8 b = *(const bf16x8*)(bbase + (size_t)kc*4096 + n*512);
          acc4[0][n] = MFMA16(a0,b,acc4[0][n]);
          acc4[1][n] = MFMA16(a1,b,acc4[1][n]);
        }
      }
    }
    {
      bf16x8 b5[2];
      #pragma unroll
      for (int kc=0;kc<2;kc++)
        b5[kc] = *(const bf16x8*)(pWpv + ((size_t)(kc*64 + wid*16 + r15)*4 + g)*8);
      #pragma unroll
      for (int c=0;c<3;c++)
        #pragma unroll
        for (int kc=0;kc<2;kc++){
          bf16x8 a0 = *(const bf16x8*)&VGs[c*2304 + (    r15)*72 + kc*32 + g*8];
          bf16x8 a1 = *(const bf16x8*)&VGs[c*2304 + (16+ r15)*72 + kc*32 + g*8];
          acc5[c][0] = MFMA16(a0,b5[kc],acc5[c][0]);
          acc5[c][1] = MFMA16(a1,b5[kc],acc5[c][1]);
        }
    }

    __syncthreads();   // all waves done reading SACT/VG before R overlay
    _Float16* R = (_Float16*)pool;   // f16 [32][320]
    #pragma unroll
    for (int m=0;m<2;m++)
      #pragma unroll
      for (int n=0;n<2;n++)
        #pragma unroll
        for (int r=0;r<4;r++){
          int e = m*16 + g*4 + r;
          int j = wid*32 + n*16 + r15;
          R[e*320 + j] = (_Float16)((acc4[m][n][r]*0.08838834764831845f + bp0v[n]) * wsc[m][n][r]);
        }
    #pragma unroll
    for (int c=0;c<3;c++)
      #pragma unroll
      for (int m=0;m<2;m++)
        #pragma unroll
        for (int r=0;r<4;r++){
          int e = m*16 + g*4 + r;
          int vch = wid*16 + r15;
          R[e*320 + 128 + vch*3 + c] = (_Float16)(acc5[c][m][r]*0.125f * wvc[m][r]);
        }
    __syncthreads();

    // segmented reduction over dst runs (slot order => sorted dst), then atomics
    for (int j = tid; j < 320; j += 256){
      float accv = (float)R[j];
      int cur = EDST[0];
      for (int e=1;e<32;e++){
        int d = EDST[e];
        float v = (float)R[e*320 + j];
        if (d != cur){
          float* tgt = (j<128) ? &sa[(size_t)cur*128 + j] : &va[(size_t)cur*192 + (j-128)];
          atomicAdd(tgt, accv);
          accv = v; cur = d;
        } else accv += v;
      }
      float* tgt = (j<128) ? &sa[(size_t)cur*128 + j] : &va[(size_t)cur*192 + (j-128)];
      atomicAdd(tgt, accv);
    }
  }
}

// ---------------- Kernel 3: per-node head + residual ----------------
__global__ __launch_bounds__(256) void k_node_out(
  const float* __restrict__ nf, const float* __restrict__ oh,
  const float* __restrict__ Wtp0, const float* __restrict__ Wtp1,
  const float* __restrict__ Wo0, const float* __restrict__ bo0,
  const float* __restrict__ Wov, const float* __restrict__ resp,
  const float* __restrict__ sa, const float* __restrict__ va,
  float* __restrict__ out)
{
  __shared__ float SAB[4][128];
  __shared__ float VX[4][64], VY[4][64], VZ[4][64];
  __shared__ float S3 [4][128];
  __shared__ float V3 [4][256];
  const int tid=threadIdx.x, lane=tid&63, g=tid>>6;
  const int n = blockIdx.x*4 + g;

  float cf=0.f;
  #pragma unroll
  for (int j=0;j<16;j++) cf += j*oh[(size_t)n*16+j];
  const int c = (int)(cf+0.5f);

  SAB[g][lane]    = sa[(size_t)n*128+lane]   *0.25f;
  SAB[g][64+lane] = sa[(size_t)n*128+64+lane]*0.25f;
  VX[g][lane] = va[(size_t)n*192+lane*3+0]*0.25f;
  VY[g][lane] = va[(size_t)n*192+lane*3+1]*0.25f;
  VZ[g][lane] = va[(size_t)n*192+lane*3+2]*0.25f;
  __syncthreads();

  float t00=0.f, t01=0.f, t02=0.f;
  const float* w0c = Wtp0 + (size_t)c*192;
  for (int u=0;u<128;u++){
    float s = SAB[g][u];
    t00 += s * w0c[(size_t)u*3072 + lane];
    t01 += s * w0c[(size_t)u*3072 + lane+64];
    t02 += s * w0c[(size_t)u*3072 + lane+128];
  }
  const float sct0 = 0.02209708691f; // 1/sqrt(2048)
  t00*=sct0; t01*=sct0; t02*=sct0;

  float t1x=0.f,t1y=0.f,t1z=0.f;
  const float* w1c = Wtp1 + (size_t)c*64;
  for (int u=0;u<64;u++){
    float wv = w1c[(size_t)u*1024 + lane];
    t1x += VX[g][u]*wv;
    t1y += VY[g][u]*wv;
    t1z += VZ[g][u]*wv;
  }
  t1x*=0.03125f; t1y*=0.03125f; t1z*=0.03125f;

  S3[g][lane]    = silu(t00);
  S3[g][64+lane] = silu(t01);
  float g2 = sigm(t02);
  float4 v3v = {t1x*g2, t1y*g2, t1z*g2, 0.f};
  *(float4*)&V3[g][lane*4] = v3v;
  __syncthreads();

  float s40=0.f, s41=0.f;
  for (int k=0;k<128;k++){
    float s3k = S3[g][k];
    s40 += s3k*Wo0[k*128+lane];
    s41 += s3k*Wo0[k*128+64+lane];
  }
  s40 = s40*0.08838834765f + bo0[lane];
  s41 = s41*0.08838834765f + bo0[64+lane];

  float v4x=0.f,v4y=0.f,v4z=0.f;
  for (int u=0;u<64;u++){
    float4 v3u = *(const float4*)&V3[g][u*4];
    float wv = Wov[u*64+lane];
    v4x += v3u.x*wv; v4y += v3u.y*wv; v4z += v3u.z*wv;
  }
  v4x*=0.125f; v4y*=0.125f; v4z*=0.125f;

  const float r = sigm(resp[0]);
  const float* row = nf + (size_t)n*320;
  float* orow = out + (size_t)n*320;
  orow[lane]      = r*row[lane]      + (1.f-r)*s40;
  orow[64+lane]   = r*row[64+lane]   + (1.f-r)*s41;
  orow[128+lane*3+0] = r*row[128+lane*3+0] + (1.f-r)*v4x;
  orow[128+lane*3+1] = r*row[128+lane*3+1] + (1.f-r)*v4y;
  orow[128+lane*3+2] = r*row[128+lane*3+2] + (1.f-r)*v4z;
}

extern "C" void kernel_launch(void* const* d_in, const int* in_sizes, int n_in,
                              void* d_out, int out_size, void* d_ws, size_t ws_size,
                              hipStream_t stream)
{
  const float* nf   = (const float*)d_in[0];
  const float* ef   = (const float*)d_in[1];
  const float* evec = (const float*)d_in[2];
  const float* lats = (const float*)d_in[3];
  const float* oh   = (const float*)d_in[4];
  const float* g0n  = (const float*)d_in[5];
  const float* b0n  = (const float*)d_in[6];
  const float* g1n  = (const float*)d_in[7];
  const float* g0e  = (const float*)d_in[8];
  const float* b0e  = (const float*)d_in[9];
  const float* g1e  = (const float*)d_in[10];
  const float* Wm0  = (const float*)d_in[11];
  const float* wr   = (const float*)d_in[12];
  const float* wi   = (const float*)d_in[13];
  const float* Wenv = (const float*)d_in[14];
  const float* Wp0  = (const float*)d_in[15];
  const float* bp0  = (const float*)d_in[16];
  const float* Wpv  = (const float*)d_in[17];
  const float* Wtp0 = (const float*)d_in[18];
  const float* Wtp1 = (const float*)d_in[19];
  const float* Wo0  = (const float*)d_in[20];
  const float* bo0  = (const float*)d_in[21];
  const float* Wov  = (const float*)d_in[22];
  const float* resp = (const float*)d_in[23];
  const int*   eidx = (const int*)d_in[24];

  char* base = (char*)d_ws;
  unsigned short* ns_ln = (unsigned short*)(base);            // 4,194,304 B
  _Float16* nv_ln = (_Float16*)(base + 4194304);              // 6,291,456 -> 10,485,760
  float* sa    = (float*)(base + 10485760);                   // 8,388,608 -> 18,874,368
  float* va    = (float*)(base + 18874368);                   // 12,582,912 -> 31,457,280
  unsigned short* wpk = (unsigned short*)(base + 31457280);   // 417,792   -> 31,875,072
  unsigned short* pWm0  = wpk;            // 480*256
  unsigned short* pWc   = wpk + 122880;   // 320*128
  unsigned short* pWenv = wpk + 163840;   // 128*192
  unsigned short* pWp0  = wpk + 188416;   // 128*128
  unsigned short* pWpv  = wpk + 204800;   //  64*64
  int* ibuf   = (int*)(base + 31875072);                      // 311,297 ints
  int* cnt    = ibuf;
  int* rowp   = ibuf + 16384;
  int* cursor = ibuf + 32769;
  int* perm   = ibuf + 49153;

  hipMemsetAsync(sa, 0, (size_t)N_NODES*320*sizeof(float), stream);
  hipMemsetAsync(cnt, 0, N_NODES*sizeof(int), stream);

  k_pack_all<<<(208896+255)/256, 256, 0, stream>>>(Wm0, wr, wi, Wenv, Wp0, Wpv, wpk);
  k_node_ln<<<N_NODES/4, 256, 0, stream>>>(nf, g0n, b0n, g1n, ns_ln, nv_ln);

  k_hist<<<(N_EDGES+255)/256, 256, 0, stream>>>(eidx, cnt);
  k_scan<<<1, 256, 0, stream>>>(cnt, rowp, cursor);
  k_fill<<<(N_EDGES+255)/256, 256, 0, stream>>>(eidx, cursor, perm);

  k_edge<<<N_EDGES/32, 256, POOL_BYTES, stream>>>(ef, evec, lats, g0e, b0e, g1e,
                                                  pWm0, pWc, pWenv, pWp0, pWpv, bp0,
                                                  eidx, perm, ns_ln, nv_ln,
                                                  sa, va);
  k_node_out<<<N_NODES/4, 256, 0, stream>>>(nf, oh, Wtp0, Wtp1, Wo0, bo0, Wov,
                                            resp, sa, va, (float*)d_out);
}

// Round 13
// 578.402 us; speedup vs baseline: 1.2735x; 1.0101x over previous
//
#include <hip/hip_runtime.h>
#include <math.h>

#define N_NODES 16384
#define N_EDGES 262144
#define EPSF 1e-8f

// ---------------- LDS pool layout (bytes), 32 edges/block ----------------
#define OFF_XE    0        // bf16 [32][232] = 14848   (LN 0..63, c0 64..223)
#define OFF_C12   14848    // bf16 [32][328] = 20992 -> 35840
#define OFF_FR    35840    // f16  [32][12]  =   768 -> 36608 (persistent)
#define OFF_EDST  36608    // int  [32]      =   128 -> 36736 (persistent)
#define OFF_ESRC  36736    // int  [32]      =   128 -> 36864 (persistent)
#define POOL_BYTES 36864   // 4 blocks/CU
// overlays (after G1/G2 done reading XE/C12)
#define OFF_SACT  0        // bf16 [32][136] = 8704
#define OFF_GATE  8704     // bf16 [32][72]  = 4608 -> 13312
#define OFF_C0O   13312    // bf16 [32][72]  = 4608 -> 17920
#define OFF_C1O   17920    // bf16 [32][72]  = 4608 -> 22528
#define OFF_C2O   22528    // bf16 [32][72]  = 4608 -> 27136
#define OFF_VG    8704     // bf16 [3][32][72] = 13824 -> 22528 (over GATE/C0O/C1O after consumed)
// final overlay: R f16 [32][320] = 20480 at 0 (after SACT/VG consumed)

typedef __bf16 bf16x8 __attribute__((ext_vector_type(8)));
typedef float  f32x4  __attribute__((ext_vector_type(4)));

__device__ __forceinline__ f32x4 MFMA16(bf16x8 a, bf16x8 b, f32x4 c){
  return __builtin_amdgcn_mfma_f32_16x16x32_bf16(a, b, c, 0, 0, 0);
}

__device__ __forceinline__ unsigned short f2bf(float x){
  __bf16 h = (__bf16)x;
  union { __bf16 b; unsigned short u; } c; c.b = h;
  return c.u;
}
__device__ __forceinline__ float bf2f(unsigned short h){
  union { unsigned u; float f; } c; c.u = ((unsigned)h)<<16;
  return c.f;
}
__device__ __forceinline__ float wsum32(float v){
  #pragma unroll
  for (int m=1; m<32; m<<=1) v += __shfl_xor(v, m);
  return v;
}
__device__ __forceinline__ float wsum64(float v){
  #pragma unroll
  for (int m=1; m<64; m<<=1) v += __shfl_xor(v, m);
  return v;
}
__device__ __forceinline__ float sigm(float x){ return 1.0f/(1.0f+__expf(-x)); }
__device__ __forceinline__ float silu(float x){ return x/(1.0f+__expf(-x)); }

// ---------------- fused weight pack kernel (B-fragment layout) ----------------
__global__ __launch_bounds__(256) void k_pack_all(
  const float* __restrict__ Wm0, const float* __restrict__ wr,
  const float* __restrict__ wi,  const float* __restrict__ Wenv,
  const float* __restrict__ Wp0, const float* __restrict__ Wpv,
  unsigned short* __restrict__ wpk)
{
  int i = blockIdx.x*256 + threadIdx.x;
  if (i < 122880){                       // Wm0 [480][256]
    int k = i >> 8, n = i & 255;
    int idx = (((k>>5)*256 + n)*4 + ((k>>3)&3))*8 + (k&7);
    wpk[idx] = f2bf(Wm0[i]);
  } else if (i < 163840){                // Wc [320][128] = [[wr,wi],[-wi,wr]]
    int j = i - 122880;
    int k = j >> 7, n = j & 127;
    float v;
    if (k < 160) v = (n < 64) ? wr[k*64 + n]        : wi[k*64 + (n-64)];
    else         v = (n < 64) ? -wi[(k-160)*64 + n] : wr[(k-160)*64 + (n-64)];
    int idx = (((k>>5)*128 + n)*4 + ((k>>3)&3))*8 + (k&7);
    wpk[122880 + idx] = f2bf(v);
  } else if (i < 188416){                // Wenv [128][192]
    int j = i - 163840;
    int k = j / 192, n = j - k*192;
    int idx = (((k>>5)*192 + n)*4 + ((k>>3)&3))*8 + (k&7);
    wpk[163840 + idx] = f2bf(Wenv[j]);
  } else if (i < 204800){                // Wp0 [128][128]
    int j = i - 188416;
    int k = j >> 7, n = j & 127;
    int idx = (((k>>5)*128 + n)*4 + ((k>>3)&3))*8 + (k&7);
    wpk[188416 + idx] = f2bf(Wp0[j]);
  } else if (i < 208896){                // Wpv [64][64]
    int j = i - 204800;
    int k = j >> 6, n = j & 63;
    int idx = (((k>>5)*64 + n)*4 + ((k>>3)&3))*8 + (k&7);
    wpk[204800 + idx] = f2bf(Wpv[j]);
  }
}

// ---------------- CSR build (perm = edges sorted by dst) ----------------
__global__ __launch_bounds__(256) void k_hist(const int* __restrict__ eidx, int* __restrict__ cnt){
  int e = blockIdx.x*256 + threadIdx.x;
  if (e < N_EDGES) atomicAdd(&cnt[eidx[N_EDGES+e]], 1);
}
__global__ __launch_bounds__(256) void k_scan(const int* __restrict__ cnt,
                                              int* __restrict__ rowp, int* __restrict__ cursor){
  __shared__ int part[256];
  __shared__ int pref[257];
  const int t = threadIdx.x;
  const int base = t*64;
  int s = 0;
  for (int i=0;i<64;i++) s += cnt[base+i];
  part[t] = s; __syncthreads();
  if (t==0){ int a=0; for (int i=0;i<256;i++){ pref[i]=a; a+=part[i]; } pref[256]=a; }
  __syncthreads();
  int a = pref[t];
  for (int i=0;i<64;i++){ rowp[base+i]=a; cursor[base+i]=a; a += cnt[base+i]; }
  if (t==0) rowp[N_NODES] = pref[256];
}
__global__ __launch_bounds__(256) void k_fill(const int* __restrict__ eidx,
                                              int* __restrict__ cursor, int* __restrict__ perm){
  int e = blockIdx.x*256 + threadIdx.x;
  if (e < N_EDGES){
    int pos = atomicAdd(&cursor[eidx[N_EDGES+e]], 1);
    perm[pos] = e;
  }
}

// ---------------- Kernel 1: node separable LN (scalars bf16, vectors f16) ----------------
__global__ __launch_bounds__(256) void k_node_ln(
    const float* __restrict__ nf, const float* __restrict__ g0,
    const float* __restrict__ b0, const float* __restrict__ g1,
    unsigned short* __restrict__ ns_ln, _Float16* __restrict__ nv_ln)
{
  const int tid  = threadIdx.x;
  const int lane = tid & 63;
  const int n    = blockIdx.x*4 + (tid>>6);
  const float* row = nf + (size_t)n*320;

  float s0 = row[lane], s1 = row[64+lane];
  float mu = wsum64(s0+s1) * (1.0f/128.0f);
  float d0 = s0-mu, d1 = s1-mu;
  float var = wsum64(d0*d0+d1*d1) * (1.0f/128.0f);
  float rs = rsqrtf(var + EPSF);
  ns_ln[(size_t)n*128 + lane]    = f2bf(d0*rs*g0[lane]    + b0[lane]);
  ns_ln[(size_t)n*128 + 64+lane] = f2bf(d1*rs*g0[64+lane] + b0[64+lane]);

  float px = row[128+lane*3+0], py = row[128+lane*3+1], pz = row[128+lane*3+2];
  float vvar = wsum64(px*px+py*py+pz*pz) * (1.0f/192.0f);
  float vsc = rsqrtf(vvar + EPSF) * g1[lane];
  nv_ln[(size_t)n*192 + lane*3+0] = (_Float16)(px*vsc);
  nv_ln[(size_t)n*192 + lane*3+1] = (_Float16)(py*vsc);
  nv_ln[(size_t)n*192 + lane*3+2] = (_Float16)(pz*vsc);
}

// ---------------- Kernel 2: edge message kernel (MFMA, 32 edges/block, slot order) ----------------
__global__ __launch_bounds__(256,4) void k_edge(
  const float* __restrict__ ef, const float* __restrict__ evec,
  const float* __restrict__ lats,
  const float* __restrict__ g0e, const float* __restrict__ b0e, const float* __restrict__ g1e,
  const unsigned short* __restrict__ pWm0, const unsigned short* __restrict__ pWc,
  const unsigned short* __restrict__ pWenv, const unsigned short* __restrict__ pWp0,
  const unsigned short* __restrict__ pWpv,
  const float* __restrict__ bp0,
  const int* __restrict__ eidx, const int* __restrict__ perm,
  const unsigned short* __restrict__ ns_ln, const _Float16* __restrict__ nv_ln,
  float* __restrict__ sa, float* __restrict__ va)
{
  extern __shared__ unsigned char pool[];
  const int tid = threadIdx.x;
  unsigned short* XE   = (unsigned short*)(pool + OFF_XE);
  unsigned short* C12s = (unsigned short*)(pool + OFF_C12);
  _Float16* FRh = (_Float16*)(pool + OFF_FR);
  int* EDST = (int*)(pool + OFF_EDST);
  int* ESRC = (int*)(pool + OFF_ESRC);

  // XCD-aware swizzle: contiguous slot span per XCD (nwg = 8192, %8 == 0)
  const int nwg = gridDim.x;
  const int bswz = (blockIdx.x & 7)*(nwg>>3) + (blockIdx.x >> 3);

  const int wid = tid>>6, l = tid&63;
  const int r15 = l&15, g = l>>4;
  const int sbase = bswz*32;

  // ---------------- Phase A: prep (4 passes of 8 edges, 32 lanes/edge) ----------------
  {
    const int ln = tid & 31;
    #pragma unroll
    for (int eo=0; eo<4; ++eo){
      const int el = eo*8 + (tid>>5);
      const int slot = sbase + el;
      const size_t e = (size_t)perm[slot];
      const int src = eidx[e];
      const int dst = eidx[N_EDGES + e];

      float vx=evec[e*3+0], vy=evec[e*3+1], vz=evec[e*3+2];
      float rn = rsqrtf(vx*vx+vy*vy+vz*vz+EPSF);
      float ax=vx*rn, ay=vy*rn, az=vz*rn;
      float hx, hz;
      if (fabsf(az) < 0.99f){ hx=0.f; hz=1.f; } else { hx=1.f; hz=0.f; }
      float e1x = -hz*ay;
      float e1y = hz*ax - hx*az;
      float e1z = hx*ay;
      float rn1 = rsqrtf(e1x*e1x+e1y*e1y+e1z*e1z+EPSF);
      e1x*=rn1; e1y*=rn1; e1z*=rn1;
      float e2x = ay*e1z - az*e1y;
      float e2y = az*e1x - ax*e1z;
      float e2z = ax*e1y - ay*e1x;
      if (ln==0){
        FRh[el*12+0]=(_Float16)ax;  FRh[el*12+1]=(_Float16)ay;  FRh[el*12+2]=(_Float16)az;
        FRh[el*12+3]=(_Float16)e1x; FRh[el*12+4]=(_Float16)e1y; FRh[el*12+5]=(_Float16)e1z;
        FRh[el*12+6]=(_Float16)e2x; FRh[el*12+7]=(_Float16)e2y; FRh[el*12+8]=(_Float16)e2z;
        EDST[el]=dst;
        ESRC[el]=src;
      }

      const float* erow = ef + e*160;
      float s0=erow[ln], s1=erow[32+ln];
      float mu = wsum32(s0+s1)*(1.f/64.f);
      float d0=s0-mu, d1=s1-mu;
      float var = wsum32(d0*d0+d1*d1)*(1.f/64.f);
      float rs = rsqrtf(var+EPSF);
      XE[el*232 + ln]    = f2bf(d0*rs*g0e[ln]    + b0e[ln]);
      XE[el*232 + 32+ln] = f2bf(d1*rs*g0e[32+ln] + b0e[32+ln]);

      float wx=erow[64+ln*3+0], wy=erow[64+ln*3+1], wz=erow[64+ln*3+2];
      float vvar = wsum32(wx*wx+wy*wy+wz*wz)*(1.f/96.f);
      float vsc = rsqrtf(vvar+EPSF)*g1e[ln];
      wx*=vsc; wy*=vsc; wz*=vsc;
      XE  [el*232 + 64+64+ln]    = f2bf(wx*ax +wy*ay +wz*az);
      C12s[el*328 + 64+ln]       = f2bf(wx*e1x+wy*e1y+wz*e1z);
      C12s[el*328 + 160+64+ln]   = f2bf(wx*e2x+wy*e2y+wz*e2z);

      const _Float16* nvs = nv_ln + (size_t)src*192;
      const _Float16* nvd = nv_ln + (size_t)dst*192;
      #pragma unroll
      for (int q=0;q<2;q++){
        int u = ln+32*q;
        float px=(float)nvs[u*3+0], py=(float)nvs[u*3+1], pz=(float)nvs[u*3+2];
        XE  [el*232 + 64+u]      = f2bf(px*ax +py*ay +pz*az);
        C12s[el*328 + u]         = f2bf(px*e1x+py*e1y+pz*e1z);
        C12s[el*328 + 160+u]     = f2bf(px*e2x+py*e2y+pz*e2z);
        px=(float)nvd[u*3+0]; py=(float)nvd[u*3+1]; pz=(float)nvd[u*3+2];
        XE  [el*232 + 64+96+u]   = f2bf(px*ax +py*ay +pz*az);
        C12s[el*328 + 96+u]      = f2bf(px*e1x+py*e1y+pz*e1z);
        C12s[el*328 + 160+96+u]  = f2bf(px*e2x+py*e2y+pz*e2z);
      }
    }
  }
  __syncthreads();

  const f32x4 zero4 = {0.f,0.f,0.f,0.f};

  // G1: m0 = X[32x480] @ Wm0[480x256]
  f32x4 acc1[2][4];
  #pragma unroll
  for (int m=0;m<2;m++)
    #pragma unroll
    for (int n=0;n<4;n++) acc1[m][n]=zero4;
  {
    const unsigned short* bbase = pWm0 + ((size_t)(wid*64 + r15)*4 + g)*8;
    bf16x8 gA[2][8];
    {
      const int rs0 = ESRC[r15], rs1 = ESRC[16+r15];
      const int rd0 = EDST[r15], rd1 = EDST[16+r15];
      #pragma unroll
      for (int q=0;q<4;q++){
        gA[0][q]   = *(const bf16x8*)&ns_ln[(size_t)rs0*128 + q*32 + g*8];
        gA[1][q]   = *(const bf16x8*)&ns_ln[(size_t)rs1*128 + q*32 + g*8];
        gA[0][4+q] = *(const bf16x8*)&ns_ln[(size_t)rd0*128 + q*32 + g*8];
        gA[1][4+q] = *(const bf16x8*)&ns_ln[(size_t)rd1*128 + q*32 + g*8];
      }
    }
    #pragma unroll
    for (int t=0;t<7;t++){
      const int kc  = (t<2) ? (4+t) : (10 + t-2);
      const int col = (t<2) ? (t*32) : (64 + (t-2)*32);
      bf16x8 a0 = *(const bf16x8*)&XE[(    r15)*232 + col + g*8];
      bf16x8 a1 = *(const bf16x8*)&XE[(16+ r15)*232 + col + g*8];
      const unsigned short* bp = bbase + (size_t)kc*8192;
      #pragma unroll
      for (int n=0;n<4;n++){
        bf16x8 b = *(const bf16x8*)(bp + n*512);
        acc1[0][n] = MFMA16(a0,b,acc1[0][n]);
        acc1[1][n] = MFMA16(a1,b,acc1[1][n]);
      }
    }
    #pragma unroll
    for (int t=0;t<8;t++){
      const int kc = (t<4) ? t : (6 + t-4);
      const unsigned short* bp = bbase + (size_t)kc*8192;
      #pragma unroll
      for (int n=0;n<4;n++){
        bf16x8 b = *(const bf16x8*)(bp + n*512);
        acc1[0][n] = MFMA16(gA[0][t],b,acc1[0][n]);
        acc1[1][n] = MFMA16(gA[1][t],b,acc1[1][n]);
      }
    }
  }

  // G2: c12o = C12[32x320] @ Wc[320x128]
  f32x4 acc2[2][2];
  #pragma unroll
  for (int m=0;m<2;m++){ acc2[m][0]=zero4; acc2[m][1]=zero4; }
  {
    const unsigned short* bbase = pWc + ((size_t)(wid*32 + r15)*4 + g)*8;
    #pragma unroll
    for (int kc=0;kc<10;kc++){
      bf16x8 a0 = *(const bf16x8*)&C12s[(    r15)*328 + kc*32 + g*8];
      bf16x8 a1 = *(const bf16x8*)&C12s[(16+ r15)*328 + kc*32 + g*8];
      const unsigned short* bp = bbase + (size_t)kc*4096;
      #pragma unroll
      for (int n=0;n<2;n++){
        bf16x8 b = *(const bf16x8*)(bp + n*512);
        acc2[0][n] = MFMA16(a0,b,acc2[0][n]);
        acc2[1][n] = MFMA16(a1,b,acc2[1][n]);
      }
    }
  }

  // ---------------- G3 (in-wave, post-G2): w = lats[32x128] @ Wenv col-tiles ----------------
  // Placed here so the random lats gather overlaps the barrier drain + other waves' MFMA,
  // instead of serializing at the head of the kernel (round-11 lesson).
  float wsc[2][2][4], wvc[2][4];
  {
    f32x4 acc3[2][3];
    #pragma unroll
    for (int m=0;m<2;m++)
      #pragma unroll
      for (int n=0;n<3;n++) acc3[m][n]=zero4;
    const int eg0 = perm[sbase + r15];
    const int eg1 = perm[sbase + 16 + r15];
    const float* la0 = lats + (size_t)eg0*128;
    const float* la1 = lats + (size_t)eg1*128;
    const int colb0 = wid*32, colb1 = wid*32+16, colb2 = 128+wid*16;
    #pragma unroll
    for (int kc=0;kc<4;kc++){
      float4 f00 = *(const float4*)&la0[kc*32 + g*8];
      float4 f01 = *(const float4*)&la0[kc*32 + g*8 + 4];
      float4 f10 = *(const float4*)&la1[kc*32 + g*8];
      float4 f11 = *(const float4*)&la1[kc*32 + g*8 + 4];
      union { bf16x8 v; unsigned short s[8]; } a0, a1;
      a0.s[0]=f2bf(f00.x); a0.s[1]=f2bf(f00.y); a0.s[2]=f2bf(f00.z); a0.s[3]=f2bf(f00.w);
      a0.s[4]=f2bf(f01.x); a0.s[5]=f2bf(f01.y); a0.s[6]=f2bf(f01.z); a0.s[7]=f2bf(f01.w);
      a1.s[0]=f2bf(f10.x); a1.s[1]=f2bf(f10.y); a1.s[2]=f2bf(f10.z); a1.s[3]=f2bf(f10.w);
      a1.s[4]=f2bf(f11.x); a1.s[5]=f2bf(f11.y); a1.s[6]=f2bf(f11.z); a1.s[7]=f2bf(f11.w);
      bf16x8 b0 = *(const bf16x8*)(pWenv + ((size_t)(kc*192 + colb0 + r15)*4 + g)*8);
      bf16x8 b1 = *(const bf16x8*)(pWenv + ((size_t)(kc*192 + colb1 + r15)*4 + g)*8);
      bf16x8 b2 = *(const bf16x8*)(pWenv + ((size_t)(kc*192 + colb2 + r15)*4 + g)*8);
      acc3[0][0] = MFMA16(a0.v,b0,acc3[0][0]);
      acc3[1][0] = MFMA16(a1.v,b0,acc3[1][0]);
      acc3[0][1] = MFMA16(a0.v,b1,acc3[0][1]);
      acc3[1][1] = MFMA16(a1.v,b1,acc3[1][1]);
      acc3[0][2] = MFMA16(a0.v,b2,acc3[0][2]);
      acc3[1][2] = MFMA16(a1.v,b2,acc3[1][2]);
    }
    const float S = 0.08838834764831845f;  // 1/sqrt(128)
    #pragma unroll
    for (int m=0;m<2;m++)
      #pragma unroll
      for (int r=0;r<4;r++){
        wsc[m][0][r] = acc3[m][0][r]*S;
        wsc[m][1][r] = acc3[m][1][r]*S;
        wvc[m][r]    = acc3[m][2][r]*S;
      }
  }

  // bias prefetch
  float bp0v[2];
  #pragma unroll
  for (int n=0;n<2;n++) bp0v[n] = bp0[wid*32 + n*16 + r15];

  __syncthreads();   // all waves done reading XE/C12

  // G1/G2 epilogues -> overlays (bf16)
  {
    unsigned short* SAs = (unsigned short*)(pool + OFF_SACT);
    unsigned short* GAb = (unsigned short*)(pool + OFF_GATE);
    unsigned short* C0b = (unsigned short*)(pool + OFF_C0O);
    #pragma unroll
    for (int m=0;m<2;m++)
      #pragma unroll
      for (int n=0;n<4;n++)
        #pragma unroll
        for (int r=0;r<4;r++){
          int e = m*16 + g*4 + r;
          int j = wid*64 + n*16 + r15;
          float v = acc1[m][n][r]*0.04564354645876384f;  // 1/sqrt(480)
          if (j < 128)      SAs[e*136 + j] = f2bf(silu(v));
          else if (j < 192) GAb[e*72 + (j-128)] = f2bf(sigm(v));
          else              C0b[e*72 + (j-192)] = f2bf(v);
        }
    unsigned short* C1b = (unsigned short*)(pool + OFF_C1O);
    unsigned short* C2b = (unsigned short*)(pool + OFF_C2O);
    #pragma unroll
    for (int m=0;m<2;m++)
      #pragma unroll
      for (int n=0;n<2;n++)
        #pragma unroll
        for (int r=0;r<4;r++){
          int e = m*16 + g*4 + r;
          int j = wid*32 + n*16 + r15;
          float v = acc2[m][n][r]*0.07905694150420949f;  // 1/sqrt(160)
          if (j < 64) C1b[e*72 + j] = f2bf(v);
          else        C2b[e*72 + (j-64)] = f2bf(v);
        }
  }
  __syncthreads();

  // C1: v_g = (c0o*a + c1o*e1 + c2o*e2)*gate -> VG bf16 (8 u's/thread)
  {
    const int e = tid>>3, u0 = (tid&7)*8;
    const unsigned short* GAb = (const unsigned short*)(pool + OFF_GATE);
    const unsigned short* C0b = (const unsigned short*)(pool + OFF_C0O);
    const unsigned short* C1b = (const unsigned short*)(pool + OFF_C1O);
    const unsigned short* C2b = (const unsigned short*)(pool + OFF_C2O);
    float ax=(float)FRh[e*12+0],  ay=(float)FRh[e*12+1],  az=(float)FRh[e*12+2];
    float b1x=(float)FRh[e*12+3], b1y=(float)FRh[e*12+4], b1z=(float)FRh[e*12+5];
    float b2x=(float)FRh[e*12+6], b2y=(float)FRh[e*12+7], b2z=(float)FRh[e*12+8];
    float vgx[8], vgy[8], vgz[8];
    #pragma unroll
    for (int i=0;i<8;i++){
      int u = u0+i;
      float gt = bf2f(GAb[e*72+u]);
      float c0 = bf2f(C0b[e*72+u]), c1 = bf2f(C1b[e*72+u]), c2 = bf2f(C2b[e*72+u]);
      vgx[i] = (c0*ax + c1*b1x + c2*b2x)*gt;
      vgy[i] = (c0*ay + c1*b1y + c2*b2y)*gt;
      vgz[i] = (c0*az + c1*b1z + c2*b2z)*gt;
    }
    __syncthreads();   // GATE/C0O/C1O reads done before VG overlay writes
    unsigned short* VGs = (unsigned short*)(pool + OFF_VG);
    #pragma unroll
    for (int i=0;i<8;i++){
      VGs[0*2304 + e*72 + u0+i] = f2bf(vgx[i]);
      VGs[1*2304 + e*72 + u0+i] = f2bf(vgy[i]);
      VGs[2*2304 + e*72 + u0+i] = f2bf(vgz[i]);
    }
  }
  __syncthreads();

  // G4: s2 = SACT @ Wp0 ; G5: v2c = VG[c] @ Wpv
  {
    const unsigned short* SAs = (const unsigned short*)(pool + OFF_SACT);
    const unsigned short* VGs = (const unsigned short*)(pool + OFF_VG);

    f32x4 acc4[2][2], acc5[3][2];
    #pragma unroll
    for (int m=0;m<2;m++){ acc4[m][0]=zero4; acc4[m][1]=zero4; }
    #pragma unroll
    for (int c=0;c<3;c++){ acc5[c][0]=zero4; acc5[c][1]=zero4; }

    {
      const unsigned short* bbase = pWp0 + ((size_t)(wid*32 + r15)*4 + g)*8;
      #pragma unroll
      for (int kc=0;kc<4;kc++){
        bf16x8 a0 = *(const bf16x8*)&SAs[(    r15)*136 + kc*32 + g*8];
        bf16x8 a1 = *(const bf16x8*)&SAs[(16+ r15)*136 + kc*32 + g*8];
        #pragma unroll
        for (int n=0;n<2;n++){
          bf16x8 b = *(const bf16x8*)(bbase + (size_t)kc*4096 + n*512);
          acc4[0][n] = MFMA16(a0,b,acc4[0][n]);
          acc4[1][n] = MFMA16(a1,b,acc4[1][n]);
        }
      }
    }
    {
      bf16x8 b5[2];
      #pragma unroll
      for (int kc=0;kc<2;kc++)
        b5[kc] = *(const bf16x8*)(pWpv + ((size_t)(kc*64 + wid*16 + r15)*4 + g)*8);
      #pragma unroll
      for (int c=0;c<3;c++)
        #pragma unroll
        for (int kc=0;kc<2;kc++){
          bf16x8 a0 = *(const bf16x8*)&VGs[c*2304 + (    r15)*72 + kc*32 + g*8];
          bf16x8 a1 = *(const bf16x8*)&VGs[c*2304 + (16+ r15)*72 + kc*32 + g*8];
          acc5[c][0] = MFMA16(a0,b5[kc],acc5[c][0]);
          acc5[c][1] = MFMA16(a1,b5[kc],acc5[c][1]);
        }
    }

    __syncthreads();   // all waves done reading SACT/VG before R overlay
    _Float16* R = (_Float16*)pool;   // f16 [32][320]
    #pragma unroll
    for (int m=0;m<2;m++)
      #pragma unroll
      for (int n=0;n<2;n++)
        #pragma unroll
        for (int r=0;r<4;r++){
          int e = m*16 + g*4 + r;
          int j = wid*32 + n*16 + r15;
          R[e*320 + j] = (_Float16)((acc4[m][n][r]*0.08838834764831845f + bp0v[n]) * wsc[m][n][r]);
        }
    #pragma unroll
    for (int c=0;c<3;c++)
      #pragma unroll
      for (int m=0;m<2;m++)
        #pragma unroll
        for (int r=0;r<4;r++){
          int e = m*16 + g*4 + r;
          int vch = wid*16 + r15;
          R[e*320 + 128 + vch*3 + c] = (_Float16)(acc5[c][m][r]*0.125f * wvc[m][r]);
        }
    __syncthreads();

    // segmented reduction over dst runs (slot order => sorted dst), then atomics
    for (int j = tid; j < 320; j += 256){
      float accv = (float)R[j];
      int cur = EDST[0];
      for (int e=1;e<32;e++){
        int d = EDST[e];
        float v = (float)R[e*320 + j];
        if (d != cur){
          float* tgt = (j<128) ? &sa[(size_t)cur*128 + j] : &va[(size_t)cur*192 + (j-128)];
          atomicAdd(tgt, accv);
          accv = v; cur = d;
        } else accv += v;
      }
      float* tgt = (j<128) ? &sa[(size_t)cur*128 + j] : &va[(size_t)cur*192 + (j-128)];
      atomicAdd(tgt, accv);
    }
  }
}

// ---------------- Kernel 3: per-node head + residual ----------------
__global__ __launch_bounds__(256) void k_node_out(
  const float* __restrict__ nf, const float* __restrict__ oh,
  const float* __restrict__ Wtp0, const float* __restrict__ Wtp1,
  const float* __restrict__ Wo0, const float* __restrict__ bo0,
  const float* __restrict__ Wov, const float* __restrict__ resp,
  const float* __restrict__ sa, const float* __restrict__ va,
  float* __restrict__ out)
{
  __shared__ float SAB[4][128];
  __shared__ float VX[4][64], VY[4][64], VZ[4][64];
  __shared__ float S3 [4][128];
  __shared__ float V3 [4][256];
  const int tid=threadIdx.x, lane=tid&63, g=tid>>6;
  const int n = blockIdx.x*4 + g;

  float cf=0.f;
  #pragma unroll
  for (int j=0;j<16;j++) cf += j*oh[(size_t)n*16+j];
  const int c = (int)(cf+0.5f);

  SAB[g][lane]    = sa[(size_t)n*128+lane]   *0.25f;
  SAB[g][64+lane] = sa[(size_t)n*128+64+lane]*0.25f;
  VX[g][lane] = va[(size_t)n*192+lane*3+0]*0.25f;
  VY[g][lane] = va[(size_t)n*192+lane*3+1]*0.25f;
  VZ[g][lane] = va[(size_t)n*192+lane*3+2]*0.25f;
  __syncthreads();

  float t00=0.f, t01=0.f, t02=0.f;
  const float* w0c = Wtp0 + (size_t)c*192;
  for (int u=0;u<128;u++){
    float s = SAB[g][u];
    t00 += s * w0c[(size_t)u*3072 + lane];
    t01 += s * w0c[(size_t)u*3072 + lane+64];
    t02 += s * w0c[(size_t)u*3072 + lane+128];
  }
  const float sct0 = 0.02209708691f; // 1/sqrt(2048)
  t00*=sct0; t01*=sct0; t02*=sct0;

  float t1x=0.f,t1y=0.f,t1z=0.f;
  const float* w1c = Wtp1 + (size_t)c*64;
  for (int u=0;u<64;u++){
    float wv = w1c[(size_t)u*1024 + lane];
    t1x += VX[g][u]*wv;
    t1y += VY[g][u]*wv;
    t1z += VZ[g][u]*wv;
  }
  t1x*=0.03125f; t1y*=0.03125f; t1z*=0.03125f;

  S3[g][lane]    = silu(t00);
  S3[g][64+lane] = silu(t01);
  float g2 = sigm(t02);
  float4 v3v = {t1x*g2, t1y*g2, t1z*g2, 0.f};
  *(float4*)&V3[g][lane*4] = v3v;
  __syncthreads();

  float s40=0.f, s41=0.f;
  for (int k=0;k<128;k++){
    float s3k = S3[g][k];
    s40 += s3k*Wo0[k*128+lane];
    s41 += s3k*Wo0[k*128+64+lane];
  }
  s40 = s40*0.08838834765f + bo0[lane];
  s41 = s41*0.08838834765f + bo0[64+lane];

  float v4x=0.f,v4y=0.f,v4z=0.f;
  for (int u=0;u<64;u++){
    float4 v3u = *(const float4*)&V3[g][u*4];
    float wv = Wov[u*64+lane];
    v4x += v3u.x*wv; v4y += v3u.y*wv; v4z += v3u.z*wv;
  }
  v4x*=0.125f; v4y*=0.125f; v4z*=0.125f;

  const float r = sigm(resp[0]);
  const float* row = nf + (size_t)n*320;
  float* orow = out + (size_t)n*320;
  orow[lane]      = r*row[lane]      + (1.f-r)*s40;
  orow[64+lane]   = r*row[64+lane]   + (1.f-r)*s41;
  orow[128+lane*3+0] = r*row[128+lane*3+0] + (1.f-r)*v4x;
  orow[128+lane*3+1] = r*row[128+lane*3+1] + (1.f-r)*v4y;
  orow[128+lane*3+2] = r*row[128+lane*3+2] + (1.f-r)*v4z;
}

extern "C" void kernel_launch(void* const* d_in, const int* in_sizes, int n_in,
                              void* d_out, int out_size, void* d_ws, size_t ws_size,
                              hipStream_t stream)
{
  const float* nf   = (const float*)d_in[0];
  const float* ef   = (const float*)d_in[1];
  const float* evec = (const float*)d_in[2];
  const float* lats = (const float*)d_in[3];
  const float* oh   = (const float*)d_in[4];
  const float* g0n  = (const float*)d_in[5];
  const float* b0n  = (const float*)d_in[6];
  const float* g1n  = (const float*)d_in[7];
  const float* g0e  = (const float*)d_in[8];
  const float* b0e  = (const float*)d_in[9];
  const float* g1e  = (const float*)d_in[10];
  const float* Wm0  = (const float*)d_in[11];
  const float* wr   = (const float*)d_in[12];
  const float* wi   = (const float*)d_in[13];
  const float* Wenv = (const float*)d_in[14];
  const float* Wp0  = (const float*)d_in[15];
  const float* bp0  = (const float*)d_in[16];
  const float* Wpv  = (const float*)d_in[17];
  const float* Wtp0 = (const float*)d_in[18];
  const float* Wtp1 = (const float*)d_in[19];
  const float* Wo0  = (const float*)d_in[20];
  const float* bo0  = (const float*)d_in[21];
  const float* Wov  = (const float*)d_in[22];
  const float* resp = (const float*)d_in[23];
  const int*   eidx = (const int*)d_in[24];

  char* base = (char*)d_ws;
  unsigned short* ns_ln = (unsigned short*)(base);            // 4,194,304 B
  _Float16* nv_ln = (_Float16*)(base + 4194304);              // 6,291,456 -> 10,485,760
  float* sa    = (float*)(base + 10485760);                   // 8,388,608 -> 18,874,368
  float* va    = (float*)(base + 18874368);                   // 12,582,912 -> 31,457,280
  unsigned short* wpk = (unsigned short*)(base + 31457280);   // 417,792   -> 31,875,072
  unsigned short* pWm0  = wpk;            // 480*256
  unsigned short* pWc   = wpk + 122880;   // 320*128
  unsigned short* pWenv = wpk + 163840;   // 128*192
  unsigned short* pWp0  = wpk + 188416;   // 128*128
  unsigned short* pWpv  = wpk + 204800;   //  64*64
  int* ibuf   = (int*)(base + 31875072);                      // 311,297 ints
  int* cnt    = ibuf;
  int* rowp   = ibuf + 16384;
  int* cursor = ibuf + 32769;
  int* perm   = ibuf + 49153;

  hipMemsetAsync(sa, 0, (size_t)N_NODES*320*sizeof(float), stream);
  hipMemsetAsync(cnt, 0, N_NODES*sizeof(int), stream);

  k_pack_all<<<(208896+255)/256, 256, 0, stream>>>(Wm0, wr, wi, Wenv, Wp0, Wpv, wpk);
  k_node_ln<<<N_NODES/4, 256, 0, stream>>>(nf, g0n, b0n, g1n, ns_ln, nv_ln);

  k_hist<<<(N_EDGES+255)/256, 256, 0, stream>>>(eidx, cnt);
  k_scan<<<1, 256, 0, stream>>>(cnt, rowp, cursor);
  k_fill<<<(N_EDGES+255)/256, 256, 0, stream>>>(eidx, cursor, perm);

  k_edge<<<N_EDGES/32, 256, POOL_BYTES, stream>>>(ef, evec, lats, g0e, b0e, g1e,
                                                  pWm0, pWc, pWenv, pWp0, pWpv, bp0,
                                                  eidx, perm, ns_ln, nv_ln,
                                                  sa, va);
  k_node_out<<<N_NODES/4, 256, 0, stream>>>(nf, oh, Wtp0, Wtp1, Wo0, bo0, Wov,
                                            resp, sa, va, (float*)d_out);
}

// Round 14
// 564.601 us; speedup vs baseline: 1.3047x; 1.0244x over previous
//
#include <hip/hip_runtime.h>
#include <math.h>

#define N_NODES 16384
#define N_EDGES 262144
#define EPSF 1e-8f

// ---------------- LDS pool layout (bytes), 32 edges/block ----------------
#define OFF_XE    0        // bf16 [32][232] = 14848   (LN 0..63, c0 64..223)
#define OFF_C12   14848    // bf16 [32][328] = 20992 -> 35840
#define OFF_FR    35840    // f16  [32][12]  =   768 -> 36608 (persistent)
#define OFF_EDST  36608    // int  [32]      =   128 -> 36736 (persistent)
#define OFF_ESRC  36736    // int  [32]      =   128 -> 36864 (persistent)
#define POOL_BYTES 36864   // 4 blocks/CU
// overlays (after G1/G2 done reading XE/C12)
#define OFF_SACT  0        // bf16 [32][136] = 8704
#define OFF_GATE  8704     // bf16 [32][72]  = 4608 -> 13312
#define OFF_C0O   13312    // bf16 [32][72]  = 4608 -> 17920
#define OFF_C1O   17920    // bf16 [32][72]  = 4608 -> 22528
#define OFF_C2O   22528    // bf16 [32][72]  = 4608 -> 27136
#define OFF_VG    8704     // bf16 [3][32][72] = 13824 -> 22528 (over GATE/C0O/C1O after consumed)
// final overlay: R f16 [32][320] = 20480 at 0 (after SACT/VG consumed)

typedef __bf16 bf16x8 __attribute__((ext_vector_type(8)));
typedef float  f32x4  __attribute__((ext_vector_type(4)));

__device__ __forceinline__ f32x4 MFMA16(bf16x8 a, bf16x8 b, f32x4 c){
  return __builtin_amdgcn_mfma_f32_16x16x32_bf16(a, b, c, 0, 0, 0);
}

__device__ __forceinline__ unsigned short f2bf(float x){
  __bf16 h = (__bf16)x;
  union { __bf16 b; unsigned short u; } c; c.b = h;
  return c.u;
}
__device__ __forceinline__ float bf2f(unsigned short h){
  union { unsigned u; float f; } c; c.u = ((unsigned)h)<<16;
  return c.f;
}
__device__ __forceinline__ float wsum32(float v){
  #pragma unroll
  for (int m=1; m<32; m<<=1) v += __shfl_xor(v, m);
  return v;
}
__device__ __forceinline__ float wsum64(float v){
  #pragma unroll
  for (int m=1; m<64; m<<=1) v += __shfl_xor(v, m);
  return v;
}
__device__ __forceinline__ float sigm(float x){ return 1.0f/(1.0f+__expf(-x)); }
__device__ __forceinline__ float silu(float x){ return x/(1.0f+__expf(-x)); }

// ---------------- fused weight pack kernel (B-fragment layout) ----------------
__global__ __launch_bounds__(256) void k_pack_all(
  const float* __restrict__ Wm0, const float* __restrict__ wr,
  const float* __restrict__ wi,  const float* __restrict__ Wenv,
  const float* __restrict__ Wp0, const float* __restrict__ Wpv,
  unsigned short* __restrict__ wpk)
{
  int i = blockIdx.x*256 + threadIdx.x;
  if (i < 122880){                       // Wm0 [480][256]
    int k = i >> 8, n = i & 255;
    int idx = (((k>>5)*256 + n)*4 + ((k>>3)&3))*8 + (k&7);
    wpk[idx] = f2bf(Wm0[i]);
  } else if (i < 163840){                // Wc [320][128] = [[wr,wi],[-wi,wr]]
    int j = i - 122880;
    int k = j >> 7, n = j & 127;
    float v;
    if (k < 160) v = (n < 64) ? wr[k*64 + n]        : wi[k*64 + (n-64)];
    else         v = (n < 64) ? -wi[(k-160)*64 + n] : wr[(k-160)*64 + (n-64)];
    int idx = (((k>>5)*128 + n)*4 + ((k>>3)&3))*8 + (k&7);
    wpk[122880 + idx] = f2bf(v);
  } else if (i < 188416){                // Wenv [128][192]
    int j = i - 163840;
    int k = j / 192, n = j - k*192;
    int idx = (((k>>5)*192 + n)*4 + ((k>>3)&3))*8 + (k&7);
    wpk[163840 + idx] = f2bf(Wenv[j]);
  } else if (i < 204800){                // Wp0 [128][128]
    int j = i - 188416;
    int k = j >> 7, n = j & 127;
    int idx = (((k>>5)*128 + n)*4 + ((k>>3)&3))*8 + (k&7);
    wpk[188416 + idx] = f2bf(Wp0[j]);
  } else if (i < 208896){                // Wpv [64][64]
    int j = i - 204800;
    int k = j >> 6, n = j & 63;
    int idx = (((k>>5)*64 + n)*4 + ((k>>3)&3))*8 + (k&7);
    wpk[204800 + idx] = f2bf(Wpv[j]);
  }
}

// ---------------- CSR build (perm = edges sorted by dst) ----------------
__global__ __launch_bounds__(256) void k_hist(const int* __restrict__ eidx, int* __restrict__ cnt){
  int e = blockIdx.x*256 + threadIdx.x;
  if (e < N_EDGES) atomicAdd(&cnt[eidx[N_EDGES+e]], 1);
}
__global__ __launch_bounds__(256) void k_scan(const int* __restrict__ cnt,
                                              int* __restrict__ rowp, int* __restrict__ cursor){
  __shared__ int part[256];
  __shared__ int pref[257];
  const int t = threadIdx.x;
  const int base = t*64;
  int s = 0;
  for (int i=0;i<64;i++) s += cnt[base+i];
  part[t] = s; __syncthreads();
  if (t==0){ int a=0; for (int i=0;i<256;i++){ pref[i]=a; a+=part[i]; } pref[256]=a; }
  __syncthreads();
  int a = pref[t];
  for (int i=0;i<64;i++){ rowp[base+i]=a; cursor[base+i]=a; a += cnt[base+i]; }
  if (t==0) rowp[N_NODES] = pref[256];
}
__global__ __launch_bounds__(256) void k_fill(const int* __restrict__ eidx,
                                              int* __restrict__ cursor, int* __restrict__ perm){
  int e = blockIdx.x*256 + threadIdx.x;
  if (e < N_EDGES){
    int pos = atomicAdd(&cursor[eidx[N_EDGES+e]], 1);
    perm[pos] = e;
  }
}

// ---------------- Kernel 1: node separable LN (scalars bf16, vectors f16) ----------------
__global__ __launch_bounds__(256) void k_node_ln(
    const float* __restrict__ nf, const float* __restrict__ g0,
    const float* __restrict__ b0, const float* __restrict__ g1,
    unsigned short* __restrict__ ns_ln, _Float16* __restrict__ nv_ln)
{
  const int tid  = threadIdx.x;
  const int lane = tid & 63;
  const int n    = blockIdx.x*4 + (tid>>6);
  const float* row = nf + (size_t)n*320;

  float s0 = row[lane], s1 = row[64+lane];
  float mu = wsum64(s0+s1) * (1.0f/128.0f);
  float d0 = s0-mu, d1 = s1-mu;
  float var = wsum64(d0*d0+d1*d1) * (1.0f/128.0f);
  float rs = rsqrtf(var + EPSF);
  ns_ln[(size_t)n*128 + lane]    = f2bf(d0*rs*g0[lane]    + b0[lane]);
  ns_ln[(size_t)n*128 + 64+lane] = f2bf(d1*rs*g0[64+lane] + b0[64+lane]);

  float px = row[128+lane*3+0], py = row[128+lane*3+1], pz = row[128+lane*3+2];
  float vvar = wsum64(px*px+py*py+pz*pz) * (1.0f/192.0f);
  float vsc = rsqrtf(vvar + EPSF) * g1[lane];
  nv_ln[(size_t)n*192 + lane*3+0] = (_Float16)(px*vsc);
  nv_ln[(size_t)n*192 + lane*3+1] = (_Float16)(py*vsc);
  nv_ln[(size_t)n*192 + lane*3+2] = (_Float16)(pz*vsc);
}

// ---------------- Kernel 2: edge message kernel (MFMA, 32 edges/block, slot order) ----------------
__global__ __launch_bounds__(256,4) void k_edge(
  const float* __restrict__ ef, const float* __restrict__ evec,
  const float* __restrict__ lats,
  const float* __restrict__ g0e, const float* __restrict__ b0e, const float* __restrict__ g1e,
  const unsigned short* __restrict__ pWm0, const unsigned short* __restrict__ pWc,
  const unsigned short* __restrict__ pWenv, const unsigned short* __restrict__ pWp0,
  const unsigned short* __restrict__ pWpv,
  const float* __restrict__ bp0,
  const int* __restrict__ eidx, const int* __restrict__ perm,
  const unsigned short* __restrict__ ns_ln, const _Float16* __restrict__ nv_ln,
  float* __restrict__ sa, float* __restrict__ va)
{
  extern __shared__ unsigned char pool[];
  const int tid = threadIdx.x;
  unsigned short* XE   = (unsigned short*)(pool + OFF_XE);
  unsigned short* C12s = (unsigned short*)(pool + OFF_C12);
  _Float16* FRh = (_Float16*)(pool + OFF_FR);
  int* EDST = (int*)(pool + OFF_EDST);
  int* ESRC = (int*)(pool + OFF_ESRC);

  // XCD-aware swizzle: contiguous slot span per XCD (nwg = 8192, %8 == 0)
  const int nwg = gridDim.x;
  const int bswz = (blockIdx.x & 7)*(nwg>>3) + (blockIdx.x >> 3);

  const int wid = tid>>6, l = tid&63;
  const int r15 = l&15, g = l>>4;
  const int sbase = bswz*32;

  // ---------------- Phase A: prep (4 passes of 8 edges, 32 lanes/edge) ----------------
  // Index-level prefetch: run all four passes' dependent chains CONCURRENTLY
  // (perm -> eidx -> evec / ef first-level), then the pass bodies start with
  // addresses and first-level data ready.  (MLP fix; Little's-law diagnosis r13.)
  {
    const int ln = tid & 31;
    int pe[4], psrc[4], pdst[4];
    float pvx[4], pvy[4], pvz[4];
    float pef0[4], pef1[4], pwx[4], pwy[4], pwz[4];
    #pragma unroll
    for (int eo=0; eo<4; ++eo){
      const int slot = sbase + eo*8 + (tid>>5);
      const int e = perm[slot];
      pe[eo] = e;
      psrc[eo] = eidx[e];
      pdst[eo] = eidx[N_EDGES + e];
      pvx[eo] = evec[(size_t)e*3+0];
      pvy[eo] = evec[(size_t)e*3+1];
      pvz[eo] = evec[(size_t)e*3+2];
      const float* erow = ef + (size_t)e*160;
      pef0[eo] = erow[ln];
      pef1[eo] = erow[32+ln];
      pwx[eo]  = erow[64+ln*3+0];
      pwy[eo]  = erow[64+ln*3+1];
      pwz[eo]  = erow[64+ln*3+2];
    }

    #pragma unroll
    for (int eo=0; eo<4; ++eo){
      const int el = eo*8 + (tid>>5);
      const int src = psrc[eo];
      const int dst = pdst[eo];

      float vx=pvx[eo], vy=pvy[eo], vz=pvz[eo];
      float rn = rsqrtf(vx*vx+vy*vy+vz*vz+EPSF);
      float ax=vx*rn, ay=vy*rn, az=vz*rn;
      float hx, hz;
      if (fabsf(az) < 0.99f){ hx=0.f; hz=1.f; } else { hx=1.f; hz=0.f; }
      float e1x = -hz*ay;
      float e1y = hz*ax - hx*az;
      float e1z = hx*ay;
      float rn1 = rsqrtf(e1x*e1x+e1y*e1y+e1z*e1z+EPSF);
      e1x*=rn1; e1y*=rn1; e1z*=rn1;
      float e2x = ay*e1z - az*e1y;
      float e2y = az*e1x - ax*e1z;
      float e2z = ax*e1y - ay*e1x;
      if (ln==0){
        FRh[el*12+0]=(_Float16)ax;  FRh[el*12+1]=(_Float16)ay;  FRh[el*12+2]=(_Float16)az;
        FRh[el*12+3]=(_Float16)e1x; FRh[el*12+4]=(_Float16)e1y; FRh[el*12+5]=(_Float16)e1z;
        FRh[el*12+6]=(_Float16)e2x; FRh[el*12+7]=(_Float16)e2y; FRh[el*12+8]=(_Float16)e2z;
        EDST[el]=dst;
        ESRC[el]=src;
      }

      float s0=pef0[eo], s1=pef1[eo];
      float mu = wsum32(s0+s1)*(1.f/64.f);
      float d0=s0-mu, d1=s1-mu;
      float var = wsum32(d0*d0+d1*d1)*(1.f/64.f);
      float rs = rsqrtf(var+EPSF);
      XE[el*232 + ln]    = f2bf(d0*rs*g0e[ln]    + b0e[ln]);
      XE[el*232 + 32+ln] = f2bf(d1*rs*g0e[32+ln] + b0e[32+ln]);

      float wx=pwx[eo], wy=pwy[eo], wz=pwz[eo];
      float vvar = wsum32(wx*wx+wy*wy+wz*wz)*(1.f/96.f);
      float vsc = rsqrtf(vvar+EPSF)*g1e[ln];
      wx*=vsc; wy*=vsc; wz*=vsc;
      XE  [el*232 + 64+64+ln]    = f2bf(wx*ax +wy*ay +wz*az);
      C12s[el*328 + 64+ln]       = f2bf(wx*e1x+wy*e1y+wz*e1z);
      C12s[el*328 + 160+64+ln]   = f2bf(wx*e2x+wy*e2y+wz*e2z);

      const _Float16* nvs = nv_ln + (size_t)src*192;
      const _Float16* nvd = nv_ln + (size_t)dst*192;
      #pragma unroll
      for (int q=0;q<2;q++){
        int u = ln+32*q;
        float px=(float)nvs[u*3+0], py=(float)nvs[u*3+1], pz=(float)nvs[u*3+2];
        XE  [el*232 + 64+u]      = f2bf(px*ax +py*ay +pz*az);
        C12s[el*328 + u]         = f2bf(px*e1x+py*e1y+pz*e1z);
        C12s[el*328 + 160+u]     = f2bf(px*e2x+py*e2y+pz*e2z);
        px=(float)nvd[u*3+0]; py=(float)nvd[u*3+1]; pz=(float)nvd[u*3+2];
        XE  [el*232 + 64+96+u]   = f2bf(px*ax +py*ay +pz*az);
        C12s[el*328 + 96+u]      = f2bf(px*e1x+py*e1y+pz*e1z);
        C12s[el*328 + 160+96+u]  = f2bf(px*e2x+py*e2y+pz*e2z);
      }
    }
  }
  __syncthreads();

  const f32x4 zero4 = {0.f,0.f,0.f,0.f};

  // G1: m0 = X[32x480] @ Wm0[480x256]
  f32x4 acc1[2][4];
  #pragma unroll
  for (int m=0;m<2;m++)
    #pragma unroll
    for (int n=0;n<4;n++) acc1[m][n]=zero4;
  {
    const unsigned short* bbase = pWm0 + ((size_t)(wid*64 + r15)*4 + g)*8;
    bf16x8 gA[2][8];
    {
      const int rs0 = ESRC[r15], rs1 = ESRC[16+r15];
      const int rd0 = EDST[r15], rd1 = EDST[16+r15];
      #pragma unroll
      for (int q=0;q<4;q++){
        gA[0][q]   = *(const bf16x8*)&ns_ln[(size_t)rs0*128 + q*32 + g*8];
        gA[1][q]   = *(const bf16x8*)&ns_ln[(size_t)rs1*128 + q*32 + g*8];
        gA[0][4+q] = *(const bf16x8*)&ns_ln[(size_t)rd0*128 + q*32 + g*8];
        gA[1][4+q] = *(const bf16x8*)&ns_ln[(size_t)rd1*128 + q*32 + g*8];
      }
    }
    #pragma unroll
    for (int t=0;t<7;t++){
      const int kc  = (t<2) ? (4+t) : (10 + t-2);
      const int col = (t<2) ? (t*32) : (64 + (t-2)*32);
      bf16x8 a0 = *(const bf16x8*)&XE[(    r15)*232 + col + g*8];
      bf16x8 a1 = *(const bf16x8*)&XE[(16+ r15)*232 + col + g*8];
      const unsigned short* bp = bbase + (size_t)kc*8192;
      #pragma unroll
      for (int n=0;n<4;n++){
        bf16x8 b = *(const bf16x8*)(bp + n*512);
        acc1[0][n] = MFMA16(a0,b,acc1[0][n]);
        acc1[1][n] = MFMA16(a1,b,acc1[1][n]);
      }
    }
    #pragma unroll
    for (int t=0;t<8;t++){
      const int kc = (t<4) ? t : (6 + t-4);
      const unsigned short* bp = bbase + (size_t)kc*8192;
      #pragma unroll
      for (int n=0;n<4;n++){
        bf16x8 b = *(const bf16x8*)(bp + n*512);
        acc1[0][n] = MFMA16(gA[0][t],b,acc1[0][n]);
        acc1[1][n] = MFMA16(gA[1][t],b,acc1[1][n]);
      }
    }
  }

  // G2: c12o = C12[32x320] @ Wc[320x128]
  f32x4 acc2[2][2];
  #pragma unroll
  for (int m=0;m<2;m++){ acc2[m][0]=zero4; acc2[m][1]=zero4; }
  {
    const unsigned short* bbase = pWc + ((size_t)(wid*32 + r15)*4 + g)*8;
    #pragma unroll
    for (int kc=0;kc<10;kc++){
      bf16x8 a0 = *(const bf16x8*)&C12s[(    r15)*328 + kc*32 + g*8];
      bf16x8 a1 = *(const bf16x8*)&C12s[(16+ r15)*328 + kc*32 + g*8];
      const unsigned short* bp = bbase + (size_t)kc*4096;
      #pragma unroll
      for (int n=0;n<2;n++){
        bf16x8 b = *(const bf16x8*)(bp + n*512);
        acc2[0][n] = MFMA16(a0,b,acc2[0][n]);
        acc2[1][n] = MFMA16(a1,b,acc2[1][n]);
      }
    }
  }

  // ---------------- G3 (in-wave, post-G2): w = lats[32x128] @ Wenv col-tiles ----------------
  float wsc[2][2][4], wvc[2][4];
  {
    f32x4 acc3[2][3];
    #pragma unroll
    for (int m=0;m<2;m++)
      #pragma unroll
      for (int n=0;n<3;n++) acc3[m][n]=zero4;
    const int eg0 = perm[sbase + r15];
    const int eg1 = perm[sbase + 16 + r15];
    const float* la0 = lats + (size_t)eg0*128;
    const float* la1 = lats + (size_t)eg1*128;
    const int colb0 = wid*32, colb1 = wid*32+16, colb2 = 128+wid*16;
    #pragma unroll
    for (int kc=0;kc<4;kc++){
      float4 f00 = *(const float4*)&la0[kc*32 + g*8];
      float4 f01 = *(const float4*)&la0[kc*32 + g*8 + 4];
      float4 f10 = *(const float4*)&la1[kc*32 + g*8];
      float4 f11 = *(const float4*)&la1[kc*32 + g*8 + 4];
      union { bf16x8 v; unsigned short s[8]; } a0, a1;
      a0.s[0]=f2bf(f00.x); a0.s[1]=f2bf(f00.y); a0.s[2]=f2bf(f00.z); a0.s[3]=f2bf(f00.w);
      a0.s[4]=f2bf(f01.x); a0.s[5]=f2bf(f01.y); a0.s[6]=f2bf(f01.z); a0.s[7]=f2bf(f01.w);
      a1.s[0]=f2bf(f10.x); a1.s[1]=f2bf(f10.y); a1.s[2]=f2bf(f10.z); a1.s[3]=f2bf(f10.w);
      a1.s[4]=f2bf(f11.x); a1.s[5]=f2bf(f11.y); a1.s[6]=f2bf(f11.z); a1.s[7]=f2bf(f11.w);
      bf16x8 b0 = *(const bf16x8*)(pWenv + ((size_t)(kc*192 + colb0 + r15)*4 + g)*8);
      bf16x8 b1 = *(const bf16x8*)(pWenv + ((size_t)(kc*192 + colb1 + r15)*4 + g)*8);
      bf16x8 b2 = *(const bf16x8*)(pWenv + ((size_t)(kc*192 + colb2 + r15)*4 + g)*8);
      acc3[0][0] = MFMA16(a0.v,b0,acc3[0][0]);
      acc3[1][0] = MFMA16(a1.v,b0,acc3[1][0]);
      acc3[0][1] = MFMA16(a0.v,b1,acc3[0][1]);
      acc3[1][1] = MFMA16(a1.v,b1,acc3[1][1]);
      acc3[0][2] = MFMA16(a0.v,b2,acc3[0][2]);
      acc3[1][2] = MFMA16(a1.v,b2,acc3[1][2]);
    }
    const float S = 0.08838834764831845f;  // 1/sqrt(128)
    #pragma unroll
    for (int m=0;m<2;m++)
      #pragma unroll
      for (int r=0;r<4;r++){
        wsc[m][0][r] = acc3[m][0][r]*S;
        wsc[m][1][r] = acc3[m][1][r]*S;
        wvc[m][r]    = acc3[m][2][r]*S;
      }
  }

  // bias prefetch
  float bp0v[2];
  #pragma unroll
  for (int n=0;n<2;n++) bp0v[n] = bp0[wid*32 + n*16 + r15];

  __syncthreads();   // all waves done reading XE/C12

  // G1/G2 epilogues -> overlays (bf16)
  {
    unsigned short* SAs = (unsigned short*)(pool + OFF_SACT);
    unsigned short* GAb = (unsigned short*)(pool + OFF_GATE);
    unsigned short* C0b = (unsigned short*)(pool + OFF_C0O);
    #pragma unroll
    for (int m=0;m<2;m++)
      #pragma unroll
      for (int n=0;n<4;n++)
        #pragma unroll
        for (int r=0;r<4;r++){
          int e = m*16 + g*4 + r;
          int j = wid*64 + n*16 + r15;
          float v = acc1[m][n][r]*0.04564354645876384f;  // 1/sqrt(480)
          if (j < 128)      SAs[e*136 + j] = f2bf(silu(v));
          else if (j < 192) GAb[e*72 + (j-128)] = f2bf(sigm(v));
          else              C0b[e*72 + (j-192)] = f2bf(v);
        }
    unsigned short* C1b = (unsigned short*)(pool + OFF_C1O);
    unsigned short* C2b = (unsigned short*)(pool + OFF_C2O);
    #pragma unroll
    for (int m=0;m<2;m++)
      #pragma unroll
      for (int n=0;n<2;n++)
        #pragma unroll
        for (int r=0;r<4;r++){
          int e = m*16 + g*4 + r;
          int j = wid*32 + n*16 + r15;
          float v = acc2[m][n][r]*0.07905694150420949f;  // 1/sqrt(160)
          if (j < 64) C1b[e*72 + j] = f2bf(v);
          else        C2b[e*72 + (j-64)] = f2bf(v);
        }
  }
  __syncthreads();

  // C1: v_g = (c0o*a + c1o*e1 + c2o*e2)*gate -> VG bf16 (8 u's/thread)
  {
    const int e = tid>>3, u0 = (tid&7)*8;
    const unsigned short* GAb = (const unsigned short*)(pool + OFF_GATE);
    const unsigned short* C0b = (const unsigned short*)(pool + OFF_C0O);
    const unsigned short* C1b = (const unsigned short*)(pool + OFF_C1O);
    const unsigned short* C2b = (const unsigned short*)(pool + OFF_C2O);
    float ax=(float)FRh[e*12+0],  ay=(float)FRh[e*12+1],  az=(float)FRh[e*12+2];
    float b1x=(float)FRh[e*12+3], b1y=(float)FRh[e*12+4], b1z=(float)FRh[e*12+5];
    float b2x=(float)FRh[e*12+6], b2y=(float)FRh[e*12+7], b2z=(float)FRh[e*12+8];
    float vgx[8], vgy[8], vgz[8];
    #pragma unroll
    for (int i=0;i<8;i++){
      int u = u0+i;
      float gt = bf2f(GAb[e*72+u]);
      float c0 = bf2f(C0b[e*72+u]), c1 = bf2f(C1b[e*72+u]), c2 = bf2f(C2b[e*72+u]);
      vgx[i] = (c0*ax + c1*b1x + c2*b2x)*gt;
      vgy[i] = (c0*ay + c1*b1y + c2*b2y)*gt;
      vgz[i] = (c0*az + c1*b1z + c2*b2z)*gt;
    }
    __syncthreads();   // GATE/C0O/C1O reads done before VG overlay writes
    unsigned short* VGs = (unsigned short*)(pool + OFF_VG);
    #pragma unroll
    for (int i=0;i<8;i++){
      VGs[0*2304 + e*72 + u0+i] = f2bf(vgx[i]);
      VGs[1*2304 + e*72 + u0+i] = f2bf(vgy[i]);
      VGs[2*2304 + e*72 + u0+i] = f2bf(vgz[i]);
    }
  }
  __syncthreads();

  // G4: s2 = SACT @ Wp0 ; G5: v2c = VG[c] @ Wpv
  {
    const unsigned short* SAs = (const unsigned short*)(pool + OFF_SACT);
    const unsigned short* VGs = (const unsigned short*)(pool + OFF_VG);

    f32x4 acc4[2][2], acc5[3][2];
    #pragma unroll
    for (int m=0;m<2;m++){ acc4[m][0]=zero4; acc4[m][1]=zero4; }
    #pragma unroll
    for (int c=0;c<3;c++){ acc5[c][0]=zero4; acc5[c][1]=zero4; }

    {
      const unsigned short* bbase = pWp0 + ((size_t)(wid*32 + r15)*4 + g)*8;
      #pragma unroll
      for (int kc=0;kc<4;kc++){
        bf16x8 a0 = *(const bf16x8*)&SAs[(    r15)*136 + kc*32 + g*8];
        bf16x8 a1 = *(const bf16x8*)&SAs[(16+ r15)*136 + kc*32 + g*8];
        #pragma unroll
        for (int n=0;n<2;n++){
          bf16x8 b = *(const bf16x8*)(bbase + (size_t)kc*4096 + n*512);
          acc4[0][n] = MFMA16(a0,b,acc4[0][n]);
          acc4[1][n] = MFMA16(a1,b,acc4[1][n]);
        }
      }
    }
    {
      bf16x8 b5[2];
      #pragma unroll
      for (int kc=0;kc<2;kc++)
        b5[kc] = *(const bf16x8*)(pWpv + ((size_t)(kc*64 + wid*16 + r15)*4 + g)*8);
      #pragma unroll
      for (int c=0;c<3;c++)
        #pragma unroll
        for (int kc=0;kc<2;kc++){
          bf16x8 a0 = *(const bf16x8*)&VGs[c*2304 + (    r15)*72 + kc*32 + g*8];
          bf16x8 a1 = *(const bf16x8*)&VGs[c*2304 + (16+ r15)*72 + kc*32 + g*8];
          acc5[c][0] = MFMA16(a0,b5[kc],acc5[c][0]);
          acc5[c][1] = MFMA16(a1,b5[kc],acc5[c][1]);
        }
    }

    __syncthreads();   // all waves done reading SACT/VG before R overlay
    _Float16* R = (_Float16*)pool;   // f16 [32][320]
    #pragma unroll
    for (int m=0;m<2;m++)
      #pragma unroll
      for (int n=0;n<2;n++)
        #pragma unroll
        for (int r=0;r<4;r++){
          int e = m*16 + g*4 + r;
          int j = wid*32 + n*16 + r15;
          R[e*320 + j] = (_Float16)((acc4[m][n][r]*0.08838834764831845f + bp0v[n]) * wsc[m][n][r]);
        }
    #pragma unroll
    for (int c=0;c<3;c++)
      #pragma unroll
      for (int m=0;m<2;m++)
        #pragma unroll
        for (int r=0;r<4;r++){
          int e = m*16 + g*4 + r;
          int vch = wid*16 + r15;
          R[e*320 + 128 + vch*3 + c] = (_Float16)(acc5[c][m][r]*0.125f * wvc[m][r]);
        }
    __syncthreads();

    // segmented reduction over dst runs (slot order => sorted dst), then atomics
    for (int j = tid; j < 320; j += 256){
      float accv = (float)R[j];
      int cur = EDST[0];
      for (int e=1;e<32;e++){
        int d = EDST[e];
        float v = (float)R[e*320 + j];
        if (d != cur){
          float* tgt = (j<128) ? &sa[(size_t)cur*128 + j] : &va[(size_t)cur*192 + (j-128)];
          atomicAdd(tgt, accv);
          accv = v; cur = d;
        } else accv += v;
      }
      float* tgt = (j<128) ? &sa[(size_t)cur*128 + j] : &va[(size_t)cur*192 + (j-128)];
      atomicAdd(tgt, accv);
    }
  }
}

// ---------------- Kernel 3: per-node head + residual ----------------
__global__ __launch_bounds__(256) void k_node_out(
  const float* __restrict__ nf, const float* __restrict__ oh,
  const float* __restrict__ Wtp0, const float* __restrict__ Wtp1,
  const float* __restrict__ Wo0, const float* __restrict__ bo0,
  const float* __restrict__ Wov, const float* __restrict__ resp,
  const float* __restrict__ sa, const float* __restrict__ va,
  float* __restrict__ out)
{
  __shared__ float SAB[4][128];
  __shared__ float VX[4][64], VY[4][64], VZ[4][64];
  __shared__ float S3 [4][128];
  __shared__ float V3 [4][256];
  const int tid=threadIdx.x, lane=tid&63, g=tid>>6;
  const int n = blockIdx.x*4 + g;

  float cf=0.f;
  #pragma unroll
  for (int j=0;j<16;j++) cf += j*oh[(size_t)n*16+j];
  const int c = (int)(cf+0.5f);

  SAB[g][lane]    = sa[(size_t)n*128+lane]   *0.25f;
  SAB[g][64+lane] = sa[(size_t)n*128+64+lane]*0.25f;
  VX[g][lane] = va[(size_t)n*192+lane*3+0]*0.25f;
  VY[g][lane] = va[(size_t)n*192+lane*3+1]*0.25f;
  VZ[g][lane] = va[(size_t)n*192+lane*3+2]*0.25f;
  __syncthreads();

  float t00=0.f, t01=0.f, t02=0.f;
  const float* w0c = Wtp0 + (size_t)c*192;
  for (int u=0;u<128;u++){
    float s = SAB[g][u];
    t00 += s * w0c[(size_t)u*3072 + lane];
    t01 += s * w0c[(size_t)u*3072 + lane+64];
    t02 += s * w0c[(size_t)u*3072 + lane+128];
  }
  const float sct0 = 0.02209708691f; // 1/sqrt(2048)
  t00*=sct0; t01*=sct0; t02*=sct0;

  float t1x=0.f,t1y=0.f,t1z=0.f;
  const float* w1c = Wtp1 + (size_t)c*64;
  for (int u=0;u<64;u++){
    float wv = w1c[(size_t)u*1024 + lane];
    t1x += VX[g][u]*wv;
    t1y += VY[g][u]*wv;
    t1z += VZ[g][u]*wv;
  }
  t1x*=0.03125f; t1y*=0.03125f; t1z*=0.03125f;

  S3[g][lane]    = silu(t00);
  S3[g][64+lane] = silu(t01);
  float g2 = sigm(t02);
  float4 v3v = {t1x*g2, t1y*g2, t1z*g2, 0.f};
  *(float4*)&V3[g][lane*4] = v3v;
  __syncthreads();

  float s40=0.f, s41=0.f;
  for (int k=0;k<128;k++){
    float s3k = S3[g][k];
    s40 += s3k*Wo0[k*128+lane];
    s41 += s3k*Wo0[k*128+64+lane];
  }
  s40 = s40*0.08838834765f + bo0[lane];
  s41 = s41*0.08838834765f + bo0[64+lane];

  float v4x=0.f,v4y=0.f,v4z=0.f;
  for (int u=0;u<64;u++){
    float4 v3u = *(const float4*)&V3[g][u*4];
    float wv = Wov[u*64+lane];
    v4x += v3u.x*wv; v4y += v3u.y*wv; v4z += v3u.z*wv;
  }
  v4x*=0.125f; v4y*=0.125f; v4z*=0.125f;

  const float r = sigm(resp[0]);
  const float* row = nf + (size_t)n*320;
  float* orow = out + (size_t)n*320;
  orow[lane]      = r*row[lane]      + (1.f-r)*s40;
  orow[64+lane]   = r*row[64+lane]   + (1.f-r)*s41;
  orow[128+lane*3+0] = r*row[128+lane*3+0] + (1.f-r)*v4x;
  orow[128+lane*3+1] = r*row[128+lane*3+1] + (1.f-r)*v4y;
  orow[128+lane*3+2] = r*row[128+lane*3+2] + (1.f-r)*v4z;
}

extern "C" void kernel_launch(void* const* d_in, const int* in_sizes, int n_in,
                              void* d_out, int out_size, void* d_ws, size_t ws_size,
                              hipStream_t stream)
{
  const float* nf   = (const float*)d_in[0];
  const float* ef   = (const float*)d_in[1];
  const float* evec = (const float*)d_in[2];
  const float* lats = (const float*)d_in[3];
  const float* oh   = (const float*)d_in[4];
  const float* g0n  = (const float*)d_in[5];
  const float* b0n  = (const float*)d_in[6];
  const float* g1n  = (const float*)d_in[7];
  const float* g0e  = (const float*)d_in[8];
  const float* b0e  = (const float*)d_in[9];
  const float* g1e  = (const float*)d_in[10];
  const float* Wm0  = (const float*)d_in[11];
  const float* wr   = (const float*)d_in[12];
  const float* wi   = (const float*)d_in[13];
  const float* Wenv = (const float*)d_in[14];
  const float* Wp0  = (const float*)d_in[15];
  const float* bp0  = (const float*)d_in[16];
  const float* Wpv  = (const float*)d_in[17];
  const float* Wtp0 = (const float*)d_in[18];
  const float* Wtp1 = (const float*)d_in[19];
  const float* Wo0  = (const float*)d_in[20];
  const float* bo0  = (const float*)d_in[21];
  const float* Wov  = (const float*)d_in[22];
  const float* resp = (const float*)d_in[23];
  const int*   eidx = (const int*)d_in[24];

  char* base = (char*)d_ws;
  unsigned short* ns_ln = (unsigned short*)(base);            // 4,194,304 B
  _Float16* nv_ln = (_Float16*)(base + 4194304);              // 6,291,456 -> 10,485,760
  float* sa    = (float*)(base + 10485760);                   // 8,388,608 -> 18,874,368
  float* va    = (float*)(base + 18874368);                   // 12,582,912 -> 31,457,280
  unsigned short* wpk = (unsigned short*)(base + 31457280);   // 417,792   -> 31,875,072
  unsigned short* pWm0  = wpk;            // 480*256
  unsigned short* pWc   = wpk + 122880;   // 320*128
  unsigned short* pWenv = wpk + 163840;   // 128*192
  unsigned short* pWp0  = wpk + 188416;   // 128*128
  unsigned short* pWpv  = wpk + 204800;   //  64*64
  int* ibuf   = (int*)(base + 31875072);                      // 311,297 ints
  int* cnt    = ibuf;
  int* rowp   = ibuf + 16384;
  int* cursor = ibuf + 32769;
  int* perm   = ibuf + 49153;

  hipMemsetAsync(sa, 0, (size_t)N_NODES*320*sizeof(float), stream);
  hipMemsetAsync(cnt, 0, N_NODES*sizeof(int), stream);

  k_pack_all<<<(208896+255)/256, 256, 0, stream>>>(Wm0, wr, wi, Wenv, Wp0, Wpv, wpk);
  k_node_ln<<<N_NODES/4, 256, 0, stream>>>(nf, g0n, b0n, g1n, ns_ln, nv_ln);

  k_hist<<<(N_EDGES+255)/256, 256, 0, stream>>>(eidx, cnt);
  k_scan<<<1, 256, 0, stream>>>(cnt, rowp, cursor);
  k_fill<<<(N_EDGES+255)/256, 256, 0, stream>>>(eidx, cursor, perm);

  k_edge<<<N_EDGES/32, 256, POOL_BYTES, stream>>>(ef, evec, lats, g0e, b0e, g1e,
                                                  pWm0, pWc, pWenv, pWp0, pWpv, bp0,
                                                  eidx, perm, ns_ln, nv_ln,
                                                  sa, va);
  k_node_out<<<N_NODES/4, 256, 0, stream>>>(nf, oh, Wtp0, Wtp1, Wo0, bo0, Wov,
                                            resp, sa, va, (float*)d_out);
}

// Round 15
// 558.210 us; speedup vs baseline: 1.3196x; 1.0114x over previous
//
#include <hip/hip_runtime.h>
#include <math.h>

#define N_NODES 16384
#define N_EDGES 262144
#define EPSF 1e-8f

// ---------------- LDS pool layout (bytes), 32 edges/block ----------------
#define OFF_XE    0        // bf16 [32][232] = 14848   (LN 0..63, c0 64..223)
#define OFF_C12   14848    // bf16 [32][328] = 20992 -> 35840
#define OFF_FR    35840    // f16  [32][12]  =   768 -> 36608 (persistent)
#define OFF_EDST  36608    // int  [32]      =   128 -> 36736 (persistent)
#define OFF_ESRC  36736    // int  [32]      =   128 -> 36864 (persistent)
#define POOL_BYTES 36864   // 4 blocks/CU
// overlays (after G1/G2 done reading XE/C12)
#define OFF_SACT  0        // bf16 [32][136] = 8704
#define OFF_GATE  8704     // bf16 [32][72]  = 4608 -> 13312
#define OFF_C0O   13312    // bf16 [32][72]  = 4608 -> 17920
#define OFF_C1O   17920    // bf16 [32][72]  = 4608 -> 22528
#define OFF_C2O   22528    // bf16 [32][72]  = 4608 -> 27136
#define OFF_VG    8704     // bf16 [3][32][72] = 13824 -> 22528 (over GATE/C0O/C1O after consumed)
// final overlay: R f16 [32][320] = 20480 at 0 (after SACT/VG consumed)

typedef __bf16 bf16x8 __attribute__((ext_vector_type(8)));
typedef float  f32x4  __attribute__((ext_vector_type(4)));

__device__ __forceinline__ f32x4 MFMA16(bf16x8 a, bf16x8 b, f32x4 c){
  return __builtin_amdgcn_mfma_f32_16x16x32_bf16(a, b, c, 0, 0, 0);
}

__device__ __forceinline__ unsigned short f2bf(float x){
  __bf16 h = (__bf16)x;
  union { __bf16 b; unsigned short u; } c; c.b = h;
  return c.u;
}
__device__ __forceinline__ float bf2f(unsigned short h){
  union { unsigned u; float f; } c; c.u = ((unsigned)h)<<16;
  return c.f;
}
__device__ __forceinline__ float wsum32(float v){
  #pragma unroll
  for (int m=1; m<32; m<<=1) v += __shfl_xor(v, m);
  return v;
}
__device__ __forceinline__ float wsum64(float v){
  #pragma unroll
  for (int m=1; m<64; m<<=1) v += __shfl_xor(v, m);
  return v;
}
__device__ __forceinline__ float sigm(float x){ return 1.0f/(1.0f+__expf(-x)); }
__device__ __forceinline__ float silu(float x){ return x/(1.0f+__expf(-x)); }

// ---------------- fused weight pack kernel (B-fragment layout) ----------------
__global__ __launch_bounds__(256) void k_pack_all(
  const float* __restrict__ Wm0, const float* __restrict__ wr,
  const float* __restrict__ wi,  const float* __restrict__ Wenv,
  const float* __restrict__ Wp0, const float* __restrict__ Wpv,
  unsigned short* __restrict__ wpk)
{
  int i = blockIdx.x*256 + threadIdx.x;
  if (i < 122880){                       // Wm0 [480][256]
    int k = i >> 8, n = i & 255;
    int idx = (((k>>5)*256 + n)*4 + ((k>>3)&3))*8 + (k&7);
    wpk[idx] = f2bf(Wm0[i]);
  } else if (i < 163840){                // Wc [320][128] = [[wr,wi],[-wi,wr]]
    int j = i - 122880;
    int k = j >> 7, n = j & 127;
    float v;
    if (k < 160) v = (n < 64) ? wr[k*64 + n]        : wi[k*64 + (n-64)];
    else         v = (n < 64) ? -wi[(k-160)*64 + n] : wr[(k-160)*64 + (n-64)];
    int idx = (((k>>5)*128 + n)*4 + ((k>>3)&3))*8 + (k&7);
    wpk[122880 + idx] = f2bf(v);
  } else if (i < 188416){                // Wenv [128][192]
    int j = i - 163840;
    int k = j / 192, n = j - k*192;
    int idx = (((k>>5)*192 + n)*4 + ((k>>3)&3))*8 + (k&7);
    wpk[163840 + idx] = f2bf(Wenv[j]);
  } else if (i < 204800){                // Wp0 [128][128]
    int j = i - 188416;
    int k = j >> 7, n = j & 127;
    int idx = (((k>>5)*128 + n)*4 + ((k>>3)&3))*8 + (k&7);
    wpk[188416 + idx] = f2bf(Wp0[j]);
  } else if (i < 208896){                // Wpv [64][64]
    int j = i - 204800;
    int k = j >> 6, n = j & 63;
    int idx = (((k>>5)*64 + n)*4 + ((k>>3)&3))*8 + (k&7);
    wpk[204800 + idx] = f2bf(Wpv[j]);
  }
}

// ---------------- CSR build (perm = edges sorted by dst) ----------------
__global__ __launch_bounds__(256) void k_hist(const int* __restrict__ eidx, int* __restrict__ cnt){
  int e = blockIdx.x*256 + threadIdx.x;
  if (e < N_EDGES) atomicAdd(&cnt[eidx[N_EDGES+e]], 1);
}
__global__ __launch_bounds__(256) void k_scan(const int* __restrict__ cnt,
                                              int* __restrict__ rowp, int* __restrict__ cursor){
  __shared__ int part[256];
  __shared__ int pref[257];
  const int t = threadIdx.x;
  const int base = t*64;
  int s = 0;
  for (int i=0;i<64;i++) s += cnt[base+i];
  part[t] = s; __syncthreads();
  if (t==0){ int a=0; for (int i=0;i<256;i++){ pref[i]=a; a+=part[i]; } pref[256]=a; }
  __syncthreads();
  int a = pref[t];
  for (int i=0;i<64;i++){ rowp[base+i]=a; cursor[base+i]=a; a += cnt[base+i]; }
  if (t==0) rowp[N_NODES] = pref[256];
}
__global__ __launch_bounds__(256) void k_fill(const int* __restrict__ eidx,
                                              int* __restrict__ cursor, int* __restrict__ perm){
  int e = blockIdx.x*256 + threadIdx.x;
  if (e < N_EDGES){
    int pos = atomicAdd(&cursor[eidx[N_EDGES+e]], 1);
    perm[pos] = e;
  }
}

// ---------------- Kernel 1: node separable LN (scalars bf16, vectors f16) ----------------
__global__ __launch_bounds__(256) void k_node_ln(
    const float* __restrict__ nf, const float* __restrict__ g0,
    const float* __restrict__ b0, const float* __restrict__ g1,
    unsigned short* __restrict__ ns_ln, _Float16* __restrict__ nv_ln)
{
  const int tid  = threadIdx.x;
  const int lane = tid & 63;
  const int n    = blockIdx.x*4 + (tid>>6);
  const float* row = nf + (size_t)n*320;

  float s0 = row[lane], s1 = row[64+lane];
  float mu = wsum64(s0+s1) * (1.0f/128.0f);
  float d0 = s0-mu, d1 = s1-mu;
  float var = wsum64(d0*d0+d1*d1) * (1.0f/128.0f);
  float rs = rsqrtf(var + EPSF);
  ns_ln[(size_t)n*128 + lane]    = f2bf(d0*rs*g0[lane]    + b0[lane]);
  ns_ln[(size_t)n*128 + 64+lane] = f2bf(d1*rs*g0[64+lane] + b0[64+lane]);

  float px = row[128+lane*3+0], py = row[128+lane*3+1], pz = row[128+lane*3+2];
  float vvar = wsum64(px*px+py*py+pz*pz) * (1.0f/192.0f);
  float vsc = rsqrtf(vvar + EPSF) * g1[lane];
  nv_ln[(size_t)n*192 + lane*3+0] = (_Float16)(px*vsc);
  nv_ln[(size_t)n*192 + lane*3+1] = (_Float16)(py*vsc);
  nv_ln[(size_t)n*192 + lane*3+2] = (_Float16)(pz*vsc);
}

// ---------------- Kernel 2: edge message kernel (MFMA, 32 edges/block, slot order) ----------------
__global__ __launch_bounds__(256,4) void k_edge(
  const float* __restrict__ ef, const float* __restrict__ evec,
  const float* __restrict__ lats,
  const float* __restrict__ g0e, const float* __restrict__ b0e, const float* __restrict__ g1e,
  const unsigned short* __restrict__ pWm0, const unsigned short* __restrict__ pWc,
  const unsigned short* __restrict__ pWenv, const unsigned short* __restrict__ pWp0,
  const unsigned short* __restrict__ pWpv,
  const float* __restrict__ bp0,
  const int* __restrict__ eidx, const int* __restrict__ perm,
  const unsigned short* __restrict__ ns_ln, const _Float16* __restrict__ nv_ln,
  float* __restrict__ sa, float* __restrict__ va)
{
  extern __shared__ unsigned char pool[];
  const int tid = threadIdx.x;
  unsigned short* XE   = (unsigned short*)(pool + OFF_XE);
  unsigned short* C12s = (unsigned short*)(pool + OFF_C12);
  _Float16* FRh = (_Float16*)(pool + OFF_FR);
  int* EDST = (int*)(pool + OFF_EDST);
  int* ESRC = (int*)(pool + OFF_ESRC);

  // XCD-aware swizzle: contiguous slot span per XCD (nwg = 8192, %8 == 0)
  const int nwg = gridDim.x;
  const int bswz = (blockIdx.x & 7)*(nwg>>3) + (blockIdx.x >> 3);

  const int wid = tid>>6, l = tid&63;
  const int r15 = l&15, g = l>>4;
  const int sbase = bswz*32;

  // ---------------- Phase A: prep (4 passes of 8 edges, 32 lanes/edge) ----------------
  // Two-level MLP prefetch: level 1 (perm->eidx->evec/ef) and level 2 (nv rows)
  // all issued concurrently before the compute bodies. (r13/r14 Little's-law fix.)
  {
    const int ln = tid & 31;
    int psrc[4], pdst[4];
    float pvx[4], pvy[4], pvz[4];
    float pef0[4], pef1[4], pwx[4], pwy[4], pwz[4];
    #pragma unroll
    for (int eo=0; eo<4; ++eo){
      const int slot = sbase + eo*8 + (tid>>5);
      const int e = perm[slot];
      psrc[eo] = eidx[e];
      pdst[eo] = eidx[N_EDGES + e];
      pvx[eo] = evec[(size_t)e*3+0];
      pvy[eo] = evec[(size_t)e*3+1];
      pvz[eo] = evec[(size_t)e*3+2];
      const float* erow = ef + (size_t)e*160;
      pef0[eo] = erow[ln];
      pef1[eo] = erow[32+ln];
      pwx[eo]  = erow[64+ln*3+0];
      pwy[eo]  = erow[64+ln*3+1];
      pwz[eo]  = erow[64+ln*3+2];
    }
    // level-2: node-vector rows for all passes (48 f16 loads, issued together)
    _Float16 pns[4][6], pnd[4][6];
    #pragma unroll
    for (int eo=0; eo<4; ++eo){
      const _Float16* nvs = nv_ln + (size_t)psrc[eo]*192 + 3*ln;
      const _Float16* nvd = nv_ln + (size_t)pdst[eo]*192 + 3*ln;
      pns[eo][0]=nvs[0];  pns[eo][1]=nvs[1];  pns[eo][2]=nvs[2];
      pns[eo][3]=nvs[96]; pns[eo][4]=nvs[97]; pns[eo][5]=nvs[98];
      pnd[eo][0]=nvd[0];  pnd[eo][1]=nvd[1];  pnd[eo][2]=nvd[2];
      pnd[eo][3]=nvd[96]; pnd[eo][4]=nvd[97]; pnd[eo][5]=nvd[98];
    }

    #pragma unroll
    for (int eo=0; eo<4; ++eo){
      const int el = eo*8 + (tid>>5);
      const int src = psrc[eo];
      const int dst = pdst[eo];

      float vx=pvx[eo], vy=pvy[eo], vz=pvz[eo];
      float rn = rsqrtf(vx*vx+vy*vy+vz*vz+EPSF);
      float ax=vx*rn, ay=vy*rn, az=vz*rn;
      float hx, hz;
      if (fabsf(az) < 0.99f){ hx=0.f; hz=1.f; } else { hx=1.f; hz=0.f; }
      float e1x = -hz*ay;
      float e1y = hz*ax - hx*az;
      float e1z = hx*ay;
      float rn1 = rsqrtf(e1x*e1x+e1y*e1y+e1z*e1z+EPSF);
      e1x*=rn1; e1y*=rn1; e1z*=rn1;
      float e2x = ay*e1z - az*e1y;
      float e2y = az*e1x - ax*e1z;
      float e2z = ax*e1y - ay*e1x;
      if (ln==0){
        FRh[el*12+0]=(_Float16)ax;  FRh[el*12+1]=(_Float16)ay;  FRh[el*12+2]=(_Float16)az;
        FRh[el*12+3]=(_Float16)e1x; FRh[el*12+4]=(_Float16)e1y; FRh[el*12+5]=(_Float16)e1z;
        FRh[el*12+6]=(_Float16)e2x; FRh[el*12+7]=(_Float16)e2y; FRh[el*12+8]=(_Float16)e2z;
        EDST[el]=dst;
        ESRC[el]=src;
      }

      float s0=pef0[eo], s1=pef1[eo];
      float mu = wsum32(s0+s1)*(1.f/64.f);
      float d0=s0-mu, d1=s1-mu;
      float var = wsum32(d0*d0+d1*d1)*(1.f/64.f);
      float rs = rsqrtf(var+EPSF);
      XE[el*232 + ln]    = f2bf(d0*rs*g0e[ln]    + b0e[ln]);
      XE[el*232 + 32+ln] = f2bf(d1*rs*g0e[32+ln] + b0e[32+ln]);

      float wx=pwx[eo], wy=pwy[eo], wz=pwz[eo];
      float vvar = wsum32(wx*wx+wy*wy+wz*wz)*(1.f/96.f);
      float vsc = rsqrtf(vvar+EPSF)*g1e[ln];
      wx*=vsc; wy*=vsc; wz*=vsc;
      XE  [el*232 + 64+64+ln]    = f2bf(wx*ax +wy*ay +wz*az);
      C12s[el*328 + 64+ln]       = f2bf(wx*e1x+wy*e1y+wz*e1z);
      C12s[el*328 + 160+64+ln]   = f2bf(wx*e2x+wy*e2y+wz*e2z);

      #pragma unroll
      for (int q=0;q<2;q++){
        int u = ln+32*q;
        float px=(float)pns[eo][q*3+0], py=(float)pns[eo][q*3+1], pz=(float)pns[eo][q*3+2];
        XE  [el*232 + 64+u]      = f2bf(px*ax +py*ay +pz*az);
        C12s[el*328 + u]         = f2bf(px*e1x+py*e1y+pz*e1z);
        C12s[el*328 + 160+u]     = f2bf(px*e2x+py*e2y+pz*e2z);
        px=(float)pnd[eo][q*3+0]; py=(float)pnd[eo][q*3+1]; pz=(float)pnd[eo][q*3+2];
        XE  [el*232 + 64+96+u]   = f2bf(px*ax +py*ay +pz*az);
        C12s[el*328 + 96+u]      = f2bf(px*e1x+py*e1y+pz*e1z);
        C12s[el*328 + 160+96+u]  = f2bf(px*e2x+py*e2y+pz*e2z);
      }
    }
  }
  __syncthreads();

  const f32x4 zero4 = {0.f,0.f,0.f,0.f};

  // G1: m0 = X[32x480] @ Wm0[480x256]
  f32x4 acc1[2][4];
  #pragma unroll
  for (int m=0;m<2;m++)
    #pragma unroll
    for (int n=0;n<4;n++) acc1[m][n]=zero4;
  {
    const unsigned short* bbase = pWm0 + ((size_t)(wid*64 + r15)*4 + g)*8;
    bf16x8 gA[2][8];
    {
      const int rs0 = ESRC[r15], rs1 = ESRC[16+r15];
      const int rd0 = EDST[r15], rd1 = EDST[16+r15];
      #pragma unroll
      for (int q=0;q<4;q++){
        gA[0][q]   = *(const bf16x8*)&ns_ln[(size_t)rs0*128 + q*32 + g*8];
        gA[1][q]   = *(const bf16x8*)&ns_ln[(size_t)rs1*128 + q*32 + g*8];
        gA[0][4+q] = *(const bf16x8*)&ns_ln[(size_t)rd0*128 + q*32 + g*8];
        gA[1][4+q] = *(const bf16x8*)&ns_ln[(size_t)rd1*128 + q*32 + g*8];
      }
    }
    #pragma unroll
    for (int t=0;t<7;t++){
      const int kc  = (t<2) ? (4+t) : (10 + t-2);
      const int col = (t<2) ? (t*32) : (64 + (t-2)*32);
      bf16x8 a0 = *(const bf16x8*)&XE[(    r15)*232 + col + g*8];
      bf16x8 a1 = *(const bf16x8*)&XE[(16+ r15)*232 + col + g*8];
      const unsigned short* bp = bbase + (size_t)kc*8192;
      #pragma unroll
      for (int n=0;n<4;n++){
        bf16x8 b = *(const bf16x8*)(bp + n*512);
        acc1[0][n] = MFMA16(a0,b,acc1[0][n]);
        acc1[1][n] = MFMA16(a1,b,acc1[1][n]);
      }
    }
    #pragma unroll
    for (int t=0;t<8;t++){
      const int kc = (t<4) ? t : (6 + t-4);
      const unsigned short* bp = bbase + (size_t)kc*8192;
      #pragma unroll
      for (int n=0;n<4;n++){
        bf16x8 b = *(const bf16x8*)(bp + n*512);
        acc1[0][n] = MFMA16(gA[0][t],b,acc1[0][n]);
        acc1[1][n] = MFMA16(gA[1][t],b,acc1[1][n]);
      }
    }
  }

  // G2: c12o = C12[32x320] @ Wc[320x128]
  f32x4 acc2[2][2];
  #pragma unroll
  for (int m=0;m<2;m++){ acc2[m][0]=zero4; acc2[m][1]=zero4; }
  {
    const unsigned short* bbase = pWc + ((size_t)(wid*32 + r15)*4 + g)*8;
    #pragma unroll
    for (int kc=0;kc<10;kc++){
      bf16x8 a0 = *(const bf16x8*)&C12s[(    r15)*328 + kc*32 + g*8];
      bf16x8 a1 = *(const bf16x8*)&C12s[(16+ r15)*328 + kc*32 + g*8];
      const unsigned short* bp = bbase + (size_t)kc*4096;
      #pragma unroll
      for (int n=0;n<2;n++){
        bf16x8 b = *(const bf16x8*)(bp + n*512);
        acc2[0][n] = MFMA16(a0,b,acc2[0][n]);
        acc2[1][n] = MFMA16(a1,b,acc2[1][n]);
      }
    }
  }

  // ---------------- G3 (in-wave, post-G2): w = lats[32x128] @ Wenv col-tiles ----------------
  float wsc[2][2][4], wvc[2][4];
  {
    f32x4 acc3[2][3];
    #pragma unroll
    for (int m=0;m<2;m++)
      #pragma unroll
      for (int n=0;n<3;n++) acc3[m][n]=zero4;
    const int eg0 = perm[sbase + r15];
    const int eg1 = perm[sbase + 16 + r15];
    const float* la0 = lats + (size_t)eg0*128;
    const float* la1 = lats + (size_t)eg1*128;
    const int colb0 = wid*32, colb1 = wid*32+16, colb2 = 128+wid*16;
    #pragma unroll
    for (int kc=0;kc<4;kc++){
      float4 f00 = *(const float4*)&la0[kc*32 + g*8];
      float4 f01 = *(const float4*)&la0[kc*32 + g*8 + 4];
      float4 f10 = *(const float4*)&la1[kc*32 + g*8];
      float4 f11 = *(const float4*)&la1[kc*32 + g*8 + 4];
      union { bf16x8 v; unsigned short s[8]; } a0, a1;
      a0.s[0]=f2bf(f00.x); a0.s[1]=f2bf(f00.y); a0.s[2]=f2bf(f00.z); a0.s[3]=f2bf(f00.w);
      a0.s[4]=f2bf(f01.x); a0.s[5]=f2bf(f01.y); a0.s[6]=f2bf(f01.z); a0.s[7]=f2bf(f01.w);
      a1.s[0]=f2bf(f10.x); a1.s[1]=f2bf(f10.y); a1.s[2]=f2bf(f10.z); a1.s[3]=f2bf(f10.w);
      a1.s[4]=f2bf(f11.x); a1.s[5]=f2bf(f11.y); a1.s[6]=f2bf(f11.z); a1.s[7]=f2bf(f11.w);
      bf16x8 b0 = *(const bf16x8*)(pWenv + ((size_t)(kc*192 + colb0 + r15)*4 + g)*8);
      bf16x8 b1 = *(const bf16x8*)(pWenv + ((size_t)(kc*192 + colb1 + r15)*4 + g)*8);
      bf16x8 b2 = *(const bf16x8*)(pWenv + ((size_t)(kc*192 + colb2 + r15)*4 + g)*8);
      acc3[0][0] = MFMA16(a0.v,b0,acc3[0][0]);
      acc3[1][0] = MFMA16(a1.v,b0,acc3[1][0]);
      acc3[0][1] = MFMA16(a0.v,b1,acc3[0][1]);
      acc3[1][1] = MFMA16(a1.v,b1,acc3[1][1]);
      acc3[0][2] = MFMA16(a0.v,b2,acc3[0][2]);
      acc3[1][2] = MFMA16(a1.v,b2,acc3[1][2]);
    }
    const float S = 0.08838834764831845f;  // 1/sqrt(128)
    #pragma unroll
    for (int m=0;m<2;m++)
      #pragma unroll
      for (int r=0;r<4;r++){
        wsc[m][0][r] = acc3[m][0][r]*S;
        wsc[m][1][r] = acc3[m][1][r]*S;
        wvc[m][r]    = acc3[m][2][r]*S;
      }
  }

  // bias prefetch
  float bp0v[2];
  #pragma unroll
  for (int n=0;n<2;n++) bp0v[n] = bp0[wid*32 + n*16 + r15];

  __syncthreads();   // all waves done reading XE/C12

  // G1/G2 epilogues -> overlays (bf16)
  {
    unsigned short* SAs = (unsigned short*)(pool + OFF_SACT);
    unsigned short* GAb = (unsigned short*)(pool + OFF_GATE);
    unsigned short* C0b = (unsigned short*)(pool + OFF_C0O);
    #pragma unroll
    for (int m=0;m<2;m++)
      #pragma unroll
      for (int n=0;n<4;n++)
        #pragma unroll
        for (int r=0;r<4;r++){
          int e = m*16 + g*4 + r;
          int j = wid*64 + n*16 + r15;
          float v = acc1[m][n][r]*0.04564354645876384f;  // 1/sqrt(480)
          if (j < 128)      SAs[e*136 + j] = f2bf(silu(v));
          else if (j < 192) GAb[e*72 + (j-128)] = f2bf(sigm(v));
          else              C0b[e*72 + (j-192)] = f2bf(v);
        }
    unsigned short* C1b = (unsigned short*)(pool + OFF_C1O);
    unsigned short* C2b = (unsigned short*)(pool + OFF_C2O);
    #pragma unroll
    for (int m=0;m<2;m++)
      #pragma unroll
      for (int n=0;n<2;n++)
        #pragma unroll
        for (int r=0;r<4;r++){
          int e = m*16 + g*4 + r;
          int j = wid*32 + n*16 + r15;
          float v = acc2[m][n][r]*0.07905694150420949f;  // 1/sqrt(160)
          if (j < 64) C1b[e*72 + j] = f2bf(v);
          else        C2b[e*72 + (j-64)] = f2bf(v);
        }
  }
  __syncthreads();

  // C1: v_g = (c0o*a + c1o*e1 + c2o*e2)*gate -> VG bf16 (8 u's/thread)
  {
    const int e = tid>>3, u0 = (tid&7)*8;
    const unsigned short* GAb = (const unsigned short*)(pool + OFF_GATE);
    const unsigned short* C0b = (const unsigned short*)(pool + OFF_C0O);
    const unsigned short* C1b = (const unsigned short*)(pool + OFF_C1O);
    const unsigned short* C2b = (const unsigned short*)(pool + OFF_C2O);
    float ax=(float)FRh[e*12+0],  ay=(float)FRh[e*12+1],  az=(float)FRh[e*12+2];
    float b1x=(float)FRh[e*12+3], b1y=(float)FRh[e*12+4], b1z=(float)FRh[e*12+5];
    float b2x=(float)FRh[e*12+6], b2y=(float)FRh[e*12+7], b2z=(float)FRh[e*12+8];
    float vgx[8], vgy[8], vgz[8];
    #pragma unroll
    for (int i=0;i<8;i++){
      int u = u0+i;
      float gt = bf2f(GAb[e*72+u]);
      float c0 = bf2f(C0b[e*72+u]), c1 = bf2f(C1b[e*72+u]), c2 = bf2f(C2b[e*72+u]);
      vgx[i] = (c0*ax + c1*b1x + c2*b2x)*gt;
      vgy[i] = (c0*ay + c1*b1y + c2*b2y)*gt;
      vgz[i] = (c0*az + c1*b1z + c2*b2z)*gt;
    }
    __syncthreads();   // GATE/C0O/C1O reads done before VG overlay writes
    unsigned short* VGs = (unsigned short*)(pool + OFF_VG);
    #pragma unroll
    for (int i=0;i<8;i++){
      VGs[0*2304 + e*72 + u0+i] = f2bf(vgx[i]);
      VGs[1*2304 + e*72 + u0+i] = f2bf(vgy[i]);
      VGs[2*2304 + e*72 + u0+i] = f2bf(vgz[i]);
    }
  }
  __syncthreads();

  // G4: s2 = SACT @ Wp0 ; G5: v2c = VG[c] @ Wpv
  {
    const unsigned short* SAs = (const unsigned short*)(pool + OFF_SACT);
    const unsigned short* VGs = (const unsigned short*)(pool + OFF_VG);

    f32x4 acc4[2][2], acc5[3][2];
    #pragma unroll
    for (int m=0;m<2;m++){ acc4[m][0]=zero4; acc4[m][1]=zero4; }
    #pragma unroll
    for (int c=0;c<3;c++){ acc5[c][0]=zero4; acc5[c][1]=zero4; }

    {
      const unsigned short* bbase = pWp0 + ((size_t)(wid*32 + r15)*4 + g)*8;
      #pragma unroll
      for (int kc=0;kc<4;kc++){
        bf16x8 a0 = *(const bf16x8*)&SAs[(    r15)*136 + kc*32 + g*8];
        bf16x8 a1 = *(const bf16x8*)&SAs[(16+ r15)*136 + kc*32 + g*8];
        #pragma unroll
        for (int n=0;n<2;n++){
          bf16x8 b = *(const bf16x8*)(bbase + (size_t)kc*4096 + n*512);
          acc4[0][n] = MFMA16(a0,b,acc4[0][n]);
          acc4[1][n] = MFMA16(a1,b,acc4[1][n]);
        }
      }
    }
    {
      bf16x8 b5[2];
      #pragma unroll
      for (int kc=0;kc<2;kc++)
        b5[kc] = *(const bf16x8*)(pWpv + ((size_t)(kc*64 + wid*16 + r15)*4 + g)*8);
      #pragma unroll
      for (int c=0;c<3;c++)
        #pragma unroll
        for (int kc=0;kc<2;kc++){
          bf16x8 a0 = *(const bf16x8*)&VGs[c*2304 + (    r15)*72 + kc*32 + g*8];
          bf16x8 a1 = *(const bf16x8*)&VGs[c*2304 + (16+ r15)*72 + kc*32 + g*8];
          acc5[c][0] = MFMA16(a0,b5[kc],acc5[c][0]);
          acc5[c][1] = MFMA16(a1,b5[kc],acc5[c][1]);
        }
    }

    __syncthreads();   // all waves done reading SACT/VG before R overlay
    _Float16* R = (_Float16*)pool;   // f16 [32][320]
    #pragma unroll
    for (int m=0;m<2;m++)
      #pragma unroll
      for (int n=0;n<2;n++)
        #pragma unroll
        for (int r=0;r<4;r++){
          int e = m*16 + g*4 + r;
          int j = wid*32 + n*16 + r15;
          R[e*320 + j] = (_Float16)((acc4[m][n][r]*0.08838834764831845f + bp0v[n]) * wsc[m][n][r]);
        }
    #pragma unroll
    for (int c=0;c<3;c++)
      #pragma unroll
      for (int m=0;m<2;m++)
        #pragma unroll
        for (int r=0;r<4;r++){
          int e = m*16 + g*4 + r;
          int vch = wid*16 + r15;
          R[e*320 + 128 + vch*3 + c] = (_Float16)(acc5[c][m][r]*0.125f * wvc[m][r]);
        }
    __syncthreads();

    // segmented reduction over dst runs (slot order => sorted dst), then atomics
    for (int j = tid; j < 320; j += 256){
      float accv = (float)R[j];
      int cur = EDST[0];
      for (int e=1;e<32;e++){
        int d = EDST[e];
        float v = (float)R[e*320 + j];
        if (d != cur){
          float* tgt = (j<128) ? &sa[(size_t)cur*128 + j] : &va[(size_t)cur*192 + (j-128)];
          atomicAdd(tgt, accv);
          accv = v; cur = d;
        } else accv += v;
      }
      float* tgt = (j<128) ? &sa[(size_t)cur*128 + j] : &va[(size_t)cur*192 + (j-128)];
      atomicAdd(tgt, accv);
    }
  }
}

// ---------------- Kernel 3: per-node head + residual ----------------
__global__ __launch_bounds__(256) void k_node_out(
  const float* __restrict__ nf, const float* __restrict__ oh,
  const float* __restrict__ Wtp0, const float* __restrict__ Wtp1,
  const float* __restrict__ Wo0, const float* __restrict__ bo0,
  const float* __restrict__ Wov, const float* __restrict__ resp,
  const float* __restrict__ sa, const float* __restrict__ va,
  float* __restrict__ out)
{
  __shared__ float SAB[4][128];
  __shared__ float VX[4][64], VY[4][64], VZ[4][64];
  __shared__ float S3 [4][128];
  __shared__ float V3 [4][256];
  const int tid=threadIdx.x, lane=tid&63, g=tid>>6;
  const int n = blockIdx.x*4 + g;

  float cf=0.f;
  #pragma unroll
  for (int j=0;j<16;j++) cf += j*oh[(size_t)n*16+j];
  const int c = (int)(cf+0.5f);

  SAB[g][lane]    = sa[(size_t)n*128+lane]   *0.25f;
  SAB[g][64+lane] = sa[(size_t)n*128+64+lane]*0.25f;
  VX[g][lane] = va[(size_t)n*192+lane*3+0]*0.25f;
  VY[g][lane] = va[(size_t)n*192+lane*3+1]*0.25f;
  VZ[g][lane] = va[(size_t)n*192+lane*3+2]*0.25f;
  __syncthreads();

  float t00=0.f, t01=0.f, t02=0.f;
  const float* w0c = Wtp0 + (size_t)c*192;
  for (int u=0;u<128;u++){
    float s = SAB[g][u];
    t00 += s * w0c[(size_t)u*3072 + lane];
    t01 += s * w0c[(size_t)u*3072 + lane+64];
    t02 += s * w0c[(size_t)u*3072 + lane+128];
  }
  const float sct0 = 0.02209708691f; // 1/sqrt(2048)
  t00*=sct0; t01*=sct0; t02*=sct0;

  float t1x=0.f,t1y=0.f,t1z=0.f;
  const float* w1c = Wtp1 + (size_t)c*64;
  for (int u=0;u<64;u++){
    float wv = w1c[(size_t)u*1024 + lane];
    t1x += VX[g][u]*wv;
    t1y += VY[g][u]*wv;
    t1z += VZ[g][u]*wv;
  }
  t1x*=0.03125f; t1y*=0.03125f; t1z*=0.03125f;

  S3[g][lane]    = silu(t00);
  S3[g][64+lane] = silu(t01);
  float g2 = sigm(t02);
  float4 v3v = {t1x*g2, t1y*g2, t1z*g2, 0.f};
  *(float4*)&V3[g][lane*4] = v3v;
  __syncthreads();

  float s40=0.f, s41=0.f;
  for (int k=0;k<128;k++){
    float s3k = S3[g][k];
    s40 += s3k*Wo0[k*128+lane];
    s41 += s3k*Wo0[k*128+64+lane];
  }
  s40 = s40*0.08838834765f + bo0[lane];
  s41 = s41*0.08838834765f + bo0[64+lane];

  float v4x=0.f,v4y=0.f,v4z=0.f;
  for (int u=0;u<64;u++){
    float4 v3u = *(const float4*)&V3[g][u*4];
    float wv = Wov[u*64+lane];
    v4x += v3u.x*wv; v4y += v3u.y*wv; v4z += v3u.z*wv;
  }
  v4x*=0.125f; v4y*=0.125f; v4z*=0.125f;

  const float r = sigm(resp[0]);
  const float* row = nf + (size_t)n*320;
  float* orow = out + (size_t)n*320;
  orow[lane]      = r*row[lane]      + (1.f-r)*s40;
  orow[64+lane]   = r*row[64+lane]   + (1.f-r)*s41;
  orow[128+lane*3+0] = r*row[128+lane*3+0] + (1.f-r)*v4x;
  orow[128+lane*3+1] = r*row[128+lane*3+1] + (1.f-r)*v4y;
  orow[128+lane*3+2] = r*row[128+lane*3+2] + (1.f-r)*v4z;
}

extern "C" void kernel_launch(void* const* d_in, const int* in_sizes, int n_in,
                              void* d_out, int out_size, void* d_ws, size_t ws_size,
                              hipStream_t stream)
{
  const float* nf   = (const float*)d_in[0];
  const float* ef   = (const float*)d_in[1];
  const float* evec = (const float*)d_in[2];
  const float* lats = (const float*)d_in[3];
  const float* oh   = (const float*)d_in[4];
  const float* g0n  = (const float*)d_in[5];
  const float* b0n  = (const float*)d_in[6];
  const float* g1n  = (const float*)d_in[7];
  const float* g0e  = (const float*)d_in[8];
  const float* b0e  = (const float*)d_in[9];
  const float* g1e  = (const float*)d_in[10];
  const float* Wm0  = (const float*)d_in[11];
  const float* wr   = (const float*)d_in[12];
  const float* wi   = (const float*)d_in[13];
  const float* Wenv = (const float*)d_in[14];
  const float* Wp0  = (const float*)d_in[15];
  const float* bp0  = (const float*)d_in[16];
  const float* Wpv  = (const float*)d_in[17];
  const float* Wtp0 = (const float*)d_in[18];
  const float* Wtp1 = (const float*)d_in[19];
  const float* Wo0  = (const float*)d_in[20];
  const float* bo0  = (const float*)d_in[21];
  const float* Wov  = (const float*)d_in[22];
  const float* resp = (const float*)d_in[23];
  const int*   eidx = (const int*)d_in[24];

  char* base = (char*)d_ws;
  unsigned short* ns_ln = (unsigned short*)(base);            // 4,194,304 B
  _Float16* nv_ln = (_Float16*)(base + 4194304);              // 6,291,456 -> 10,485,760
  float* sa    = (float*)(base + 10485760);                   // 8,388,608 -> 18,874,368
  float* va    = (float*)(base + 18874368);                   // 12,582,912 -> 31,457,280
  unsigned short* wpk = (unsigned short*)(base + 31457280);   // 417,792   -> 31,875,072
  unsigned short* pWm0  = wpk;            // 480*256
  unsigned short* pWc   = wpk + 122880;   // 320*128
  unsigned short* pWenv = wpk + 163840;   // 128*192
  unsigned short* pWp0  = wpk + 188416;   // 128*128
  unsigned short* pWpv  = wpk + 204800;   //  64*64
  int* ibuf   = (int*)(base + 31875072);                      // 311,297 ints
  int* cnt    = ibuf;
  int* rowp   = ibuf + 16384;
  int* cursor = ibuf + 32769;
  int* perm   = ibuf + 49153;

  hipMemsetAsync(sa, 0, (size_t)N_NODES*320*sizeof(float), stream);
  hipMemsetAsync(cnt, 0, N_NODES*sizeof(int), stream);

  k_pack_all<<<(208896+255)/256, 256, 0, stream>>>(Wm0, wr, wi, Wenv, Wp0, Wpv, wpk);
  k_node_ln<<<N_NODES/4, 256, 0, stream>>>(nf, g0n, b0n, g1n, ns_ln, nv_ln);

  k_hist<<<(N_EDGES+255)/256, 256, 0, stream>>>(eidx, cnt);
  k_scan<<<1, 256, 0, stream>>>(cnt, rowp, cursor);
  k_fill<<<(N_EDGES+255)/256, 256, 0, stream>>>(eidx, cursor, perm);

  k_edge<<<N_EDGES/32, 256, POOL_BYTES, stream>>>(ef, evec, lats, g0e, b0e, g1e,
                                                  pWm0, pWc, pWenv, pWp0, pWpv, bp0,
                                                  eidx, perm, ns_ln, nv_ln,
                                                  sa, va);
  k_node_out<<<N_NODES/4, 256, 0, stream>>>(nf, oh, Wtp0, Wtp1, Wo0, bo0, Wov,
                                            resp, sa, va, (float*)d_out);
}